// Round 20
// baseline (272.704 us; speedup 1.0000x reference)
//
#include <hip/hip_runtime.h>

#define NHW 2304
#define NB  8
#define NS  20
#define NC  512
#define SCL 0.09016844005555897f   // log2(e)/16

typedef unsigned short u16;
typedef unsigned char u8;
typedef short short8 __attribute__((ext_vector_type(8)));
typedef unsigned short u16x8 __attribute__((ext_vector_type(8)));
typedef u8 u8x16 __attribute__((ext_vector_type(16)));
typedef float f32x4 __attribute__((ext_vector_type(4)));

__device__ __forceinline__ float b2f(u16 u) {
    unsigned int v = ((unsigned int)u) << 16;
    return __builtin_bit_cast(float, v);
}
__device__ __forceinline__ u16 f2b(float f) {
    unsigned int u = __builtin_bit_cast(unsigned int, f);
    u += 0x7fffu + ((u >> 16) & 1u);
    return (u16)(u >> 16);
}

// ---- software fp8 e4m3fn fallback ----
__device__ __forceinline__ u8 f2e4_sw(float f) {
    unsigned int u = __builtin_bit_cast(unsigned int, f);
    u8 sign = (u >> 24) & 0x80;
    unsigned int a = u & 0x7FFFFFFFu;
    if (a >= 0x43E00000u) return sign | 0x7E;
    int e = (int)(a >> 23) - 127;
    unsigned int m = (a & 0x7FFFFF) | 0x800000;
    int ne = e + 7;
    if (ne <= 0) {
        int shift = 21 - ne;
        if (shift > 24) return sign;
        unsigned int q = m >> shift;
        unsigned int rem = m & ((1u << shift) - 1);
        unsigned int half = 1u << (shift - 1);
        q += (rem > half) || (rem == half && (q & 1));
        return sign | (u8)q;
    }
    unsigned int q = m >> 20;
    unsigned int rem = m & 0xFFFFFu;
    q += (rem > 0x80000u) || (rem == 0x80000u && (q & 1));
    if (q >= 16) { q >>= 1; ne++; }
    if (ne >= 16 || (ne == 15 && q == 15)) return sign | 0x7E;
    return sign | (u8)((ne << 3) | (q & 7));
}
__device__ __forceinline__ float e42f_sw(u8 v) {
    int e = (v >> 3) & 15;
    int m = v & 7;
    float r;
    if (e == 0) r = (float)m * 0.001953125f;
    else {
        unsigned int bits = ((unsigned int)(e + 120) << 23) | ((unsigned int)m << 20);
        r = __builtin_bit_cast(float, bits);
    }
    return (v & 0x80) ? -r : r;
}

// ---- hardware fp8 conversion (gfx950); hi/sel must be immediates ----
#if defined(__has_builtin)
#if __has_builtin(__builtin_amdgcn_cvt_pk_fp8_f32) && __has_builtin(__builtin_amdgcn_cvt_f32_fp8)
#define HW_FP8 1
#endif
#endif

template<bool HI>
__device__ __forceinline__ unsigned int pk2_fp8(float a, float b, unsigned int old) {
#ifdef HW_FP8
    return (unsigned int)__builtin_amdgcn_cvt_pk_fp8_f32(a, b, (int)old, HI);
#else
    unsigned int lo = (unsigned int)f2e4_sw(a) | ((unsigned int)f2e4_sw(b) << 8);
    return HI ? ((old & 0x0000FFFFu) | (lo << 16)) : ((old & 0xFFFF0000u) | lo);
#endif
}
#ifdef HW_FP8
#define DEC_FP8(w, sel) __builtin_amdgcn_cvt_f32_fp8((int)(w), (sel))
#else
#define DEC_FP8(w, sel) e42f_sw((u8)((w) >> (8 * (sel))))
#endif

__device__ __forceinline__ void load_lds16(const void* g, void* l) {
    __builtin_amdgcn_global_load_lds((const __attribute__((address_space(1))) void*)g,
                                     (__attribute__((address_space(3))) void*)l, 16, 0, 0);
}

// ---------------------------------------------------------------------------
// bf16 NT GEMM, 128x128 tile, BK=64, bank-swizzled LDS.
// out_mode: 0 bf16, 1 f32, 2 fp8
// ---------------------------------------------------------------------------
__global__ __launch_bounds__(256)
void gemm_nt_bf16(const u16* __restrict__ A, long As, int lda,
                  const u16* __restrict__ B, long Bs, int ldb,
                  void* __restrict__ C, long Cs, int ldc,
                  int K, const float* __restrict__ bias, int bias_mode,
                  float scale, int out_mode)
{
    __shared__ __align__(16) u16 sA[2 * 4096];
    __shared__ __align__(16) u16 sB[2 * 4096];
    const int tid   = threadIdx.x;
    const int b     = blockIdx.z;
    const int nBase = blockIdx.x * 128;
    const int mBase = blockIdx.y * 128;
    const u16* Ab = A + (size_t)b * As + (size_t)mBase * lda;
    const u16* Bb = B + (size_t)b * Bs + (size_t)nBase * ldb;
    const int lane = tid & 63;
    const int wave = tid >> 6;
    const int wr = wave >> 1, wc = wave & 1;
    const int srow[4] = { ((wave * 4 + 0) & 7) * 16 + (lane >> 2),
                          ((wave * 4 + 1) & 7) * 16 + (lane >> 2),
                          ((wave * 4 + 2) & 7) * 16 + (lane >> 2),
                          ((wave * 4 + 3) & 7) * 16 + (lane >> 2) };
    const int swzw = ((lane & 3) ^ ((lane >> 3) & 3)) * 8;
    const int rsw  = ((lane >> 4) ^ ((lane >> 1) & 3)) * 8;
    f32x4 acc[4][4] = {};
    for (int k0 = 0; k0 < K; k0 += 64) {
        __syncthreads();
        #pragma unroll
        for (int it = 0; it < 4; ++it) {
            const int chunk = wave * 4 + it;
            const int kofs = (chunk >> 3) * 32 + swzw;
            load_lds16(&Ab[(size_t)srow[it] * lda + k0 + kofs], &sA[chunk * 512 + lane * 8]);
            load_lds16(&Bb[(size_t)srow[it] * ldb + k0 + kofs], &sB[chunk * 512 + lane * 8]);
        }
        __syncthreads();
        #pragma unroll
        for (int kk = 0; kk < 2; ++kk) {
            short8 af[4], bg[4];
            #pragma unroll
            for (int i = 0; i < 4; ++i)
                af[i] = *(const short8*)&sA[kk * 4096 + (wr * 64 + i * 16 + (lane & 15)) * 32 + rsw];
            #pragma unroll
            for (int j = 0; j < 4; ++j)
                bg[j] = *(const short8*)&sB[kk * 4096 + (wc * 64 + j * 16 + (lane & 15)) * 32 + rsw];
            #pragma unroll
            for (int i = 0; i < 4; ++i)
                #pragma unroll
                for (int j = 0; j < 4; ++j)
                    acc[i][j] = __builtin_amdgcn_mfma_f32_16x16x32_bf16(af[i], bg[j], acc[i][j], 0, 0, 0);
        }
    }
    const int r0 = mBase + wr * 64 + (lane >> 4) * 4;
    const int c0 = nBase + wc * 64 + (lane & 15);
    #pragma unroll
    for (int i = 0; i < 4; ++i) {
        #pragma unroll
        for (int r = 0; r < 4; ++r) {
            const int row = r0 + i * 16 + r;
            const float br = (bias_mode == 1) ? bias[row] : 0.f;
            if (out_mode == 2) {
                float vv[4];
                #pragma unroll
                for (int j = 0; j < 4; ++j) vv[j] = acc[i][j][r] * scale + br;
                unsigned int w = 0;
                w = pk2_fp8<false>(vv[0], vv[1], w);
                w = pk2_fp8<true>(vv[2], vv[3], w);
                #pragma unroll
                for (int j = 0; j < 4; ++j)
                    ((u8*)C)[(size_t)b * Cs + (size_t)row * ldc + c0 + j * 16] = (u8)(w >> (8 * j));
            } else {
                #pragma unroll
                for (int j = 0; j < 4; ++j) {
                    const int col = c0 + j * 16;
                    float v = acc[i][j][r] * scale + br;
                    const size_t off = (size_t)b * Cs + (size_t)row * ldc + col;
                    if (out_mode == 1) ((float*)C)[off] = v;
                    else               ((u16*)C)[off] = f2b(v);
                }
            }
        }
    }
}

// ---------------------------------------------------------------------------
// E-GEMM: E8[n][m] = fp8(exp2(attnwT[n]·ks[m])); Dpart from ROUNDED values (HW cvt).
// ---------------------------------------------------------------------------
__global__ __launch_bounds__(256)
void e_gemm(const u16* __restrict__ attnwT, const u16* __restrict__ ks,
            u8* __restrict__ E8, float* __restrict__ Dpart)
{
    __shared__ __align__(16) u16 sA[128 * 32];
    __shared__ __align__(16) u16 sB[128 * 32];
    __shared__ __align__(16) u8 Etile[128 * 128];   // 16 KB, swizzled
    __shared__ float Dsh[2][128];
    const int tid = threadIdx.x;
    const int b = blockIdx.z;
    const int mt = blockIdx.x, nt = blockIdx.y;
    const int mBase = mt * 128, nBase = nt * 128;
    const u16* Ab = attnwT + ((size_t)b * NHW + nBase) * 32;
    const u16* Bb = ks     + ((size_t)b * NHW + mBase) * 32;
    const int lane = tid & 63;
    const int wave = tid >> 6;
    const int wr = wave >> 1, wc = wave & 1;
    const int str = tid >> 2;
    const int stk = (tid & 3) * 8;
    load_lds16(&Ab[(size_t)str * 32 + stk],        &sA[tid * 8]);
    load_lds16(&Ab[(size_t)(str + 64) * 32 + stk], &sA[2048 + tid * 8]);
    load_lds16(&Bb[(size_t)str * 32 + stk],        &sB[tid * 8]);
    load_lds16(&Bb[(size_t)(str + 64) * 32 + stk], &sB[2048 + tid * 8]);
    __syncthreads();
    short8 af[4], bg[4];
    #pragma unroll
    for (int i = 0; i < 4; ++i)
        af[i] = *(const short8*)&sA[(wr * 64 + i * 16 + (lane & 15)) * 32 + (lane >> 4) * 8];
    #pragma unroll
    for (int j = 0; j < 4; ++j)
        bg[j] = *(const short8*)&sB[(wc * 64 + j * 16 + (lane & 15)) * 32 + (lane >> 4) * 8];
    f32x4 acc[4][4] = {};
    #pragma unroll
    for (int i = 0; i < 4; ++i)
        #pragma unroll
        for (int j = 0; j < 4; ++j)
            acc[i][j] = __builtin_amdgcn_mfma_f32_16x16x32_bf16(af[i], bg[j], acc[i][j], 0, 0, 0);

    float dpart[16] = {};
    #pragma unroll
    for (int i = 0; i < 4; ++i) {
        #pragma unroll
        for (int r = 0; r < 4; ++r) {
            const int rowloc = wr * 64 + i * 16 + (lane >> 4) * 4 + r;
            unsigned int w = 0;
            w = pk2_fp8<false>(exp2f(acc[i][0][r]), exp2f(acc[i][1][r]), w);
            w = pk2_fp8<true>(exp2f(acc[i][2][r]), exp2f(acc[i][3][r]), w);
            dpart[i * 4 + r] += DEC_FP8(w, 0) + DEC_FP8(w, 1) + DEC_FP8(w, 2) + DEC_FP8(w, 3);
            #pragma unroll
            for (int j = 0; j < 4; ++j) {
                const int colloc = wc * 64 + j * 16 + (lane & 15);
                Etile[rowloc * 128 + (colloc ^ ((rowloc & 7) << 4))] = (u8)(w >> (8 * j));
            }
        }
    }
    #pragma unroll
    for (int mask = 1; mask < 16; mask <<= 1)
        #pragma unroll
        for (int k = 0; k < 16; ++k)
            dpart[k] += __shfl_xor(dpart[k], mask, 64);
    if ((lane & 15) == 0) {
        #pragma unroll
        for (int i = 0; i < 4; ++i)
            #pragma unroll
            for (int r = 0; r < 4; ++r)
                Dsh[wc][wr * 64 + i * 16 + (lane >> 4) * 4 + r] = dpart[i * 4 + r];
    }
    __syncthreads();
    if (tid < 128)
        Dpart[((size_t)(b * 18 + mt)) * NHW + nBase + tid] = Dsh[0][tid] + Dsh[1][tid];
    #pragma unroll
    for (int rep = 0; rep < 4; ++rep) {
        const int row = wave * 32 + rep * 8 + (lane >> 3);
        const int slot = lane & 7;
        u8x16 v = *(const u8x16*)&Etile[row * 128 + ((slot ^ (row & 7)) << 4)];
        *(u8x16*)&E8[((size_t)b * NHW + nBase + row) * NHW + mBase + slot * 16] = v;
    }
}

// ---------------------------------------------------------------------------
// PV GEMM fp8, 128x128 tile, BK=128, chunk-XOR swizzle c^=(row&7).
// out = (vp8·E8 + qp·(aw·Dsum)) * Dinv. Grid 576, b = XCD.
// ---------------------------------------------------------------------------
__global__ __launch_bounds__(256)
void pv_gemm(const u8* __restrict__ vp8, const u8* __restrict__ E8,
             const float* __restrict__ Dpart, const float* __restrict__ attnw,
             const float* __restrict__ Ofold, const float* __restrict__ b2,
             float* __restrict__ out)
{
    __shared__ __align__(16) u8 sA[16384];
    __shared__ __align__(16) u8 sB[16384];
    __shared__ float DsumSh[128];
    __shared__ float DinvSh[128];
    const int tid = threadIdx.x;
    const int bid = blockIdx.x;
    const int xcd = bid & 7, slot = bid >> 3;
    const int b = xcd;
    const int nt = slot >> 2;
    const int ot = slot & 3;
    const int oBase = ot * 128, nBase = nt * 128;

    const u8* A8 = vp8 + ((size_t)b * NC + oBase) * NHW;
    const u8* B8 = E8  + ((size_t)b * NHW + nBase) * NHW;
    const int lane = tid & 63;
    const int wave = tid >> 6;
    const int wr = wave >> 1, wc = wave & 1;

    int srowS[4], sgofS[4];
    #pragma unroll
    for (int it = 0; it < 4; ++it) {
        const int cd = (wave * 4 + it) * 64 + lane;
        srowS[it] = cd >> 3;
        sgofS[it] = ((cd & 7) ^ ((cd >> 3) & 7)) * 16;
    }
    #define PV_STAGE(k0) { \
        _Pragma("unroll") \
        for (int it = 0; it < 4; ++it) { \
            load_lds16(&A8[(size_t)srowS[it] * NHW + (k0) + sgofS[it]], &sA[((wave * 4 + it) * 64 + lane) * 16]); \
            load_lds16(&B8[(size_t)srowS[it] * NHW + (k0) + sgofS[it]], &sB[((wave * 4 + it) * 64 + lane) * 16]); \
        } }

    u16* sAh = (u16*)sA;
    u16* sBh = (u16*)sB;
    if (tid < 128) {
        float s = 0.f;
        #pragma unroll
        for (int mt = 0; mt < 18; ++mt)
            s += Dpart[((size_t)(b * 18 + mt)) * NHW + nBase + tid];
        DsumSh[tid] = s;
        DinvSh[tid] = 1.f / s;
    }
    for (int idx = tid; idx < 128 * 32; idx += 256) {
        const int o = idx >> 5, s = idx & 31;
        float v = 0.f;
        if (s < 20) v = Ofold[((size_t)b * 768 + 256 + oBase + o) * NS + s];
        else if (s == 20) v = b2[oBase + o];
        sAh[idx] = f2b(v);
    }
    __syncthreads();
    for (int idx = tid; idx < 128 * 32; idx += 256) {
        const int n = idx >> 5, s = idx & 31;
        float v = 0.f;
        if (s <= 20) {
            const float ds = DsumSh[n];
            v = (s < 20) ? attnw[((size_t)b * NS + s) * NHW + nBase + n] * ds : ds;
        }
        sBh[idx] = f2b(v);
    }
    __syncthreads();

    f32x4 acc[4][4];
    {
        const f32x4 zero = {0.f, 0.f, 0.f, 0.f};
        short8 qf[4], afr[4];
        #pragma unroll
        for (int i = 0; i < 4; ++i)
            qf[i] = *(const short8*)&sAh[(wr * 64 + i * 16 + (lane & 15)) * 32 + (lane >> 4) * 8];
        #pragma unroll
        for (int j = 0; j < 4; ++j)
            afr[j] = *(const short8*)&sBh[(wc * 64 + j * 16 + (lane & 15)) * 32 + (lane >> 4) * 8];
        #pragma unroll
        for (int i = 0; i < 4; ++i)
            #pragma unroll
            for (int j = 0; j < 4; ++j)
                acc[i][j] = __builtin_amdgcn_mfma_f32_16x16x32_bf16(qf[i], afr[j], zero, 0, 0, 0);
    }

    const int krow_a = wr * 64 + (lane & 15);
    const int krow_b = wc * 64 + (lane & 15);
    const int khalf = ((lane >> 4) & 1) * 8;
    const int kc2   = (lane >> 5);

    for (int k0 = 0; k0 < NHW; k0 += 128) {
        __syncthreads();
        PV_STAGE(k0);
        __syncthreads();
        #pragma unroll
        for (int kk = 0; kk < 4; ++kk) {
            long af[4], bg[4];
            #pragma unroll
            for (int i = 0; i < 4; ++i) {
                const int row = krow_a + i * 16;
                const int c = (kk * 2 + kc2) ^ (row & 7);
                af[i] = *(const long*)&sA[row * 128 + c * 16 + khalf];
            }
            #pragma unroll
            for (int j = 0; j < 4; ++j) {
                const int row = krow_b + j * 16;
                const int c = (kk * 2 + kc2) ^ (row & 7);
                bg[j] = *(const long*)&sB[row * 128 + c * 16 + khalf];
            }
            #pragma unroll
            for (int i = 0; i < 4; ++i)
                #pragma unroll
                for (int j = 0; j < 4; ++j)
                    acc[i][j] = __builtin_amdgcn_mfma_f32_16x16x32_fp8_fp8(af[i], bg[j], acc[i][j], 0, 0, 0);
        }
    }
    #pragma unroll
    for (int i = 0; i < 4; ++i) {
        #pragma unroll
        for (int r = 0; r < 4; ++r) {
            const int rowloc = wr * 64 + i * 16 + (lane >> 4) * 4 + r;
            #pragma unroll
            for (int j = 0; j < 4; ++j) {
                const int colloc = wc * 64 + j * 16 + (lane & 15);
                out[((size_t)b * NC + oBase + rowloc) * NHW + nBase + colloc] =
                    acc[i][j][r] * DinvSh[colloc];
            }
        }
    }
    #undef PV_STAGE
}

// src (batch, R, Cc) fp32 -> dst (batch, Cc, R) bf16  (fv only now)
__global__ __launch_bounds__(256)
void transpose_gen(const float* __restrict__ src, u16* __restrict__ dst,
                   int R, int Cc)
{
    __shared__ u16 t[64][72];
    const int b = blockIdx.z;
    const int cBase = blockIdx.x * 64;
    const int rBase = blockIdx.y * 64;
    const int tid = threadIdx.x;
    const float* sb = src + ((size_t)b * R + rBase) * Cc + cBase;
    const int ln = tid & 63;
    const int lr = tid >> 6;
    #pragma unroll
    for (int rr = 0; rr < 16; ++rr) {
        int r = lr + rr * 4;
        t[r][ln] = f2b(sb[(size_t)r * Cc + ln]);
    }
    __syncthreads();
    u16* ob = dst + ((size_t)b * Cc + cBase) * R + rBase;
    #pragma unroll
    for (int rep = 0; rep < 2; ++rep) {
        int slot = rep * 256 + tid;
        int cc = slot >> 3;
        int r8 = (slot & 7) * 8;
        u16x8 v;
        #pragma unroll
        for (int e = 0; e < 8; ++e) v[e] = t[r8 + e][cc];
        *(u16x8*)&ob[(size_t)cc * R + r8] = v;
    }
}

__global__ __launch_bounds__(256)
void make_wc2(const float* __restrict__ w1, const float* __restrict__ w1b,
              const float* __restrict__ w2, const float* __restrict__ w2b,
              const float* __restrict__ fvb,
              u16* __restrict__ wc2b, float* __restrict__ b2)
{
    const int o = blockIdx.x;
    const int t = threadIdx.x;
    float part = 0.f;
    for (int c = t; c < 512; c += 256) {
        float v = w1[(size_t)o * 1024 + c] + w2[(size_t)o * 512 + c];
        wc2b[(size_t)o * 512 + c] = f2b(v);
        part += v * fvb[c];
    }
    #pragma unroll
    for (int off = 32; off > 0; off >>= 1) part += __shfl_down(part, off, 64);
    __shared__ float red[4];
    if ((t & 63) == 0) red[t >> 6] = part;
    __syncthreads();
    if (t == 0) b2[o] = (red[0] + red[1]) + (red[2] + red[3]) + w1b[o] + w2b[o];
}

__global__ __launch_bounds__(256)
void fold_query_wv(const float* __restrict__ query, const float* __restrict__ wv_w,
                   const float* __restrict__ wv_b,
                   float* __restrict__ qw, float* __restrict__ qb)
{
    __shared__ float qs[NC];
    const int b = blockIdx.y, s = blockIdx.x;
    const int tid = threadIdx.x;
    qs[tid] = query[((size_t)b * NS + s) * NC + tid];
    qs[tid + 256] = query[((size_t)b * NS + s) * NC + tid + 256];
    __syncthreads();
    float a0 = 0.f, a1 = 0.f;
    for (int o = 0; o < NC; ++o) {
        float qv = qs[o];
        a0 += qv * wv_w[(size_t)o * NC + tid];
        a1 += qv * wv_w[(size_t)o * NC + tid + 256];
    }
    qw[((size_t)b * NS + s) * NC + tid] = a0;
    qw[((size_t)b * NS + s) * NC + tid + 256] = a1;
    float pb = qs[tid] * wv_b[tid] + qs[tid + 256] * wv_b[tid + 256];
    #pragma unroll
    for (int off = 32; off > 0; off >>= 1) pb += __shfl_down(pb, off, 64);
    __shared__ float red[4];
    if ((tid & 63) == 0) red[tid >> 6] = pb;
    __syncthreads();
    if (tid == 0) qb[b * NS + s] = (red[0] + red[1]) + (red[2] + red[3]);
}

__global__ __launch_bounds__(256)
void fold_wq(const float* __restrict__ query, const float* __restrict__ fq,
             const float* __restrict__ w1, float* __restrict__ O)
{
    __shared__ float qsh[NS][NC];
    const int b = blockIdx.y;
    const int tid = threadIdx.x;
    for (int idx = tid; idx < NS * NC; idx += 256)
        qsh[idx >> 9][idx & 511] = query[(size_t)b * NS * NC + idx];
    __syncthreads();
    const int row = blockIdx.x * 16 + (tid >> 4);
    const int ct = tid & 15;
    const float* wp = (row < 256) ? &fq[(size_t)row * NC]
                                  : &w1[(size_t)(row - 256) * 1024 + 512];
    float acc[NS] = {};
    #pragma unroll 4
    for (int i = 0; i < 32; ++i) {
        int c = ct + i * 16;
        float w = wp[c];
        #pragma unroll
        for (int s = 0; s < NS; ++s) acc[s] += w * qsh[s][c];
    }
    #pragma unroll
    for (int off = 1; off < 16; off <<= 1)
        #pragma unroll
        for (int s = 0; s < NS; ++s) acc[s] += __shfl_xor(acc[s], off, 64);
    if (ct == 0) {
        #pragma unroll
        for (int s = 0; s < NS; ++s)
            O[((size_t)b * 768 + row) * NS + s] = acc[s];
    }
}

// ---------------------------------------------------------------------------
// Fused key scan: word-attn logits + ks logits + keyT transpose in one pass.
// ---------------------------------------------------------------------------
__global__ __launch_bounds__(256)
void scan_wk(const float* __restrict__ key, const float* __restrict__ qw,
             const float* __restrict__ qb, const int* __restrict__ wid,
             const float* __restrict__ g, const float* __restrict__ h,
             float* __restrict__ attnw, u16* __restrict__ attnwT,
             u16* __restrict__ ks, u16* __restrict__ keyT)
{
    __shared__ float qshT[NC][20];
    __shared__ u16 gshb[NC][22];
    __shared__ float red[3][64][7];
    __shared__ float msk[20], qbs[20], hsh[21];
    const int b = blockIdx.y;
    const int tid = threadIdx.x;
    const float* qwb = qw + (size_t)b * NS * NC;
    for (int idx = tid; idx < NC * 20; idx += 256) {
        int c = idx / 20, s = idx - c * 20;
        qshT[c][s] = qwb[s * NC + c];
    }
    for (int idx = tid; idx < NC * 21; idx += 256) {
        int c = idx / 21, s = idx - c * 21;
        gshb[c][s] = f2b(g[((size_t)b * NC + c) * 24 + s]);
    }
    if (tid < 20) {
        msk[tid] = (wid[b * NS + tid] != 0) ? 1.f : 0.f;
        qbs[tid] = qb[b * NS + tid];
    }
    if (tid < 21) hsh[tid] = h[b * 24 + tid];
    __syncthreads();
    const int wave = tid >> 6, lane = tid & 63;
    const int n = blockIdx.x * 64 + lane;
    const int cbase = wave * 128;
    const float* kp = key + (size_t)b * NC * NHW + n;
    u16* ktp = keyT + ((size_t)b * NHW + n) * NC + cbase;
    float acc[41];
    #pragma unroll
    for (int s = 0; s < 41; ++s)
        acc[s] = (wave == 0) ? (s < 20 ? qbs[s] : hsh[s - 20]) : 0.f;
    for (int c8 = 0; c8 < 16; ++c8) {
        u16x8 pk;
        #pragma unroll
        for (int e = 0; e < 8; ++e) {
            const int c = cbase + c8 * 8 + e;
            float kv = kp[(size_t)c * NHW];
            pk[e] = f2b(kv);
            #pragma unroll
            for (int s = 0; s < 20; ++s) acc[s] += qshT[c][s] * kv;
            #pragma unroll
            for (int s = 0; s < 21; ++s) acc[20 + s] += b2f(gshb[c][s]) * kv;
        }
        *(u16x8*)&ktp[c8 * 8] = pk;
    }
    #pragma unroll
    for (int r = 0; r < 6; ++r) {
        if (wave > 0) {
            #pragma unroll
            for (int k = 0; k < 7; ++k) {
                int idx = r * 7 + k;
                if (idx < 41) red[wave - 1][lane][k] = acc[idx];
            }
        }
        __syncthreads();
        if (wave == 0) {
            #pragma unroll
            for (int k = 0; k < 7; ++k) {
                int idx = r * 7 + k;
                if (idx < 41)
                    acc[idx] += red[0][lane][k] + red[1][lane][k] + red[2][lane][k];
            }
        }
        __syncthreads();
    }
    if (wave == 0) {
        float mx = acc[0];
        #pragma unroll
        for (int s = 1; s < 20; ++s) mx = fmaxf(mx, acc[s]);
        float msum = 0.f;
        #pragma unroll
        for (int s = 0; s < 20; ++s) {
            acc[s] = __expf(acc[s] - mx) * msk[s];
            msum += acc[s];
        }
        const float rr = 1.f / msum;
        u16 row32[32];
        #pragma unroll
        for (int s = 0; s < 20; ++s) {
            float a = acc[s] * rr;
            attnw[((size_t)b * NS + s) * NHW + n] = a;
            row32[s] = f2b(a);
        }
        row32[20] = 0x3F80;
        #pragma unroll
        for (int s = 21; s < 32; ++s) row32[s] = 0;
        u16* dp = attnwT + ((size_t)b * NHW + n) * 32;
        #pragma unroll
        for (int q = 0; q < 4; ++q)
            *(u16x8*)&dp[q * 8] = *(u16x8*)&row32[q * 8];
        u16 rk[32];
        #pragma unroll
        for (int s = 0; s < 21; ++s) rk[s] = f2b(acc[20 + s]);
        #pragma unroll
        for (int s = 21; s < 32; ++s) rk[s] = 0;
        u16* kp2 = ks + ((size_t)b * NHW + n) * 32;
        #pragma unroll
        for (int q = 0; q < 4; ++q)
            *(u16x8*)&kp2[q * 8] = *(u16x8*)&rk[q * 8];
    }
}

__global__ __launch_bounds__(256)
void fold_g(const float* __restrict__ O, const float* __restrict__ fk,
            const float* __restrict__ fq_b, const float* __restrict__ fk_b,
            float* __restrict__ g, float* __restrict__ h)
{
    __shared__ float fqqsh[256][21];
    __shared__ float fqbsh[256];
    __shared__ float red[3][64][7];
    const int b = blockIdx.y;
    const int tid = threadIdx.x;
    for (int idx = tid; idx < 256 * NS; idx += 256) {
        int kc = idx / NS, s = idx - kc * NS;
        fqqsh[kc][s] = O[((size_t)b * 768 + kc) * NS + s];
    }
    fqbsh[tid] = fq_b[tid];
    __syncthreads();
    const int wave = tid >> 6, lane = tid & 63;
    const int c = blockIdx.x * 64 + lane;
    float acc[21] = {};
    for (int i = 0; i < 64; ++i) {
        int kc = wave * 64 + i;
        float w = fk[(size_t)kc * NC + c];
        #pragma unroll
        for (int s = 0; s < NS; ++s) acc[s] += w * fqqsh[kc][s];
        acc[20] += w * fqbsh[kc];
    }
    #pragma unroll
    for (int r = 0; r < 3; ++r) {
        if (wave > 0) {
            #pragma unroll
            for (int k = 0; k < 7; ++k) red[wave - 1][lane][k] = acc[r * 7 + k];
        }
        __syncthreads();
        if (wave == 0) {
            #pragma unroll
            for (int k = 0; k < 7; ++k)
                acc[r * 7 + k] += red[0][lane][k] + red[1][lane][k] + red[2][lane][k];
        }
        __syncthreads();
    }
    if (wave == 0) {
        float* gp = &g[((size_t)b * NC + c) * 24];
        #pragma unroll
        for (int s = 0; s < 21; ++s) gp[s] = acc[s] * SCL;
        gp[21] = gp[22] = gp[23] = 0.f;
    }
    if (blockIdx.x == 0 && tid < 21) {
        float hh = 0.f;
        for (int kc = 0; kc < 256; ++kc)
            hh += fk_b[kc] * (tid < 20 ? fqqsh[kc][tid] : fqbsh[kc]);
        h[b * 24 + tid] = hh * SCL;
    }
}

extern "C" void kernel_launch(void* const* d_in, const int* in_sizes, int n_in,
                              void* d_out, int out_size, void* d_ws, size_t ws_size,
                              hipStream_t stream)
{
    const float* key   = (const float*)d_in[0];
    const float* query = (const float*)d_in[1];
    const int*   wid   = (const int*)d_in[2];
    const float* wv_w  = (const float*)d_in[3];
    const float* wv_b  = (const float*)d_in[4];
    const float* fk_w  = (const float*)d_in[5];
    const float* fk_b  = (const float*)d_in[6];
    const float* fq_w  = (const float*)d_in[7];
    const float* fq_b  = (const float*)d_in[8];
    const float* fv_w  = (const float*)d_in[9];
    const float* fv_b  = (const float*)d_in[10];
    const float* w1_w  = (const float*)d_in[11];
    const float* w1_b  = (const float*)d_in[12];
    const float* w2_w  = (const float*)d_in[13];
    const float* w2_b  = (const float*)d_in[14];
    float* out = (float*)d_out;

    char* p = (char*)d_ws;
    u16*   keyT   = (u16*)p;   p += (size_t)NB * NHW * NC * 2;    // 18.9 MB
    u8*    E8     = (u8*)p;    p += (size_t)NB * NHW * NHW;       // 42.5 MB
    u8*    vp8    = (u8*)p;    p += (size_t)NB * NC * NHW;        // 9.4 MB
    u16*   fvT    = (u16*)p;   p += (size_t)512 * 512 * 2;
    u16*   wc2b   = (u16*)p;   p += (size_t)512 * 512 * 2;
    u16*   wcv    = (u16*)p;   p += (size_t)512 * 512 * 2;
    u16*   attnwT = (u16*)p;   p += (size_t)NB * NHW * 32 * 2;
    u16*   ksb    = (u16*)p;   p += (size_t)NB * NHW * 32 * 2;
    float* attnw  = (float*)p; p += (size_t)NB * NS * NHW * 4;
    float* qw     = (float*)p; p += (size_t)NB * NS * NC * 4;
    float* qbuf   = (float*)p; p += (size_t)NB * NS * 4;
    float* Ofold  = (float*)p; p += (size_t)NB * 768 * NS * 4;
    float* g      = (float*)p; p += (size_t)NB * NC * 24 * 4;
    float* h      = (float*)p; p += (size_t)NB * 24 * 4;
    float* b2     = (float*)p; p += (size_t)512 * 4;
    float* Dpart  = (float*)p; p += (size_t)NB * 18 * NHW * 4;

    dim3 blk(256);

    transpose_gen<<<dim3(8, 8, 1), blk, 0, stream>>>(fv_w, fvT, 512, 512);
    make_wc2<<<dim3(512), blk, 0, stream>>>(w1_w, w1_b, w2_w, w2_b, fv_b, wc2b, b2);
    fold_query_wv<<<dim3(NS, NB), blk, 0, stream>>>(query, wv_w, wv_b, qw, qbuf);
    fold_wq<<<dim3(48, NB), blk, 0, stream>>>(query, fq_w, w1_w, Ofold);
    fold_g<<<dim3(8, NB), blk, 0, stream>>>(Ofold, fk_w, fq_b, fk_b, g, h);
    // fused key scan: word attention + ks logits + keyT transpose (one 75.5 MB read)
    scan_wk<<<dim3(36, NB), blk, 0, stream>>>(key, qw, qbuf, wid, g, h,
                                              attnw, attnwT, ksb, keyT);

    // wcv = wc2 @ fv  (512x512, K=512), bf16 out
    gemm_nt_bf16<<<dim3(4, 4, 1), blk, 0, stream>>>(
        wc2b, 0, 512, fvT, 0, 512, wcv, 0, 512, 512,
        nullptr, 0, 1.f, 0);
    // vproj = wcv @ keyT -> fp8 out (hardware cvt)
    gemm_nt_bf16<<<dim3(18, 4, NB), blk, 0, stream>>>(
        wcv, 0, 512, keyT, (long)NHW * 512, 512,
        vp8, (long)NC * NHW, NHW, 512,
        nullptr, 0, 1.f, 2);
    // E (fp8, hardware cvt) + partial row sums from rounded values
    e_gemm<<<dim3(18, 18, NB), blk, 0, stream>>>(attnwT, ksb, E8, Dpart);
    // PV fp8 BK=128 with low-rank accumulator init; grid 576, b = XCD
    pv_gemm<<<dim3(576), blk, 0, stream>>>(vp8, E8, Dpart, attnw, Ofold, b2, out);
}

// Round 21
// 238.471 us; speedup vs baseline: 1.1436x; 1.1436x over previous
//
#include <hip/hip_runtime.h>

#define NHW 2304
#define NB  8
#define NS  20
#define NC  512
#define SCL 0.09016844005555897f   // log2(e)/16

typedef unsigned short u16;
typedef unsigned char u8;
typedef short short8 __attribute__((ext_vector_type(8)));
typedef unsigned short u16x8 __attribute__((ext_vector_type(8)));
typedef u8 u8x16 __attribute__((ext_vector_type(16)));
typedef float f32x4 __attribute__((ext_vector_type(4)));

__device__ __forceinline__ float b2f(u16 u) {
    unsigned int v = ((unsigned int)u) << 16;
    return __builtin_bit_cast(float, v);
}
__device__ __forceinline__ u16 f2b(float f) {
    unsigned int u = __builtin_bit_cast(unsigned int, f);
    u += 0x7fffu + ((u >> 16) & 1u);
    return (u16)(u >> 16);
}

// ---- software fp8 e4m3fn fallback ----
__device__ __forceinline__ u8 f2e4_sw(float f) {
    unsigned int u = __builtin_bit_cast(unsigned int, f);
    u8 sign = (u >> 24) & 0x80;
    unsigned int a = u & 0x7FFFFFFFu;
    if (a >= 0x43E00000u) return sign | 0x7E;
    int e = (int)(a >> 23) - 127;
    unsigned int m = (a & 0x7FFFFF) | 0x800000;
    int ne = e + 7;
    if (ne <= 0) {
        int shift = 21 - ne;
        if (shift > 24) return sign;
        unsigned int q = m >> shift;
        unsigned int rem = m & ((1u << shift) - 1);
        unsigned int half = 1u << (shift - 1);
        q += (rem > half) || (rem == half && (q & 1));
        return sign | (u8)q;
    }
    unsigned int q = m >> 20;
    unsigned int rem = m & 0xFFFFFu;
    q += (rem > 0x80000u) || (rem == 0x80000u && (q & 1));
    if (q >= 16) { q >>= 1; ne++; }
    if (ne >= 16 || (ne == 15 && q == 15)) return sign | 0x7E;
    return sign | (u8)((ne << 3) | (q & 7));
}
__device__ __forceinline__ float e42f_sw(u8 v) {
    int e = (v >> 3) & 15;
    int m = v & 7;
    float r;
    if (e == 0) r = (float)m * 0.001953125f;
    else {
        unsigned int bits = ((unsigned int)(e + 120) << 23) | ((unsigned int)m << 20);
        r = __builtin_bit_cast(float, bits);
    }
    return (v & 0x80) ? -r : r;
}

// ---- hardware fp8 conversion (gfx950); hi/sel must be immediates ----
#if defined(__has_builtin)
#if __has_builtin(__builtin_amdgcn_cvt_pk_fp8_f32) && __has_builtin(__builtin_amdgcn_cvt_f32_fp8)
#define HW_FP8 1
#endif
#endif

template<bool HI>
__device__ __forceinline__ unsigned int pk2_fp8(float a, float b, unsigned int old) {
#ifdef HW_FP8
    return (unsigned int)__builtin_amdgcn_cvt_pk_fp8_f32(a, b, (int)old, HI);
#else
    unsigned int lo = (unsigned int)f2e4_sw(a) | ((unsigned int)f2e4_sw(b) << 8);
    return HI ? ((old & 0x0000FFFFu) | (lo << 16)) : ((old & 0xFFFF0000u) | lo);
#endif
}
#ifdef HW_FP8
#define DEC_FP8(w, sel) __builtin_amdgcn_cvt_f32_fp8((int)(w), (sel))
#else
#define DEC_FP8(w, sel) e42f_sw((u8)((w) >> (8 * (sel))))
#endif

__device__ __forceinline__ void load_lds16(const void* g, void* l) {
    __builtin_amdgcn_global_load_lds((const __attribute__((address_space(1))) void*)g,
                                     (__attribute__((address_space(3))) void*)l, 16, 0, 0);
}

// ---------------------------------------------------------------------------
// bf16 NT GEMM, 128x128 tile, BK=64, bank-swizzled LDS.
// out_mode: 0 bf16, 1 f32, 2 fp8
// ---------------------------------------------------------------------------
__global__ __launch_bounds__(256)
void gemm_nt_bf16(const u16* __restrict__ A, long As, int lda,
                  const u16* __restrict__ B, long Bs, int ldb,
                  void* __restrict__ C, long Cs, int ldc,
                  int K, const float* __restrict__ bias, int bias_mode,
                  float scale, int out_mode)
{
    __shared__ __align__(16) u16 sA[2 * 4096];
    __shared__ __align__(16) u16 sB[2 * 4096];
    const int tid   = threadIdx.x;
    const int b     = blockIdx.z;
    const int nBase = blockIdx.x * 128;
    const int mBase = blockIdx.y * 128;
    const u16* Ab = A + (size_t)b * As + (size_t)mBase * lda;
    const u16* Bb = B + (size_t)b * Bs + (size_t)nBase * ldb;
    const int lane = tid & 63;
    const int wave = tid >> 6;
    const int wr = wave >> 1, wc = wave & 1;
    const int srow[4] = { ((wave * 4 + 0) & 7) * 16 + (lane >> 2),
                          ((wave * 4 + 1) & 7) * 16 + (lane >> 2),
                          ((wave * 4 + 2) & 7) * 16 + (lane >> 2),
                          ((wave * 4 + 3) & 7) * 16 + (lane >> 2) };
    const int swzw = ((lane & 3) ^ ((lane >> 3) & 3)) * 8;
    const int rsw  = ((lane >> 4) ^ ((lane >> 1) & 3)) * 8;
    f32x4 acc[4][4] = {};
    for (int k0 = 0; k0 < K; k0 += 64) {
        __syncthreads();
        #pragma unroll
        for (int it = 0; it < 4; ++it) {
            const int chunk = wave * 4 + it;
            const int kofs = (chunk >> 3) * 32 + swzw;
            load_lds16(&Ab[(size_t)srow[it] * lda + k0 + kofs], &sA[chunk * 512 + lane * 8]);
            load_lds16(&Bb[(size_t)srow[it] * ldb + k0 + kofs], &sB[chunk * 512 + lane * 8]);
        }
        __syncthreads();
        #pragma unroll
        for (int kk = 0; kk < 2; ++kk) {
            short8 af[4], bg[4];
            #pragma unroll
            for (int i = 0; i < 4; ++i)
                af[i] = *(const short8*)&sA[kk * 4096 + (wr * 64 + i * 16 + (lane & 15)) * 32 + rsw];
            #pragma unroll
            for (int j = 0; j < 4; ++j)
                bg[j] = *(const short8*)&sB[kk * 4096 + (wc * 64 + j * 16 + (lane & 15)) * 32 + rsw];
            #pragma unroll
            for (int i = 0; i < 4; ++i)
                #pragma unroll
                for (int j = 0; j < 4; ++j)
                    acc[i][j] = __builtin_amdgcn_mfma_f32_16x16x32_bf16(af[i], bg[j], acc[i][j], 0, 0, 0);
        }
    }
    const int r0 = mBase + wr * 64 + (lane >> 4) * 4;
    const int c0 = nBase + wc * 64 + (lane & 15);
    #pragma unroll
    for (int i = 0; i < 4; ++i) {
        #pragma unroll
        for (int r = 0; r < 4; ++r) {
            const int row = r0 + i * 16 + r;
            const float br = (bias_mode == 1) ? bias[row] : 0.f;
            if (out_mode == 2) {
                float vv[4];
                #pragma unroll
                for (int j = 0; j < 4; ++j) vv[j] = acc[i][j][r] * scale + br;
                unsigned int w = 0;
                w = pk2_fp8<false>(vv[0], vv[1], w);
                w = pk2_fp8<true>(vv[2], vv[3], w);
                #pragma unroll
                for (int j = 0; j < 4; ++j)
                    ((u8*)C)[(size_t)b * Cs + (size_t)row * ldc + c0 + j * 16] = (u8)(w >> (8 * j));
            } else {
                #pragma unroll
                for (int j = 0; j < 4; ++j) {
                    const int col = c0 + j * 16;
                    float v = acc[i][j][r] * scale + br;
                    const size_t off = (size_t)b * Cs + (size_t)row * ldc + col;
                    if (out_mode == 1) ((float*)C)[off] = v;
                    else               ((u16*)C)[off] = f2b(v);
                }
            }
        }
    }
}

// ---------------------------------------------------------------------------
// E-GEMM: E8[n][m] = fp8(exp2(attnwT[n]·ks[m])); Dpart from ROUNDED values (HW cvt).
// ---------------------------------------------------------------------------
__global__ __launch_bounds__(256)
void e_gemm(const u16* __restrict__ attnwT, const u16* __restrict__ ks,
            u8* __restrict__ E8, float* __restrict__ Dpart)
{
    __shared__ __align__(16) u16 sA[128 * 32];
    __shared__ __align__(16) u16 sB[128 * 32];
    __shared__ __align__(16) u8 Etile[128 * 128];   // 16 KB, swizzled
    __shared__ float Dsh[2][128];
    const int tid = threadIdx.x;
    const int b = blockIdx.z;
    const int mt = blockIdx.x, nt = blockIdx.y;
    const int mBase = mt * 128, nBase = nt * 128;
    const u16* Ab = attnwT + ((size_t)b * NHW + nBase) * 32;
    const u16* Bb = ks     + ((size_t)b * NHW + mBase) * 32;
    const int lane = tid & 63;
    const int wave = tid >> 6;
    const int wr = wave >> 1, wc = wave & 1;
    const int str = tid >> 2;
    const int stk = (tid & 3) * 8;
    load_lds16(&Ab[(size_t)str * 32 + stk],        &sA[tid * 8]);
    load_lds16(&Ab[(size_t)(str + 64) * 32 + stk], &sA[2048 + tid * 8]);
    load_lds16(&Bb[(size_t)str * 32 + stk],        &sB[tid * 8]);
    load_lds16(&Bb[(size_t)(str + 64) * 32 + stk], &sB[2048 + tid * 8]);
    __syncthreads();
    short8 af[4], bg[4];
    #pragma unroll
    for (int i = 0; i < 4; ++i)
        af[i] = *(const short8*)&sA[(wr * 64 + i * 16 + (lane & 15)) * 32 + (lane >> 4) * 8];
    #pragma unroll
    for (int j = 0; j < 4; ++j)
        bg[j] = *(const short8*)&sB[(wc * 64 + j * 16 + (lane & 15)) * 32 + (lane >> 4) * 8];
    f32x4 acc[4][4] = {};
    #pragma unroll
    for (int i = 0; i < 4; ++i)
        #pragma unroll
        for (int j = 0; j < 4; ++j)
            acc[i][j] = __builtin_amdgcn_mfma_f32_16x16x32_bf16(af[i], bg[j], acc[i][j], 0, 0, 0);

    float dpart[16] = {};
    #pragma unroll
    for (int i = 0; i < 4; ++i) {
        #pragma unroll
        for (int r = 0; r < 4; ++r) {
            const int rowloc = wr * 64 + i * 16 + (lane >> 4) * 4 + r;
            unsigned int w = 0;
            w = pk2_fp8<false>(exp2f(acc[i][0][r]), exp2f(acc[i][1][r]), w);
            w = pk2_fp8<true>(exp2f(acc[i][2][r]), exp2f(acc[i][3][r]), w);
            dpart[i * 4 + r] += DEC_FP8(w, 0) + DEC_FP8(w, 1) + DEC_FP8(w, 2) + DEC_FP8(w, 3);
            #pragma unroll
            for (int j = 0; j < 4; ++j) {
                const int colloc = wc * 64 + j * 16 + (lane & 15);
                Etile[rowloc * 128 + (colloc ^ ((rowloc & 7) << 4))] = (u8)(w >> (8 * j));
            }
        }
    }
    #pragma unroll
    for (int mask = 1; mask < 16; mask <<= 1)
        #pragma unroll
        for (int k = 0; k < 16; ++k)
            dpart[k] += __shfl_xor(dpart[k], mask, 64);
    if ((lane & 15) == 0) {
        #pragma unroll
        for (int i = 0; i < 4; ++i)
            #pragma unroll
            for (int r = 0; r < 4; ++r)
                Dsh[wc][wr * 64 + i * 16 + (lane >> 4) * 4 + r] = dpart[i * 4 + r];
    }
    __syncthreads();
    if (tid < 128)
        Dpart[((size_t)(b * 18 + mt)) * NHW + nBase + tid] = Dsh[0][tid] + Dsh[1][tid];
    #pragma unroll
    for (int rep = 0; rep < 4; ++rep) {
        const int row = wave * 32 + rep * 8 + (lane >> 3);
        const int slot = lane & 7;
        u8x16 v = *(const u8x16*)&Etile[row * 128 + ((slot ^ (row & 7)) << 4)];
        *(u8x16*)&E8[((size_t)b * NHW + nBase + row) * NHW + mBase + slot * 16] = v;
    }
}

// ---------------------------------------------------------------------------
// PV GEMM fp8, 128x128 tile, BK=128, chunk-XOR swizzle c^=(row&7).
// out = (vp8·E8 + qp·(aw·Dsum)) * Dinv. Grid 576, b = XCD.
// ---------------------------------------------------------------------------
__global__ __launch_bounds__(256)
void pv_gemm(const u8* __restrict__ vp8, const u8* __restrict__ E8,
             const float* __restrict__ Dpart, const float* __restrict__ attnw,
             const float* __restrict__ Ofold, const float* __restrict__ b2,
             float* __restrict__ out)
{
    __shared__ __align__(16) u8 sA[16384];
    __shared__ __align__(16) u8 sB[16384];
    __shared__ float DsumSh[128];
    __shared__ float DinvSh[128];
    const int tid = threadIdx.x;
    const int bid = blockIdx.x;
    const int xcd = bid & 7, slot = bid >> 3;
    const int b = xcd;
    const int nt = slot >> 2;
    const int ot = slot & 3;
    const int oBase = ot * 128, nBase = nt * 128;

    const u8* A8 = vp8 + ((size_t)b * NC + oBase) * NHW;
    const u8* B8 = E8  + ((size_t)b * NHW + nBase) * NHW;
    const int lane = tid & 63;
    const int wave = tid >> 6;
    const int wr = wave >> 1, wc = wave & 1;

    int srowS[4], sgofS[4];
    #pragma unroll
    for (int it = 0; it < 4; ++it) {
        const int cd = (wave * 4 + it) * 64 + lane;
        srowS[it] = cd >> 3;
        sgofS[it] = ((cd & 7) ^ ((cd >> 3) & 7)) * 16;
    }
    #define PV_STAGE(k0) { \
        _Pragma("unroll") \
        for (int it = 0; it < 4; ++it) { \
            load_lds16(&A8[(size_t)srowS[it] * NHW + (k0) + sgofS[it]], &sA[((wave * 4 + it) * 64 + lane) * 16]); \
            load_lds16(&B8[(size_t)srowS[it] * NHW + (k0) + sgofS[it]], &sB[((wave * 4 + it) * 64 + lane) * 16]); \
        } }

    u16* sAh = (u16*)sA;
    u16* sBh = (u16*)sB;
    if (tid < 128) {
        float s = 0.f;
        #pragma unroll
        for (int mt = 0; mt < 18; ++mt)
            s += Dpart[((size_t)(b * 18 + mt)) * NHW + nBase + tid];
        DsumSh[tid] = s;
        DinvSh[tid] = 1.f / s;
    }
    for (int idx = tid; idx < 128 * 32; idx += 256) {
        const int o = idx >> 5, s = idx & 31;
        float v = 0.f;
        if (s < 20) v = Ofold[((size_t)b * 768 + 256 + oBase + o) * NS + s];
        else if (s == 20) v = b2[oBase + o];
        sAh[idx] = f2b(v);
    }
    __syncthreads();
    for (int idx = tid; idx < 128 * 32; idx += 256) {
        const int n = idx >> 5, s = idx & 31;
        float v = 0.f;
        if (s <= 20) {
            const float ds = DsumSh[n];
            v = (s < 20) ? attnw[((size_t)b * NS + s) * NHW + nBase + n] * ds : ds;
        }
        sBh[idx] = f2b(v);
    }
    __syncthreads();

    f32x4 acc[4][4];
    {
        const f32x4 zero = {0.f, 0.f, 0.f, 0.f};
        short8 qf[4], afr[4];
        #pragma unroll
        for (int i = 0; i < 4; ++i)
            qf[i] = *(const short8*)&sAh[(wr * 64 + i * 16 + (lane & 15)) * 32 + (lane >> 4) * 8];
        #pragma unroll
        for (int j = 0; j < 4; ++j)
            afr[j] = *(const short8*)&sBh[(wc * 64 + j * 16 + (lane & 15)) * 32 + (lane >> 4) * 8];
        #pragma unroll
        for (int i = 0; i < 4; ++i)
            #pragma unroll
            for (int j = 0; j < 4; ++j)
                acc[i][j] = __builtin_amdgcn_mfma_f32_16x16x32_bf16(qf[i], afr[j], zero, 0, 0, 0);
    }

    const int krow_a = wr * 64 + (lane & 15);
    const int krow_b = wc * 64 + (lane & 15);
    const int khalf = ((lane >> 4) & 1) * 8;
    const int kc2   = (lane >> 5);

    for (int k0 = 0; k0 < NHW; k0 += 128) {
        __syncthreads();
        PV_STAGE(k0);
        __syncthreads();
        #pragma unroll
        for (int kk = 0; kk < 4; ++kk) {
            long af[4], bg[4];
            #pragma unroll
            for (int i = 0; i < 4; ++i) {
                const int row = krow_a + i * 16;
                const int c = (kk * 2 + kc2) ^ (row & 7);
                af[i] = *(const long*)&sA[row * 128 + c * 16 + khalf];
            }
            #pragma unroll
            for (int j = 0; j < 4; ++j) {
                const int row = krow_b + j * 16;
                const int c = (kk * 2 + kc2) ^ (row & 7);
                bg[j] = *(const long*)&sB[row * 128 + c * 16 + khalf];
            }
            #pragma unroll
            for (int i = 0; i < 4; ++i)
                #pragma unroll
                for (int j = 0; j < 4; ++j)
                    acc[i][j] = __builtin_amdgcn_mfma_f32_16x16x32_fp8_fp8(af[i], bg[j], acc[i][j], 0, 0, 0);
        }
    }
    #pragma unroll
    for (int i = 0; i < 4; ++i) {
        #pragma unroll
        for (int r = 0; r < 4; ++r) {
            const int rowloc = wr * 64 + i * 16 + (lane >> 4) * 4 + r;
            #pragma unroll
            for (int j = 0; j < 4; ++j) {
                const int colloc = wc * 64 + j * 16 + (lane & 15);
                out[((size_t)b * NC + oBase + rowloc) * NHW + nBase + colloc] =
                    acc[i][j][r] * DinvSh[colloc];
            }
        }
    }
    #undef PV_STAGE
}

// src (batch, R, Cc) fp32 -> dst (batch, Cc, R) bf16
__global__ __launch_bounds__(256)
void transpose_gen(const float* __restrict__ src, u16* __restrict__ dst,
                   int R, int Cc)
{
    __shared__ u16 t[64][72];
    const int b = blockIdx.z;
    const int cBase = blockIdx.x * 64;
    const int rBase = blockIdx.y * 64;
    const int tid = threadIdx.x;
    const float* sb = src + ((size_t)b * R + rBase) * Cc + cBase;
    const int ln = tid & 63;
    const int lr = tid >> 6;
    #pragma unroll
    for (int rr = 0; rr < 16; ++rr) {
        int r = lr + rr * 4;
        t[r][ln] = f2b(sb[(size_t)r * Cc + ln]);
    }
    __syncthreads();
    u16* ob = dst + ((size_t)b * Cc + cBase) * R + rBase;
    #pragma unroll
    for (int rep = 0; rep < 2; ++rep) {
        int slot = rep * 256 + tid;
        int cc = slot >> 3;
        int r8 = (slot & 7) * 8;
        u16x8 v;
        #pragma unroll
        for (int e = 0; e < 8; ++e) v[e] = t[r8 + e][cc];
        *(u16x8*)&ob[(size_t)cc * R + r8] = v;
    }
}

__global__ __launch_bounds__(256)
void make_wc2(const float* __restrict__ w1, const float* __restrict__ w1b,
              const float* __restrict__ w2, const float* __restrict__ w2b,
              const float* __restrict__ fvb,
              u16* __restrict__ wc2b, float* __restrict__ b2)
{
    const int o = blockIdx.x;
    const int t = threadIdx.x;
    float part = 0.f;
    for (int c = t; c < 512; c += 256) {
        float v = w1[(size_t)o * 1024 + c] + w2[(size_t)o * 512 + c];
        wc2b[(size_t)o * 512 + c] = f2b(v);
        part += v * fvb[c];
    }
    #pragma unroll
    for (int off = 32; off > 0; off >>= 1) part += __shfl_down(part, off, 64);
    __shared__ float red[4];
    if ((t & 63) == 0) red[t >> 6] = part;
    __syncthreads();
    if (t == 0) b2[o] = (red[0] + red[1]) + (red[2] + red[3]) + w1b[o] + w2b[o];
}

__global__ __launch_bounds__(256)
void fold_query_wv(const float* __restrict__ query, const float* __restrict__ wv_w,
                   const float* __restrict__ wv_b,
                   float* __restrict__ qw, float* __restrict__ qb)
{
    __shared__ float qs[NC];
    const int b = blockIdx.y, s = blockIdx.x;
    const int tid = threadIdx.x;
    qs[tid] = query[((size_t)b * NS + s) * NC + tid];
    qs[tid + 256] = query[((size_t)b * NS + s) * NC + tid + 256];
    __syncthreads();
    float a0 = 0.f, a1 = 0.f;
    for (int o = 0; o < NC; ++o) {
        float qv = qs[o];
        a0 += qv * wv_w[(size_t)o * NC + tid];
        a1 += qv * wv_w[(size_t)o * NC + tid + 256];
    }
    qw[((size_t)b * NS + s) * NC + tid] = a0;
    qw[((size_t)b * NS + s) * NC + tid + 256] = a1;
    float pb = qs[tid] * wv_b[tid] + qs[tid + 256] * wv_b[tid + 256];
    #pragma unroll
    for (int off = 32; off > 0; off >>= 1) pb += __shfl_down(pb, off, 64);
    __shared__ float red[4];
    if ((tid & 63) == 0) red[tid >> 6] = pb;
    __syncthreads();
    if (tid == 0) qb[b * NS + s] = (red[0] + red[1]) + (red[2] + red[3]);
}

__global__ __launch_bounds__(256)
void fold_wq(const float* __restrict__ query, const float* __restrict__ fq,
             const float* __restrict__ w1, float* __restrict__ O)
{
    __shared__ float qsh[NS][NC];
    const int b = blockIdx.y;
    const int tid = threadIdx.x;
    for (int idx = tid; idx < NS * NC; idx += 256)
        qsh[idx >> 9][idx & 511] = query[(size_t)b * NS * NC + idx];
    __syncthreads();
    const int row = blockIdx.x * 16 + (tid >> 4);
    const int ct = tid & 15;
    const float* wp = (row < 256) ? &fq[(size_t)row * NC]
                                  : &w1[(size_t)(row - 256) * 1024 + 512];
    float acc[NS] = {};
    #pragma unroll 4
    for (int i = 0; i < 32; ++i) {
        int c = ct + i * 16;
        float w = wp[c];
        #pragma unroll
        for (int s = 0; s < NS; ++s) acc[s] += w * qsh[s][c];
    }
    #pragma unroll
    for (int off = 1; off < 16; off <<= 1)
        #pragma unroll
        for (int s = 0; s < NS; ++s) acc[s] += __shfl_xor(acc[s], off, 64);
    if (ct == 0) {
        #pragma unroll
        for (int s = 0; s < NS; ++s)
            O[((size_t)b * 768 + row) * NS + s] = acc[s];
    }
}

// ---------------------------------------------------------------------------
// Fused key scan: word-attn logits (fp32) AND ks logits in one pass over key.
// ---------------------------------------------------------------------------
__global__ __launch_bounds__(256)
void scan_wk(const float* __restrict__ key, const float* __restrict__ qw,
             const float* __restrict__ qb, const int* __restrict__ wid,
             const float* __restrict__ g, const float* __restrict__ h,
             float* __restrict__ attnw, u16* __restrict__ attnwT,
             u16* __restrict__ ks)
{
    __shared__ float qshT[NC][20];
    __shared__ u16 gshb[NC][22];
    __shared__ float red[3][64][7];
    __shared__ float msk[20], qbs[20], hsh[21];
    const int b = blockIdx.y;
    const int tid = threadIdx.x;
    const float* qwb = qw + (size_t)b * NS * NC;
    for (int idx = tid; idx < NC * 20; idx += 256) {
        int c = idx / 20, s = idx - c * 20;
        qshT[c][s] = qwb[s * NC + c];
    }
    for (int idx = tid; idx < NC * 21; idx += 256) {
        int c = idx / 21, s = idx - c * 21;
        gshb[c][s] = f2b(g[((size_t)b * NC + c) * 24 + s]);
    }
    if (tid < 20) {
        msk[tid] = (wid[b * NS + tid] != 0) ? 1.f : 0.f;
        qbs[tid] = qb[b * NS + tid];
    }
    if (tid < 21) hsh[tid] = h[b * 24 + tid];
    __syncthreads();
    const int wave = tid >> 6, lane = tid & 63;
    const int n = blockIdx.x * 64 + lane;
    const int cbase = wave * 128;
    const float* kp = key + (size_t)b * NC * NHW + n;
    float acc[41];
    #pragma unroll
    for (int s = 0; s < 41; ++s)
        acc[s] = (wave == 0) ? (s < 20 ? qbs[s] : hsh[s - 20]) : 0.f;
    #pragma unroll 4
    for (int ci = 0; ci < 128; ++ci) {
        const int c = cbase + ci;
        float kv = kp[(size_t)c * NHW];
        #pragma unroll
        for (int s = 0; s < 20; ++s) acc[s] += qshT[c][s] * kv;
        #pragma unroll
        for (int s = 0; s < 21; ++s) acc[20 + s] += b2f(gshb[c][s]) * kv;
    }
    #pragma unroll
    for (int r = 0; r < 6; ++r) {
        if (wave > 0) {
            #pragma unroll
            for (int k = 0; k < 7; ++k) {
                int idx = r * 7 + k;
                if (idx < 41) red[wave - 1][lane][k] = acc[idx];
            }
        }
        __syncthreads();
        if (wave == 0) {
            #pragma unroll
            for (int k = 0; k < 7; ++k) {
                int idx = r * 7 + k;
                if (idx < 41)
                    acc[idx] += red[0][lane][k] + red[1][lane][k] + red[2][lane][k];
            }
        }
        __syncthreads();
    }
    if (wave == 0) {
        float mx = acc[0];
        #pragma unroll
        for (int s = 1; s < 20; ++s) mx = fmaxf(mx, acc[s]);
        float msum = 0.f;
        #pragma unroll
        for (int s = 0; s < 20; ++s) {
            acc[s] = __expf(acc[s] - mx) * msk[s];
            msum += acc[s];
        }
        const float rr = 1.f / msum;
        u16 row32[32];
        #pragma unroll
        for (int s = 0; s < 20; ++s) {
            float a = acc[s] * rr;
            attnw[((size_t)b * NS + s) * NHW + n] = a;
            row32[s] = f2b(a);
        }
        row32[20] = 0x3F80;
        #pragma unroll
        for (int s = 21; s < 32; ++s) row32[s] = 0;
        u16* dp = attnwT + ((size_t)b * NHW + n) * 32;
        #pragma unroll
        for (int q = 0; q < 4; ++q)
            *(u16x8*)&dp[q * 8] = *(u16x8*)&row32[q * 8];
        u16 rk[32];
        #pragma unroll
        for (int s = 0; s < 21; ++s) rk[s] = f2b(acc[20 + s]);
        #pragma unroll
        for (int s = 21; s < 32; ++s) rk[s] = 0;
        u16* kp2 = ks + ((size_t)b * NHW + n) * 32;
        #pragma unroll
        for (int q = 0; q < 4; ++q)
            *(u16x8*)&kp2[q * 8] = *(u16x8*)&rk[q * 8];
    }
}

__global__ __launch_bounds__(256)
void fold_g(const float* __restrict__ O, const float* __restrict__ fk,
            const float* __restrict__ fq_b, const float* __restrict__ fk_b,
            float* __restrict__ g, float* __restrict__ h)
{
    __shared__ float fqqsh[256][21];
    __shared__ float fqbsh[256];
    __shared__ float red[3][64][7];
    const int b = blockIdx.y;
    const int tid = threadIdx.x;
    for (int idx = tid; idx < 256 * NS; idx += 256) {
        int kc = idx / NS, s = idx - kc * NS;
        fqqsh[kc][s] = O[((size_t)b * 768 + kc) * NS + s];
    }
    fqbsh[tid] = fq_b[tid];
    __syncthreads();
    const int wave = tid >> 6, lane = tid & 63;
    const int c = blockIdx.x * 64 + lane;
    float acc[21] = {};
    for (int i = 0; i < 64; ++i) {
        int kc = wave * 64 + i;
        float w = fk[(size_t)kc * NC + c];
        #pragma unroll
        for (int s = 0; s < NS; ++s) acc[s] += w * fqqsh[kc][s];
        acc[20] += w * fqbsh[kc];
    }
    #pragma unroll
    for (int r = 0; r < 3; ++r) {
        if (wave > 0) {
            #pragma unroll
            for (int k = 0; k < 7; ++k) red[wave - 1][lane][k] = acc[r * 7 + k];
        }
        __syncthreads();
        if (wave == 0) {
            #pragma unroll
            for (int k = 0; k < 7; ++k)
                acc[r * 7 + k] += red[0][lane][k] + red[1][lane][k] + red[2][lane][k];
        }
        __syncthreads();
    }
    if (wave == 0) {
        float* gp = &g[((size_t)b * NC + c) * 24];
        #pragma unroll
        for (int s = 0; s < 21; ++s) gp[s] = acc[s] * SCL;
        gp[21] = gp[22] = gp[23] = 0.f;
    }
    if (blockIdx.x == 0 && tid < 21) {
        float hh = 0.f;
        for (int kc = 0; kc < 256; ++kc)
            hh += fk_b[kc] * (tid < 20 ? fqqsh[kc][tid] : fqbsh[kc]);
        h[b * 24 + tid] = hh * SCL;
    }
}

extern "C" void kernel_launch(void* const* d_in, const int* in_sizes, int n_in,
                              void* d_out, int out_size, void* d_ws, size_t ws_size,
                              hipStream_t stream)
{
    const float* key   = (const float*)d_in[0];
    const float* query = (const float*)d_in[1];
    const int*   wid   = (const int*)d_in[2];
    const float* wv_w  = (const float*)d_in[3];
    const float* wv_b  = (const float*)d_in[4];
    const float* fk_w  = (const float*)d_in[5];
    const float* fk_b  = (const float*)d_in[6];
    const float* fq_w  = (const float*)d_in[7];
    const float* fq_b  = (const float*)d_in[8];
    const float* fv_w  = (const float*)d_in[9];
    const float* fv_b  = (const float*)d_in[10];
    const float* w1_w  = (const float*)d_in[11];
    const float* w1_b  = (const float*)d_in[12];
    const float* w2_w  = (const float*)d_in[13];
    const float* w2_b  = (const float*)d_in[14];
    float* out = (float*)d_out;

    char* p = (char*)d_ws;
    u16*   keyT   = (u16*)p;   p += (size_t)NB * NHW * NC * 2;    // 18.9 MB
    u8*    E8     = (u8*)p;    p += (size_t)NB * NHW * NHW;       // 42.5 MB
    u8*    vp8    = (u8*)p;    p += (size_t)NB * NC * NHW;        // 9.4 MB
    u16*   fvT    = (u16*)p;   p += (size_t)512 * 512 * 2;
    u16*   wc2b   = (u16*)p;   p += (size_t)512 * 512 * 2;
    u16*   wcv    = (u16*)p;   p += (size_t)512 * 512 * 2;
    u16*   attnwT = (u16*)p;   p += (size_t)NB * NHW * 32 * 2;
    u16*   ksb    = (u16*)p;   p += (size_t)NB * NHW * 32 * 2;
    float* attnw  = (float*)p; p += (size_t)NB * NS * NHW * 4;
    float* qw     = (float*)p; p += (size_t)NB * NS * NC * 4;
    float* qbuf   = (float*)p; p += (size_t)NB * NS * 4;
    float* Ofold  = (float*)p; p += (size_t)NB * 768 * NS * 4;
    float* g      = (float*)p; p += (size_t)NB * NC * 24 * 4;
    float* h      = (float*)p; p += (size_t)NB * 24 * 4;
    float* b2     = (float*)p; p += (size_t)512 * 4;
    float* Dpart  = (float*)p; p += (size_t)NB * 18 * NHW * 4;

    dim3 blk(256);

    transpose_gen<<<dim3(36, 8, NB), blk, 0, stream>>>(key, keyT, NC, NHW);
    transpose_gen<<<dim3(8, 8, 1), blk, 0, stream>>>(fv_w, fvT, 512, 512);
    make_wc2<<<dim3(512), blk, 0, stream>>>(w1_w, w1_b, w2_w, w2_b, fv_b, wc2b, b2);
    fold_query_wv<<<dim3(NS, NB), blk, 0, stream>>>(query, wv_w, wv_b, qw, qbuf);
    fold_wq<<<dim3(48, NB), blk, 0, stream>>>(query, fq_w, w1_w, Ofold);
    fold_g<<<dim3(8, NB), blk, 0, stream>>>(Ofold, fk_w, fq_b, fk_b, g, h);
    scan_wk<<<dim3(36, NB), blk, 0, stream>>>(key, qw, qbuf, wid, g, h,
                                              attnw, attnwT, ksb);

    // wcv = wc2 @ fv  (512x512, K=512), bf16 out
    gemm_nt_bf16<<<dim3(4, 4, 1), blk, 0, stream>>>(
        wc2b, 0, 512, fvT, 0, 512, wcv, 0, 512, 512,
        nullptr, 0, 1.f, 0);
    // vproj = wcv @ keyT -> fp8 out (hardware cvt)
    gemm_nt_bf16<<<dim3(18, 4, NB), blk, 0, stream>>>(
        wcv, 0, 512, keyT, (long)NHW * 512, 512,
        vp8, (long)NC * NHW, NHW, 512,
        nullptr, 0, 1.f, 2);
    // E (fp8, hardware cvt) + partial row sums from rounded values
    e_gemm<<<dim3(18, 18, NB), blk, 0, stream>>>(attnwT, ksb, E8, Dpart);
    // PV fp8 BK=128 with low-rank accumulator init; grid 576, b = XCD
    pv_gemm<<<dim3(576), blk, 0, stream>>>(vp8, E8, Dpart, attnw, Ofold, b2, out);
}

// Round 22
// 215.305 us; speedup vs baseline: 1.2666x; 1.1076x over previous
//
#include <hip/hip_runtime.h>

#define NHW 2304
#define NB  8
#define NS  20
#define NC  512
#define SCL 0.09016844005555897f   // log2(e)/16

typedef unsigned short u16;
typedef unsigned char u8;
typedef short short8 __attribute__((ext_vector_type(8)));
typedef unsigned short u16x8 __attribute__((ext_vector_type(8)));
typedef u8 u8x16 __attribute__((ext_vector_type(16)));
typedef float f32x4 __attribute__((ext_vector_type(4)));

__device__ __forceinline__ float b2f(u16 u) {
    unsigned int v = ((unsigned int)u) << 16;
    return __builtin_bit_cast(float, v);
}
__device__ __forceinline__ u16 f2b(float f) {
    unsigned int u = __builtin_bit_cast(unsigned int, f);
    u += 0x7fffu + ((u >> 16) & 1u);
    return (u16)(u >> 16);
}

// ---- software fp8 e4m3fn fallback ----
__device__ __forceinline__ u8 f2e4_sw(float f) {
    unsigned int u = __builtin_bit_cast(unsigned int, f);
    u8 sign = (u >> 24) & 0x80;
    unsigned int a = u & 0x7FFFFFFFu;
    if (a >= 0x43E00000u) return sign | 0x7E;
    int e = (int)(a >> 23) - 127;
    unsigned int m = (a & 0x7FFFFF) | 0x800000;
    int ne = e + 7;
    if (ne <= 0) {
        int shift = 21 - ne;
        if (shift > 24) return sign;
        unsigned int q = m >> shift;
        unsigned int rem = m & ((1u << shift) - 1);
        unsigned int half = 1u << (shift - 1);
        q += (rem > half) || (rem == half && (q & 1));
        return sign | (u8)q;
    }
    unsigned int q = m >> 20;
    unsigned int rem = m & 0xFFFFFu;
    q += (rem > 0x80000u) || (rem == 0x80000u && (q & 1));
    if (q >= 16) { q >>= 1; ne++; }
    if (ne >= 16 || (ne == 15 && q == 15)) return sign | 0x7E;
    return sign | (u8)((ne << 3) | (q & 7));
}
__device__ __forceinline__ float e42f_sw(u8 v) {
    int e = (v >> 3) & 15;
    int m = v & 7;
    float r;
    if (e == 0) r = (float)m * 0.001953125f;
    else {
        unsigned int bits = ((unsigned int)(e + 120) << 23) | ((unsigned int)m << 20);
        r = __builtin_bit_cast(float, bits);
    }
    return (v & 0x80) ? -r : r;
}

// ---- hardware fp8 conversion (gfx950); hi/sel must be immediates ----
#if defined(__has_builtin)
#if __has_builtin(__builtin_amdgcn_cvt_pk_fp8_f32) && __has_builtin(__builtin_amdgcn_cvt_f32_fp8)
#define HW_FP8 1
#endif
#endif

template<bool HI>
__device__ __forceinline__ unsigned int pk2_fp8(float a, float b, unsigned int old) {
#ifdef HW_FP8
    return (unsigned int)__builtin_amdgcn_cvt_pk_fp8_f32(a, b, (int)old, HI);
#else
    unsigned int lo = (unsigned int)f2e4_sw(a) | ((unsigned int)f2e4_sw(b) << 8);
    return HI ? ((old & 0x0000FFFFu) | (lo << 16)) : ((old & 0xFFFF0000u) | lo);
#endif
}
#ifdef HW_FP8
#define DEC_FP8(w, sel) __builtin_amdgcn_cvt_f32_fp8((int)(w), (sel))
#else
#define DEC_FP8(w, sel) e42f_sw((u8)((w) >> (8 * (sel))))
#endif

__device__ __forceinline__ void load_lds16(const void* g, void* l) {
    __builtin_amdgcn_global_load_lds((const __attribute__((address_space(1))) void*)g,
                                     (__attribute__((address_space(3))) void*)l, 16, 0, 0);
}

// ---------------------------------------------------------------------------
// bf16 NT GEMM, 128x128 tile, BK=64, bank-swizzled LDS.
// out_mode: 0 bf16, 1 f32, 2 fp8
// ---------------------------------------------------------------------------
__global__ __launch_bounds__(256)
void gemm_nt_bf16(const u16* __restrict__ A, long As, int lda,
                  const u16* __restrict__ B, long Bs, int ldb,
                  void* __restrict__ C, long Cs, int ldc,
                  int K, const float* __restrict__ bias, int bias_mode,
                  float scale, int out_mode)
{
    __shared__ __align__(16) u16 sA[2 * 4096];
    __shared__ __align__(16) u16 sB[2 * 4096];
    const int tid   = threadIdx.x;
    const int b     = blockIdx.z;
    const int nBase = blockIdx.x * 128;
    const int mBase = blockIdx.y * 128;
    const u16* Ab = A + (size_t)b * As + (size_t)mBase * lda;
    const u16* Bb = B + (size_t)b * Bs + (size_t)nBase * ldb;
    const int lane = tid & 63;
    const int wave = tid >> 6;
    const int wr = wave >> 1, wc = wave & 1;
    const int srow[4] = { ((wave * 4 + 0) & 7) * 16 + (lane >> 2),
                          ((wave * 4 + 1) & 7) * 16 + (lane >> 2),
                          ((wave * 4 + 2) & 7) * 16 + (lane >> 2),
                          ((wave * 4 + 3) & 7) * 16 + (lane >> 2) };
    const int swzw = ((lane & 3) ^ ((lane >> 3) & 3)) * 8;
    const int rsw  = ((lane >> 4) ^ ((lane >> 1) & 3)) * 8;
    f32x4 acc[4][4] = {};
    for (int k0 = 0; k0 < K; k0 += 64) {
        __syncthreads();
        #pragma unroll
        for (int it = 0; it < 4; ++it) {
            const int chunk = wave * 4 + it;
            const int kofs = (chunk >> 3) * 32 + swzw;
            load_lds16(&Ab[(size_t)srow[it] * lda + k0 + kofs], &sA[chunk * 512 + lane * 8]);
            load_lds16(&Bb[(size_t)srow[it] * ldb + k0 + kofs], &sB[chunk * 512 + lane * 8]);
        }
        __syncthreads();
        #pragma unroll
        for (int kk = 0; kk < 2; ++kk) {
            short8 af[4], bg[4];
            #pragma unroll
            for (int i = 0; i < 4; ++i)
                af[i] = *(const short8*)&sA[kk * 4096 + (wr * 64 + i * 16 + (lane & 15)) * 32 + rsw];
            #pragma unroll
            for (int j = 0; j < 4; ++j)
                bg[j] = *(const short8*)&sB[kk * 4096 + (wc * 64 + j * 16 + (lane & 15)) * 32 + rsw];
            #pragma unroll
            for (int i = 0; i < 4; ++i)
                #pragma unroll
                for (int j = 0; j < 4; ++j)
                    acc[i][j] = __builtin_amdgcn_mfma_f32_16x16x32_bf16(af[i], bg[j], acc[i][j], 0, 0, 0);
        }
    }
    const int r0 = mBase + wr * 64 + (lane >> 4) * 4;
    const int c0 = nBase + wc * 64 + (lane & 15);
    #pragma unroll
    for (int i = 0; i < 4; ++i) {
        #pragma unroll
        for (int r = 0; r < 4; ++r) {
            const int row = r0 + i * 16 + r;
            const float br = (bias_mode == 1) ? bias[row] : 0.f;
            if (out_mode == 2) {
                float vv[4];
                #pragma unroll
                for (int j = 0; j < 4; ++j) vv[j] = acc[i][j][r] * scale + br;
                unsigned int w = 0;
                w = pk2_fp8<false>(vv[0], vv[1], w);
                w = pk2_fp8<true>(vv[2], vv[3], w);
                #pragma unroll
                for (int j = 0; j < 4; ++j)
                    ((u8*)C)[(size_t)b * Cs + (size_t)row * ldc + c0 + j * 16] = (u8)(w >> (8 * j));
            } else {
                #pragma unroll
                for (int j = 0; j < 4; ++j) {
                    const int col = c0 + j * 16;
                    float v = acc[i][j][r] * scale + br;
                    const size_t off = (size_t)b * Cs + (size_t)row * ldc + col;
                    if (out_mode == 1) ((float*)C)[off] = v;
                    else               ((u16*)C)[off] = f2b(v);
                }
            }
        }
    }
}

// ---------------------------------------------------------------------------
// E-GEMM: E8[n][m] = fp8(exp2(attnwT[n]·ks[m])); Dpart from ROUNDED values (HW cvt).
// ---------------------------------------------------------------------------
__global__ __launch_bounds__(256)
void e_gemm(const u16* __restrict__ attnwT, const u16* __restrict__ ks,
            u8* __restrict__ E8, float* __restrict__ Dpart)
{
    __shared__ __align__(16) u16 sA[128 * 32];
    __shared__ __align__(16) u16 sB[128 * 32];
    __shared__ __align__(16) u8 Etile[128 * 128];   // 16 KB, swizzled
    __shared__ float Dsh[2][128];
    const int tid = threadIdx.x;
    const int b = blockIdx.z;
    const int mt = blockIdx.x, nt = blockIdx.y;
    const int mBase = mt * 128, nBase = nt * 128;
    const u16* Ab = attnwT + ((size_t)b * NHW + nBase) * 32;
    const u16* Bb = ks     + ((size_t)b * NHW + mBase) * 32;
    const int lane = tid & 63;
    const int wave = tid >> 6;
    const int wr = wave >> 1, wc = wave & 1;
    const int str = tid >> 2;
    const int stk = (tid & 3) * 8;
    load_lds16(&Ab[(size_t)str * 32 + stk],        &sA[tid * 8]);
    load_lds16(&Ab[(size_t)(str + 64) * 32 + stk], &sA[2048 + tid * 8]);
    load_lds16(&Bb[(size_t)str * 32 + stk],        &sB[tid * 8]);
    load_lds16(&Bb[(size_t)(str + 64) * 32 + stk], &sB[2048 + tid * 8]);
    __syncthreads();
    short8 af[4], bg[4];
    #pragma unroll
    for (int i = 0; i < 4; ++i)
        af[i] = *(const short8*)&sA[(wr * 64 + i * 16 + (lane & 15)) * 32 + (lane >> 4) * 8];
    #pragma unroll
    for (int j = 0; j < 4; ++j)
        bg[j] = *(const short8*)&sB[(wc * 64 + j * 16 + (lane & 15)) * 32 + (lane >> 4) * 8];
    f32x4 acc[4][4] = {};
    #pragma unroll
    for (int i = 0; i < 4; ++i)
        #pragma unroll
        for (int j = 0; j < 4; ++j)
            acc[i][j] = __builtin_amdgcn_mfma_f32_16x16x32_bf16(af[i], bg[j], acc[i][j], 0, 0, 0);

    float dpart[16] = {};
    #pragma unroll
    for (int i = 0; i < 4; ++i) {
        #pragma unroll
        for (int r = 0; r < 4; ++r) {
            const int rowloc = wr * 64 + i * 16 + (lane >> 4) * 4 + r;
            unsigned int w = 0;
            w = pk2_fp8<false>(exp2f(acc[i][0][r]), exp2f(acc[i][1][r]), w);
            w = pk2_fp8<true>(exp2f(acc[i][2][r]), exp2f(acc[i][3][r]), w);
            dpart[i * 4 + r] += DEC_FP8(w, 0) + DEC_FP8(w, 1) + DEC_FP8(w, 2) + DEC_FP8(w, 3);
            #pragma unroll
            for (int j = 0; j < 4; ++j) {
                const int colloc = wc * 64 + j * 16 + (lane & 15);
                Etile[rowloc * 128 + (colloc ^ ((rowloc & 7) << 4))] = (u8)(w >> (8 * j));
            }
        }
    }
    #pragma unroll
    for (int mask = 1; mask < 16; mask <<= 1)
        #pragma unroll
        for (int k = 0; k < 16; ++k)
            dpart[k] += __shfl_xor(dpart[k], mask, 64);
    if ((lane & 15) == 0) {
        #pragma unroll
        for (int i = 0; i < 4; ++i)
            #pragma unroll
            for (int r = 0; r < 4; ++r)
                Dsh[wc][wr * 64 + i * 16 + (lane >> 4) * 4 + r] = dpart[i * 4 + r];
    }
    __syncthreads();
    if (tid < 128)
        Dpart[((size_t)(b * 18 + mt)) * NHW + nBase + tid] = Dsh[0][tid] + Dsh[1][tid];
    #pragma unroll
    for (int rep = 0; rep < 4; ++rep) {
        const int row = wave * 32 + rep * 8 + (lane >> 3);
        const int slot = lane & 7;
        u8x16 v = *(const u8x16*)&Etile[row * 128 + ((slot ^ (row & 7)) << 4)];
        *(u8x16*)&E8[((size_t)b * NHW + nBase + row) * NHW + mBase + slot * 16] = v;
    }
}

// ---------------------------------------------------------------------------
// PV GEMM fp8, 128x128 tile, BK=128, chunk-XOR swizzle c^=(row&7).
// out = (vp8·E8 + qp·(aw·Dsum)) * Dinv. Grid 576, b = XCD.
// ---------------------------------------------------------------------------
__global__ __launch_bounds__(256)
void pv_gemm(const u8* __restrict__ vp8, const u8* __restrict__ E8,
             const float* __restrict__ Dpart, const float* __restrict__ attnw,
             const float* __restrict__ Ofold, const float* __restrict__ b2,
             float* __restrict__ out)
{
    __shared__ __align__(16) u8 sA[16384];
    __shared__ __align__(16) u8 sB[16384];
    __shared__ float DsumSh[128];
    __shared__ float DinvSh[128];
    const int tid = threadIdx.x;
    const int bid = blockIdx.x;
    const int xcd = bid & 7, slot = bid >> 3;
    const int b = xcd;
    const int nt = slot >> 2;
    const int ot = slot & 3;
    const int oBase = ot * 128, nBase = nt * 128;

    const u8* A8 = vp8 + ((size_t)b * NC + oBase) * NHW;
    const u8* B8 = E8  + ((size_t)b * NHW + nBase) * NHW;
    const int lane = tid & 63;
    const int wave = tid >> 6;
    const int wr = wave >> 1, wc = wave & 1;

    int srowS[4], sgofS[4];
    #pragma unroll
    for (int it = 0; it < 4; ++it) {
        const int cd = (wave * 4 + it) * 64 + lane;
        srowS[it] = cd >> 3;
        sgofS[it] = ((cd & 7) ^ ((cd >> 3) & 7)) * 16;
    }
    #define PV_STAGE(k0) { \
        _Pragma("unroll") \
        for (int it = 0; it < 4; ++it) { \
            load_lds16(&A8[(size_t)srowS[it] * NHW + (k0) + sgofS[it]], &sA[((wave * 4 + it) * 64 + lane) * 16]); \
            load_lds16(&B8[(size_t)srowS[it] * NHW + (k0) + sgofS[it]], &sB[((wave * 4 + it) * 64 + lane) * 16]); \
        } }

    u16* sAh = (u16*)sA;
    u16* sBh = (u16*)sB;
    if (tid < 128) {
        float s = 0.f;
        #pragma unroll
        for (int mt = 0; mt < 18; ++mt)
            s += Dpart[((size_t)(b * 18 + mt)) * NHW + nBase + tid];
        DsumSh[tid] = s;
        DinvSh[tid] = 1.f / s;
    }
    for (int idx = tid; idx < 128 * 32; idx += 256) {
        const int o = idx >> 5, s = idx & 31;
        float v = 0.f;
        if (s < 20) v = Ofold[((size_t)b * 768 + 256 + oBase + o) * NS + s];
        else if (s == 20) v = b2[oBase + o];
        sAh[idx] = f2b(v);
    }
    __syncthreads();
    for (int idx = tid; idx < 128 * 32; idx += 256) {
        const int n = idx >> 5, s = idx & 31;
        float v = 0.f;
        if (s <= 20) {
            const float ds = DsumSh[n];
            v = (s < 20) ? attnw[((size_t)b * NS + s) * NHW + nBase + n] * ds : ds;
        }
        sBh[idx] = f2b(v);
    }
    __syncthreads();

    f32x4 acc[4][4];
    {
        const f32x4 zero = {0.f, 0.f, 0.f, 0.f};
        short8 qf[4], afr[4];
        #pragma unroll
        for (int i = 0; i < 4; ++i)
            qf[i] = *(const short8*)&sAh[(wr * 64 + i * 16 + (lane & 15)) * 32 + (lane >> 4) * 8];
        #pragma unroll
        for (int j = 0; j < 4; ++j)
            afr[j] = *(const short8*)&sBh[(wc * 64 + j * 16 + (lane & 15)) * 32 + (lane >> 4) * 8];
        #pragma unroll
        for (int i = 0; i < 4; ++i)
            #pragma unroll
            for (int j = 0; j < 4; ++j)
                acc[i][j] = __builtin_amdgcn_mfma_f32_16x16x32_bf16(qf[i], afr[j], zero, 0, 0, 0);
    }

    const int krow_a = wr * 64 + (lane & 15);
    const int krow_b = wc * 64 + (lane & 15);
    const int khalf = ((lane >> 4) & 1) * 8;
    const int kc2   = (lane >> 5);

    for (int k0 = 0; k0 < NHW; k0 += 128) {
        __syncthreads();
        PV_STAGE(k0);
        __syncthreads();
        #pragma unroll
        for (int kk = 0; kk < 4; ++kk) {
            long af[4], bg[4];
            #pragma unroll
            for (int i = 0; i < 4; ++i) {
                const int row = krow_a + i * 16;
                const int c = (kk * 2 + kc2) ^ (row & 7);
                af[i] = *(const long*)&sA[row * 128 + c * 16 + khalf];
            }
            #pragma unroll
            for (int j = 0; j < 4; ++j) {
                const int row = krow_b + j * 16;
                const int c = (kk * 2 + kc2) ^ (row & 7);
                bg[j] = *(const long*)&sB[row * 128 + c * 16 + khalf];
            }
            #pragma unroll
            for (int i = 0; i < 4; ++i)
                #pragma unroll
                for (int j = 0; j < 4; ++j)
                    acc[i][j] = __builtin_amdgcn_mfma_f32_16x16x32_fp8_fp8(af[i], bg[j], acc[i][j], 0, 0, 0);
        }
    }
    #pragma unroll
    for (int i = 0; i < 4; ++i) {
        #pragma unroll
        for (int r = 0; r < 4; ++r) {
            const int rowloc = wr * 64 + i * 16 + (lane >> 4) * 4 + r;
            #pragma unroll
            for (int j = 0; j < 4; ++j) {
                const int colloc = wc * 64 + j * 16 + (lane & 15);
                out[((size_t)b * NC + oBase + rowloc) * NHW + nBase + colloc] =
                    acc[i][j][r] * DinvSh[colloc];
            }
        }
    }
    #undef PV_STAGE
}

// ---------------------------------------------------------------------------
// prep_all: fused independent prep work, branch on blockIdx range.
//   [0, 2304):      key (B,512,2304) f32 -> keyT (B,2304,512) bf16
//   [2304, 2368):   fv_w (512,512) f32 -> fvT (512,512) bf16
//   [2368, 2880):   wc2 = w1[:,:512]+w2 -> bf16; b2
//   [2880, 3040):   qw = query@wv_w; qb = query.wv_b
//   [3040, 3424):   Ofold rows (fq | w1[:,512:]) . query
// ---------------------------------------------------------------------------
__global__ __launch_bounds__(256)
void prep_all(const float* __restrict__ key, u16* __restrict__ keyT,
              const float* __restrict__ fv_w, u16* __restrict__ fvT,
              const float* __restrict__ w1, const float* __restrict__ w1b,
              const float* __restrict__ w2, const float* __restrict__ w2b,
              const float* __restrict__ fvb, u16* __restrict__ wc2b,
              float* __restrict__ b2,
              const float* __restrict__ query, const float* __restrict__ wv_w,
              const float* __restrict__ wv_b, float* __restrict__ qw,
              float* __restrict__ qb,
              const float* __restrict__ fq, float* __restrict__ O)
{
    __shared__ __align__(16) char smem[44032];
    const int bid = blockIdx.x;
    const int tid = threadIdx.x;

    if (bid < 2368) {
        // ---- transpose branch (key or fv) ----
        const float* src; u16* dst; int R, Cc, cBase, rBase, b;
        if (bid < 2304) {
            src = key; dst = keyT; R = NC; Cc = NHW;
            cBase = (bid % 36) * 64; rBase = ((bid / 36) % 8) * 64; b = bid / 288;
        } else {
            const int t2 = bid - 2304;
            src = fv_w; dst = fvT; R = 512; Cc = 512;
            cBase = (t2 % 8) * 64; rBase = (t2 / 8) * 64; b = 0;
        }
        u16 (*t)[72] = (u16(*)[72])smem;
        const float* sb = src + ((size_t)b * R + rBase) * Cc + cBase;
        const int ln = tid & 63;
        const int lr = tid >> 6;
        #pragma unroll
        for (int rr = 0; rr < 16; ++rr) {
            int r = lr + rr * 4;
            t[r][ln] = f2b(sb[(size_t)r * Cc + ln]);
        }
        __syncthreads();
        u16* ob = dst + ((size_t)b * Cc + cBase) * R + rBase;
        #pragma unroll
        for (int rep = 0; rep < 2; ++rep) {
            int slot = rep * 256 + tid;
            int cc = slot >> 3;
            int r8 = (slot & 7) * 8;
            u16x8 v;
            #pragma unroll
            for (int e = 0; e < 8; ++e) v[e] = t[r8 + e][cc];
            *(u16x8*)&ob[(size_t)cc * R + r8] = v;
        }
    } else if (bid < 2880) {
        // ---- make_wc2 ----
        const int o = bid - 2368;
        float* red = (float*)smem;
        float part = 0.f;
        for (int c = tid; c < 512; c += 256) {
            float v = w1[(size_t)o * 1024 + c] + w2[(size_t)o * 512 + c];
            wc2b[(size_t)o * 512 + c] = f2b(v);
            part += v * fvb[c];
        }
        #pragma unroll
        for (int off = 32; off > 0; off >>= 1) part += __shfl_down(part, off, 64);
        if ((tid & 63) == 0) red[tid >> 6] = part;
        __syncthreads();
        if (tid == 0) b2[o] = (red[0] + red[1]) + (red[2] + red[3]) + w1b[o] + w2b[o];
    } else if (bid < 3040) {
        // ---- fold_query_wv ----
        const int t3 = bid - 2880;
        const int s = t3 % NS, b = t3 / NS;
        float* qs  = (float*)smem;            // 512 floats
        float* red = qs + 512;                // 4 floats
        qs[tid] = query[((size_t)b * NS + s) * NC + tid];
        qs[tid + 256] = query[((size_t)b * NS + s) * NC + tid + 256];
        __syncthreads();
        float a0 = 0.f, a1 = 0.f;
        for (int o = 0; o < NC; ++o) {
            float qv = qs[o];
            a0 += qv * wv_w[(size_t)o * NC + tid];
            a1 += qv * wv_w[(size_t)o * NC + tid + 256];
        }
        qw[((size_t)b * NS + s) * NC + tid] = a0;
        qw[((size_t)b * NS + s) * NC + tid + 256] = a1;
        float pb = qs[tid] * wv_b[tid] + qs[tid + 256] * wv_b[tid + 256];
        #pragma unroll
        for (int off = 32; off > 0; off >>= 1) pb += __shfl_down(pb, off, 64);
        if ((tid & 63) == 0) red[tid >> 6] = pb;
        __syncthreads();
        if (tid == 0) qb[b * NS + s] = (red[0] + red[1]) + (red[2] + red[3]);
    } else {
        // ---- fold_wq ----
        const int t4 = bid - 3040;
        const int x = t4 % 48, b = t4 / 48;
        float (*qsh)[NC] = (float(*)[NC])smem;   // [20][512] = 40960 B
        for (int idx = tid; idx < NS * NC; idx += 256)
            qsh[idx >> 9][idx & 511] = query[(size_t)b * NS * NC + idx];
        __syncthreads();
        const int row = x * 16 + (tid >> 4);
        const int ct = tid & 15;
        const float* wp = (row < 256) ? &fq[(size_t)row * NC]
                                      : &w1[(size_t)(row - 256) * 1024 + 512];
        float acc[NS] = {};
        #pragma unroll 4
        for (int i = 0; i < 32; ++i) {
            int c = ct + i * 16;
            float w = wp[c];
            #pragma unroll
            for (int s = 0; s < NS; ++s) acc[s] += w * qsh[s][c];
        }
        #pragma unroll
        for (int off = 1; off < 16; off <<= 1)
            #pragma unroll
            for (int s = 0; s < NS; ++s) acc[s] += __shfl_xor(acc[s], off, 64);
        if (ct == 0) {
            #pragma unroll
            for (int s = 0; s < NS; ++s)
                O[((size_t)b * 768 + row) * NS + s] = acc[s];
        }
    }
}

// ---------------------------------------------------------------------------
// Fused key scan: word-attn logits (fp32) AND ks logits in one pass over key.
// ---------------------------------------------------------------------------
__global__ __launch_bounds__(256)
void scan_wk(const float* __restrict__ key, const float* __restrict__ qw,
             const float* __restrict__ qb, const int* __restrict__ wid,
             const float* __restrict__ g, const float* __restrict__ h,
             float* __restrict__ attnw, u16* __restrict__ attnwT,
             u16* __restrict__ ks)
{
    __shared__ float qshT[NC][20];
    __shared__ u16 gshb[NC][22];
    __shared__ float red[3][64][7];
    __shared__ float msk[20], qbs[20], hsh[21];
    const int b = blockIdx.y;
    const int tid = threadIdx.x;
    const float* qwb = qw + (size_t)b * NS * NC;
    for (int idx = tid; idx < NC * 20; idx += 256) {
        int c = idx / 20, s = idx - c * 20;
        qshT[c][s] = qwb[s * NC + c];
    }
    for (int idx = tid; idx < NC * 21; idx += 256) {
        int c = idx / 21, s = idx - c * 21;
        gshb[c][s] = f2b(g[((size_t)b * NC + c) * 24 + s]);
    }
    if (tid < 20) {
        msk[tid] = (wid[b * NS + tid] != 0) ? 1.f : 0.f;
        qbs[tid] = qb[b * NS + tid];
    }
    if (tid < 21) hsh[tid] = h[b * 24 + tid];
    __syncthreads();
    const int wave = tid >> 6, lane = tid & 63;
    const int n = blockIdx.x * 64 + lane;
    const int cbase = wave * 128;
    const float* kp = key + (size_t)b * NC * NHW + n;
    float acc[41];
    #pragma unroll
    for (int s = 0; s < 41; ++s)
        acc[s] = (wave == 0) ? (s < 20 ? qbs[s] : hsh[s - 20]) : 0.f;
    #pragma unroll 4
    for (int ci = 0; ci < 128; ++ci) {
        const int c = cbase + ci;
        float kv = kp[(size_t)c * NHW];
        #pragma unroll
        for (int s = 0; s < 20; ++s) acc[s] += qshT[c][s] * kv;
        #pragma unroll
        for (int s = 0; s < 21; ++s) acc[20 + s] += b2f(gshb[c][s]) * kv;
    }
    #pragma unroll
    for (int r = 0; r < 6; ++r) {
        if (wave > 0) {
            #pragma unroll
            for (int k = 0; k < 7; ++k) {
                int idx = r * 7 + k;
                if (idx < 41) red[wave - 1][lane][k] = acc[idx];
            }
        }
        __syncthreads();
        if (wave == 0) {
            #pragma unroll
            for (int k = 0; k < 7; ++k) {
                int idx = r * 7 + k;
                if (idx < 41)
                    acc[idx] += red[0][lane][k] + red[1][lane][k] + red[2][lane][k];
            }
        }
        __syncthreads();
    }
    if (wave == 0) {
        float mx = acc[0];
        #pragma unroll
        for (int s = 1; s < 20; ++s) mx = fmaxf(mx, acc[s]);
        float msum = 0.f;
        #pragma unroll
        for (int s = 0; s < 20; ++s) {
            acc[s] = __expf(acc[s] - mx) * msk[s];
            msum += acc[s];
        }
        const float rr = 1.f / msum;
        u16 row32[32];
        #pragma unroll
        for (int s = 0; s < 20; ++s) {
            float a = acc[s] * rr;
            attnw[((size_t)b * NS + s) * NHW + n] = a;
            row32[s] = f2b(a);
        }
        row32[20] = 0x3F80;
        #pragma unroll
        for (int s = 21; s < 32; ++s) row32[s] = 0;
        u16* dp = attnwT + ((size_t)b * NHW + n) * 32;
        #pragma unroll
        for (int q = 0; q < 4; ++q)
            *(u16x8*)&dp[q * 8] = *(u16x8*)&row32[q * 8];
        u16 rk[32];
        #pragma unroll
        for (int s = 0; s < 21; ++s) rk[s] = f2b(acc[20 + s]);
        #pragma unroll
        for (int s = 21; s < 32; ++s) rk[s] = 0;
        u16* kp2 = ks + ((size_t)b * NHW + n) * 32;
        #pragma unroll
        for (int q = 0; q < 4; ++q)
            *(u16x8*)&kp2[q * 8] = *(u16x8*)&rk[q * 8];
    }
}

__global__ __launch_bounds__(256)
void fold_g(const float* __restrict__ O, const float* __restrict__ fk,
            const float* __restrict__ fq_b, const float* __restrict__ fk_b,
            float* __restrict__ g, float* __restrict__ h)
{
    __shared__ float fqqsh[256][21];
    __shared__ float fqbsh[256];
    __shared__ float red[3][64][7];
    const int b = blockIdx.y;
    const int tid = threadIdx.x;
    for (int idx = tid; idx < 256 * NS; idx += 256) {
        int kc = idx / NS, s = idx - kc * NS;
        fqqsh[kc][s] = O[((size_t)b * 768 + kc) * NS + s];
    }
    fqbsh[tid] = fq_b[tid];
    __syncthreads();
    const int wave = tid >> 6, lane = tid & 63;
    const int c = blockIdx.x * 64 + lane;
    float acc[21] = {};
    for (int i = 0; i < 64; ++i) {
        int kc = wave * 64 + i;
        float w = fk[(size_t)kc * NC + c];
        #pragma unroll
        for (int s = 0; s < NS; ++s) acc[s] += w * fqqsh[kc][s];
        acc[20] += w * fqbsh[kc];
    }
    #pragma unroll
    for (int r = 0; r < 3; ++r) {
        if (wave > 0) {
            #pragma unroll
            for (int k = 0; k < 7; ++k) red[wave - 1][lane][k] = acc[r * 7 + k];
        }
        __syncthreads();
        if (wave == 0) {
            #pragma unroll
            for (int k = 0; k < 7; ++k)
                acc[r * 7 + k] += red[0][lane][k] + red[1][lane][k] + red[2][lane][k];
        }
        __syncthreads();
    }
    if (wave == 0) {
        float* gp = &g[((size_t)b * NC + c) * 24];
        #pragma unroll
        for (int s = 0; s < 21; ++s) gp[s] = acc[s] * SCL;
        gp[21] = gp[22] = gp[23] = 0.f;
    }
    if (blockIdx.x == 0 && tid < 21) {
        float hh = 0.f;
        for (int kc = 0; kc < 256; ++kc)
            hh += fk_b[kc] * (tid < 20 ? fqqsh[kc][tid] : fqbsh[kc]);
        h[b * 24 + tid] = hh * SCL;
    }
}

extern "C" void kernel_launch(void* const* d_in, const int* in_sizes, int n_in,
                              void* d_out, int out_size, void* d_ws, size_t ws_size,
                              hipStream_t stream)
{
    const float* key   = (const float*)d_in[0];
    const float* query = (const float*)d_in[1];
    const int*   wid   = (const int*)d_in[2];
    const float* wv_w  = (const float*)d_in[3];
    const float* wv_b  = (const float*)d_in[4];
    const float* fk_w  = (const float*)d_in[5];
    const float* fk_b  = (const float*)d_in[6];
    const float* fq_w  = (const float*)d_in[7];
    const float* fq_b  = (const float*)d_in[8];
    const float* fv_w  = (const float*)d_in[9];
    const float* fv_b  = (const float*)d_in[10];
    const float* w1_w  = (const float*)d_in[11];
    const float* w1_b  = (const float*)d_in[12];
    const float* w2_w  = (const float*)d_in[13];
    const float* w2_b  = (const float*)d_in[14];
    float* out = (float*)d_out;

    char* p = (char*)d_ws;
    u16*   keyT   = (u16*)p;   p += (size_t)NB * NHW * NC * 2;    // 18.9 MB
    u8*    E8     = (u8*)p;    p += (size_t)NB * NHW * NHW;       // 42.5 MB
    u8*    vp8    = (u8*)p;    p += (size_t)NB * NC * NHW;        // 9.4 MB
    u16*   fvT    = (u16*)p;   p += (size_t)512 * 512 * 2;
    u16*   wc2b   = (u16*)p;   p += (size_t)512 * 512 * 2;
    u16*   wcv    = (u16*)p;   p += (size_t)512 * 512 * 2;
    u16*   attnwT = (u16*)p;   p += (size_t)NB * NHW * 32 * 2;
    u16*   ksb    = (u16*)p;   p += (size_t)NB * NHW * 32 * 2;
    float* attnw  = (float*)p; p += (size_t)NB * NS * NHW * 4;
    float* qw     = (float*)p; p += (size_t)NB * NS * NC * 4;
    float* qbuf   = (float*)p; p += (size_t)NB * NS * 4;
    float* Ofold  = (float*)p; p += (size_t)NB * 768 * NS * 4;
    float* g      = (float*)p; p += (size_t)NB * NC * 24 * 4;
    float* h      = (float*)p; p += (size_t)NB * 24 * 4;
    float* b2     = (float*)p; p += (size_t)512 * 4;
    float* Dpart  = (float*)p; p += (size_t)NB * 18 * NHW * 4;

    dim3 blk(256);

    // fused prep: keyT + fvT + wc2/b2 + qw/qb + Ofold (one dispatch)
    prep_all<<<dim3(3424), blk, 0, stream>>>(
        key, keyT, fv_w, fvT, w1_w, w1_b, w2_w, w2_b, fv_b, wc2b, b2,
        query, wv_w, wv_b, qw, qbuf, fq_w, Ofold);
    fold_g<<<dim3(8, NB), blk, 0, stream>>>(Ofold, fk_w, fq_b, fk_b, g, h);
    scan_wk<<<dim3(36, NB), blk, 0, stream>>>(key, qw, qbuf, wid, g, h,
                                              attnw, attnwT, ksb);

    // wcv = wc2 @ fv  (512x512, K=512), bf16 out
    gemm_nt_bf16<<<dim3(4, 4, 1), blk, 0, stream>>>(
        wc2b, 0, 512, fvT, 0, 512, wcv, 0, 512, 512,
        nullptr, 0, 1.f, 0);
    // vproj = wcv @ keyT -> fp8 out (hardware cvt)
    gemm_nt_bf16<<<dim3(18, 4, NB), blk, 0, stream>>>(
        wcv, 0, 512, keyT, (long)NHW * 512, 512,
        vp8, (long)NC * NHW, NHW, 512,
        nullptr, 0, 1.f, 2);
    // E (fp8, hardware cvt) + partial row sums from rounded values
    e_gemm<<<dim3(18, 18, NB), blk, 0, stream>>>(attnwT, ksb, E8, Dpart);
    // PV fp8 BK=128 with low-rank accumulator init; grid 576, b = XCD
    pv_gemm<<<dim3(576), blk, 0, stream>>>(vp8, E8, Dpart, attnw, Ofold, b2, out);
}

// Round 23
// 202.569 us; speedup vs baseline: 1.3462x; 1.0629x over previous
//
#include <hip/hip_runtime.h>

#define NHW 2304
#define NB  8
#define NS  20
#define NC  512
#define SCL 0.09016844005555897f   // log2(e)/16

typedef unsigned short u16;
typedef unsigned char u8;
typedef short short8 __attribute__((ext_vector_type(8)));
typedef unsigned short u16x8 __attribute__((ext_vector_type(8)));
typedef u8 u8x16 __attribute__((ext_vector_type(16)));
typedef float f32x4 __attribute__((ext_vector_type(4)));

__device__ __forceinline__ float b2f(u16 u) {
    unsigned int v = ((unsigned int)u) << 16;
    return __builtin_bit_cast(float, v);
}
__device__ __forceinline__ u16 f2b(float f) {
    unsigned int u = __builtin_bit_cast(unsigned int, f);
    u += 0x7fffu + ((u >> 16) & 1u);
    return (u16)(u >> 16);
}

// ---- software fp8 e4m3fn fallback ----
__device__ __forceinline__ u8 f2e4_sw(float f) {
    unsigned int u = __builtin_bit_cast(unsigned int, f);
    u8 sign = (u >> 24) & 0x80;
    unsigned int a = u & 0x7FFFFFFFu;
    if (a >= 0x43E00000u) return sign | 0x7E;
    int e = (int)(a >> 23) - 127;
    unsigned int m = (a & 0x7FFFFF) | 0x800000;
    int ne = e + 7;
    if (ne <= 0) {
        int shift = 21 - ne;
        if (shift > 24) return sign;
        unsigned int q = m >> shift;
        unsigned int rem = m & ((1u << shift) - 1);
        unsigned int half = 1u << (shift - 1);
        q += (rem > half) || (rem == half && (q & 1));
        return sign | (u8)q;
    }
    unsigned int q = m >> 20;
    unsigned int rem = m & 0xFFFFFu;
    q += (rem > 0x80000u) || (rem == 0x80000u && (q & 1));
    if (q >= 16) { q >>= 1; ne++; }
    if (ne >= 16 || (ne == 15 && q == 15)) return sign | 0x7E;
    return sign | (u8)((ne << 3) | (q & 7));
}
__device__ __forceinline__ float e42f_sw(u8 v) {
    int e = (v >> 3) & 15;
    int m = v & 7;
    float r;
    if (e == 0) r = (float)m * 0.001953125f;
    else {
        unsigned int bits = ((unsigned int)(e + 120) << 23) | ((unsigned int)m << 20);
        r = __builtin_bit_cast(float, bits);
    }
    return (v & 0x80) ? -r : r;
}

// ---- hardware fp8 conversion (gfx950); hi/sel must be immediates ----
#if defined(__has_builtin)
#if __has_builtin(__builtin_amdgcn_cvt_pk_fp8_f32) && __has_builtin(__builtin_amdgcn_cvt_f32_fp8)
#define HW_FP8 1
#endif
#endif

template<bool HI>
__device__ __forceinline__ unsigned int pk2_fp8(float a, float b, unsigned int old) {
#ifdef HW_FP8
    return (unsigned int)__builtin_amdgcn_cvt_pk_fp8_f32(a, b, (int)old, HI);
#else
    unsigned int lo = (unsigned int)f2e4_sw(a) | ((unsigned int)f2e4_sw(b) << 8);
    return HI ? ((old & 0x0000FFFFu) | (lo << 16)) : ((old & 0xFFFF0000u) | lo);
#endif
}
#ifdef HW_FP8
#define DEC_FP8(w, sel) __builtin_amdgcn_cvt_f32_fp8((int)(w), (sel))
#else
#define DEC_FP8(w, sel) e42f_sw((u8)((w) >> (8 * (sel))))
#endif

__device__ __forceinline__ void load_lds16(const void* g, void* l) {
    __builtin_amdgcn_global_load_lds((const __attribute__((address_space(1))) void*)g,
                                     (__attribute__((address_space(3))) void*)l, 16, 0, 0);
}

// ---------------------------------------------------------------------------
// bf16 NT GEMM body (128x128 tile, BK=64, bank-swizzled LDS), no bias.
// out_mode: 0 bf16, 2 fp8. Ab/Bb pre-offset to tile; Cb pre-offset to batch.
// ---------------------------------------------------------------------------
__device__ __forceinline__ void gemm_body(
    const u16* __restrict__ Ab, int lda, const u16* __restrict__ Bb, int ldb,
    void* __restrict__ Cb, int ldc, int K, float scale, int out_mode,
    int mBase, int nBase, u16* sA, u16* sB)
{
    const int tid = threadIdx.x;
    const int lane = tid & 63;
    const int wave = tid >> 6;
    const int wr = wave >> 1, wc = wave & 1;
    const int srow[4] = { ((wave * 4 + 0) & 7) * 16 + (lane >> 2),
                          ((wave * 4 + 1) & 7) * 16 + (lane >> 2),
                          ((wave * 4 + 2) & 7) * 16 + (lane >> 2),
                          ((wave * 4 + 3) & 7) * 16 + (lane >> 2) };
    const int swzw = ((lane & 3) ^ ((lane >> 3) & 3)) * 8;
    const int rsw  = ((lane >> 4) ^ ((lane >> 1) & 3)) * 8;
    f32x4 acc[4][4] = {};
    for (int k0 = 0; k0 < K; k0 += 64) {
        __syncthreads();
        #pragma unroll
        for (int it = 0; it < 4; ++it) {
            const int chunk = wave * 4 + it;
            const int kofs = (chunk >> 3) * 32 + swzw;
            load_lds16(&Ab[(size_t)srow[it] * lda + k0 + kofs], &sA[chunk * 512 + lane * 8]);
            load_lds16(&Bb[(size_t)srow[it] * ldb + k0 + kofs], &sB[chunk * 512 + lane * 8]);
        }
        __syncthreads();
        #pragma unroll
        for (int kk = 0; kk < 2; ++kk) {
            short8 af[4], bg[4];
            #pragma unroll
            for (int i = 0; i < 4; ++i)
                af[i] = *(const short8*)&sA[kk * 4096 + (wr * 64 + i * 16 + (lane & 15)) * 32 + rsw];
            #pragma unroll
            for (int j = 0; j < 4; ++j)
                bg[j] = *(const short8*)&sB[kk * 4096 + (wc * 64 + j * 16 + (lane & 15)) * 32 + rsw];
            #pragma unroll
            for (int i = 0; i < 4; ++i)
                #pragma unroll
                for (int j = 0; j < 4; ++j)
                    acc[i][j] = __builtin_amdgcn_mfma_f32_16x16x32_bf16(af[i], bg[j], acc[i][j], 0, 0, 0);
        }
    }
    const int r0 = mBase + wr * 64 + (lane >> 4) * 4;
    const int c0 = nBase + wc * 64 + (lane & 15);
    #pragma unroll
    for (int i = 0; i < 4; ++i) {
        #pragma unroll
        for (int r = 0; r < 4; ++r) {
            const int row = r0 + i * 16 + r;
            if (out_mode == 2) {
                float vv[4];
                #pragma unroll
                for (int j = 0; j < 4; ++j) vv[j] = acc[i][j][r] * scale;
                unsigned int w = 0;
                w = pk2_fp8<false>(vv[0], vv[1], w);
                w = pk2_fp8<true>(vv[2], vv[3], w);
                #pragma unroll
                for (int j = 0; j < 4; ++j)
                    ((u8*)Cb)[(size_t)row * ldc + c0 + j * 16] = (u8)(w >> (8 * j));
            } else {
                #pragma unroll
                for (int j = 0; j < 4; ++j)
                    ((u16*)Cb)[(size_t)row * ldc + c0 + j * 16] = f2b(acc[i][j][r] * scale);
            }
        }
    }
}

// ---------------------------------------------------------------------------
// E-GEMM: E8[n][m] = fp8(exp2(attnwT[n]·ks[m])); Dpart from ROUNDED values (HW cvt).
// ---------------------------------------------------------------------------
__global__ __launch_bounds__(256)
void e_gemm(const u16* __restrict__ attnwT, const u16* __restrict__ ks,
            u8* __restrict__ E8, float* __restrict__ Dpart)
{
    __shared__ __align__(16) u16 sA[128 * 32];
    __shared__ __align__(16) u16 sB[128 * 32];
    __shared__ __align__(16) u8 Etile[128 * 128];   // 16 KB, swizzled
    __shared__ float Dsh[2][128];
    const int tid = threadIdx.x;
    const int b = blockIdx.z;
    const int mt = blockIdx.x, nt = blockIdx.y;
    const int mBase = mt * 128, nBase = nt * 128;
    const u16* Ab = attnwT + ((size_t)b * NHW + nBase) * 32;
    const u16* Bb = ks     + ((size_t)b * NHW + mBase) * 32;
    const int lane = tid & 63;
    const int wave = tid >> 6;
    const int wr = wave >> 1, wc = wave & 1;
    const int str = tid >> 2;
    const int stk = (tid & 3) * 8;
    load_lds16(&Ab[(size_t)str * 32 + stk],        &sA[tid * 8]);
    load_lds16(&Ab[(size_t)(str + 64) * 32 + stk], &sA[2048 + tid * 8]);
    load_lds16(&Bb[(size_t)str * 32 + stk],        &sB[tid * 8]);
    load_lds16(&Bb[(size_t)(str + 64) * 32 + stk], &sB[2048 + tid * 8]);
    __syncthreads();
    short8 af[4], bg[4];
    #pragma unroll
    for (int i = 0; i < 4; ++i)
        af[i] = *(const short8*)&sA[(wr * 64 + i * 16 + (lane & 15)) * 32 + (lane >> 4) * 8];
    #pragma unroll
    for (int j = 0; j < 4; ++j)
        bg[j] = *(const short8*)&sB[(wc * 64 + j * 16 + (lane & 15)) * 32 + (lane >> 4) * 8];
    f32x4 acc[4][4] = {};
    #pragma unroll
    for (int i = 0; i < 4; ++i)
        #pragma unroll
        for (int j = 0; j < 4; ++j)
            acc[i][j] = __builtin_amdgcn_mfma_f32_16x16x32_bf16(af[i], bg[j], acc[i][j], 0, 0, 0);

    float dpart[16] = {};
    #pragma unroll
    for (int i = 0; i < 4; ++i) {
        #pragma unroll
        for (int r = 0; r < 4; ++r) {
            const int rowloc = wr * 64 + i * 16 + (lane >> 4) * 4 + r;
            unsigned int w = 0;
            w = pk2_fp8<false>(exp2f(acc[i][0][r]), exp2f(acc[i][1][r]), w);
            w = pk2_fp8<true>(exp2f(acc[i][2][r]), exp2f(acc[i][3][r]), w);
            dpart[i * 4 + r] += DEC_FP8(w, 0) + DEC_FP8(w, 1) + DEC_FP8(w, 2) + DEC_FP8(w, 3);
            #pragma unroll
            for (int j = 0; j < 4; ++j) {
                const int colloc = wc * 64 + j * 16 + (lane & 15);
                Etile[rowloc * 128 + (colloc ^ ((rowloc & 7) << 4))] = (u8)(w >> (8 * j));
            }
        }
    }
    #pragma unroll
    for (int mask = 1; mask < 16; mask <<= 1)
        #pragma unroll
        for (int k = 0; k < 16; ++k)
            dpart[k] += __shfl_xor(dpart[k], mask, 64);
    if ((lane & 15) == 0) {
        #pragma unroll
        for (int i = 0; i < 4; ++i)
            #pragma unroll
            for (int r = 0; r < 4; ++r)
                Dsh[wc][wr * 64 + i * 16 + (lane >> 4) * 4 + r] = dpart[i * 4 + r];
    }
    __syncthreads();
    if (tid < 128)
        Dpart[((size_t)(b * 18 + mt)) * NHW + nBase + tid] = Dsh[0][tid] + Dsh[1][tid];
    #pragma unroll
    for (int rep = 0; rep < 4; ++rep) {
        const int row = wave * 32 + rep * 8 + (lane >> 3);
        const int slot = lane & 7;
        u8x16 v = *(const u8x16*)&Etile[row * 128 + ((slot ^ (row & 7)) << 4)];
        *(u8x16*)&E8[((size_t)b * NHW + nBase + row) * NHW + mBase + slot * 16] = v;
    }
}

// ---------------------------------------------------------------------------
// PV GEMM fp8, 128x128 tile, BK=128, chunk-XOR swizzle c^=(row&7).
// out = (vp8·E8 + qp·(aw·Dsum)) * Dinv. Grid 576, b = XCD.
// ---------------------------------------------------------------------------
__global__ __launch_bounds__(256)
void pv_gemm(const u8* __restrict__ vp8, const u8* __restrict__ E8,
             const float* __restrict__ Dpart, const float* __restrict__ attnw,
             const float* __restrict__ Ofold, const float* __restrict__ b2,
             float* __restrict__ out)
{
    __shared__ __align__(16) u8 sA[16384];
    __shared__ __align__(16) u8 sB[16384];
    __shared__ float DsumSh[128];
    __shared__ float DinvSh[128];
    const int tid = threadIdx.x;
    const int bid = blockIdx.x;
    const int xcd = bid & 7, slot = bid >> 3;
    const int b = xcd;
    const int nt = slot >> 2;
    const int ot = slot & 3;
    const int oBase = ot * 128, nBase = nt * 128;

    const u8* A8 = vp8 + ((size_t)b * NC + oBase) * NHW;
    const u8* B8 = E8  + ((size_t)b * NHW + nBase) * NHW;
    const int lane = tid & 63;
    const int wave = tid >> 6;
    const int wr = wave >> 1, wc = wave & 1;

    int srowS[4], sgofS[4];
    #pragma unroll
    for (int it = 0; it < 4; ++it) {
        const int cd = (wave * 4 + it) * 64 + lane;
        srowS[it] = cd >> 3;
        sgofS[it] = ((cd & 7) ^ ((cd >> 3) & 7)) * 16;
    }
    #define PV_STAGE(k0) { \
        _Pragma("unroll") \
        for (int it = 0; it < 4; ++it) { \
            load_lds16(&A8[(size_t)srowS[it] * NHW + (k0) + sgofS[it]], &sA[((wave * 4 + it) * 64 + lane) * 16]); \
            load_lds16(&B8[(size_t)srowS[it] * NHW + (k0) + sgofS[it]], &sB[((wave * 4 + it) * 64 + lane) * 16]); \
        } }

    u16* sAh = (u16*)sA;
    u16* sBh = (u16*)sB;
    if (tid < 128) {
        float s = 0.f;
        #pragma unroll
        for (int mt = 0; mt < 18; ++mt)
            s += Dpart[((size_t)(b * 18 + mt)) * NHW + nBase + tid];
        DsumSh[tid] = s;
        DinvSh[tid] = 1.f / s;
    }
    for (int idx = tid; idx < 128 * 32; idx += 256) {
        const int o = idx >> 5, s = idx & 31;
        float v = 0.f;
        if (s < 20) v = Ofold[((size_t)b * 768 + 256 + oBase + o) * NS + s];
        else if (s == 20) v = b2[oBase + o];
        sAh[idx] = f2b(v);
    }
    __syncthreads();
    for (int idx = tid; idx < 128 * 32; idx += 256) {
        const int n = idx >> 5, s = idx & 31;
        float v = 0.f;
        if (s <= 20) {
            const float ds = DsumSh[n];
            v = (s < 20) ? attnw[((size_t)b * NS + s) * NHW + nBase + n] * ds : ds;
        }
        sBh[idx] = f2b(v);
    }
    __syncthreads();

    f32x4 acc[4][4];
    {
        const f32x4 zero = {0.f, 0.f, 0.f, 0.f};
        short8 qf[4], afr[4];
        #pragma unroll
        for (int i = 0; i < 4; ++i)
            qf[i] = *(const short8*)&sAh[(wr * 64 + i * 16 + (lane & 15)) * 32 + (lane >> 4) * 8];
        #pragma unroll
        for (int j = 0; j < 4; ++j)
            afr[j] = *(const short8*)&sBh[(wc * 64 + j * 16 + (lane & 15)) * 32 + (lane >> 4) * 8];
        #pragma unroll
        for (int i = 0; i < 4; ++i)
            #pragma unroll
            for (int j = 0; j < 4; ++j)
                acc[i][j] = __builtin_amdgcn_mfma_f32_16x16x32_bf16(qf[i], afr[j], zero, 0, 0, 0);
    }

    const int krow_a = wr * 64 + (lane & 15);
    const int krow_b = wc * 64 + (lane & 15);
    const int khalf = ((lane >> 4) & 1) * 8;
    const int kc2   = (lane >> 5);

    for (int k0 = 0; k0 < NHW; k0 += 128) {
        __syncthreads();
        PV_STAGE(k0);
        __syncthreads();
        #pragma unroll
        for (int kk = 0; kk < 4; ++kk) {
            long af[4], bg[4];
            #pragma unroll
            for (int i = 0; i < 4; ++i) {
                const int row = krow_a + i * 16;
                const int c = (kk * 2 + kc2) ^ (row & 7);
                af[i] = *(const long*)&sA[row * 128 + c * 16 + khalf];
            }
            #pragma unroll
            for (int j = 0; j < 4; ++j) {
                const int row = krow_b + j * 16;
                const int c = (kk * 2 + kc2) ^ (row & 7);
                bg[j] = *(const long*)&sB[row * 128 + c * 16 + khalf];
            }
            #pragma unroll
            for (int i = 0; i < 4; ++i)
                #pragma unroll
                for (int j = 0; j < 4; ++j)
                    acc[i][j] = __builtin_amdgcn_mfma_f32_16x16x32_fp8_fp8(af[i], bg[j], acc[i][j], 0, 0, 0);
        }
    }
    #pragma unroll
    for (int i = 0; i < 4; ++i) {
        #pragma unroll
        for (int r = 0; r < 4; ++r) {
            const int rowloc = wr * 64 + i * 16 + (lane >> 4) * 4 + r;
            #pragma unroll
            for (int j = 0; j < 4; ++j) {
                const int colloc = wc * 64 + j * 16 + (lane & 15);
                out[((size_t)b * NC + oBase + rowloc) * NHW + nBase + colloc] =
                    acc[i][j][r] * DinvSh[colloc];
            }
        }
    }
    #undef PV_STAGE
}

// ---------------------------------------------------------------------------
// prep_all: fused independent prep work, branch on blockIdx range.
// ---------------------------------------------------------------------------
__global__ __launch_bounds__(256)
void prep_all(const float* __restrict__ key, u16* __restrict__ keyT,
              const float* __restrict__ fv_w, u16* __restrict__ fvT,
              const float* __restrict__ w1, const float* __restrict__ w1b,
              const float* __restrict__ w2, const float* __restrict__ w2b,
              const float* __restrict__ fvb, u16* __restrict__ wc2b,
              float* __restrict__ b2,
              const float* __restrict__ query, const float* __restrict__ wv_w,
              const float* __restrict__ wv_b, float* __restrict__ qw,
              float* __restrict__ qb,
              const float* __restrict__ fq, float* __restrict__ O)
{
    __shared__ __align__(16) char smem[44032];
    const int bid = blockIdx.x;
    const int tid = threadIdx.x;

    if (bid < 2368) {
        const float* src; u16* dst; int R, Cc, cBase, rBase, b;
        if (bid < 2304) {
            src = key; dst = keyT; R = NC; Cc = NHW;
            cBase = (bid % 36) * 64; rBase = ((bid / 36) % 8) * 64; b = bid / 288;
        } else {
            const int t2 = bid - 2304;
            src = fv_w; dst = fvT; R = 512; Cc = 512;
            cBase = (t2 % 8) * 64; rBase = (t2 / 8) * 64; b = 0;
        }
        u16 (*t)[72] = (u16(*)[72])smem;
        const float* sb = src + ((size_t)b * R + rBase) * Cc + cBase;
        const int ln = tid & 63;
        const int lr = tid >> 6;
        #pragma unroll
        for (int rr = 0; rr < 16; ++rr) {
            int r = lr + rr * 4;
            t[r][ln] = f2b(sb[(size_t)r * Cc + ln]);
        }
        __syncthreads();
        u16* ob = dst + ((size_t)b * Cc + cBase) * R + rBase;
        #pragma unroll
        for (int rep = 0; rep < 2; ++rep) {
            int slot = rep * 256 + tid;
            int cc = slot >> 3;
            int r8 = (slot & 7) * 8;
            u16x8 v;
            #pragma unroll
            for (int e = 0; e < 8; ++e) v[e] = t[r8 + e][cc];
            *(u16x8*)&ob[(size_t)cc * R + r8] = v;
        }
    } else if (bid < 2880) {
        const int o = bid - 2368;
        float* red = (float*)smem;
        float part = 0.f;
        for (int c = tid; c < 512; c += 256) {
            float v = w1[(size_t)o * 1024 + c] + w2[(size_t)o * 512 + c];
            wc2b[(size_t)o * 512 + c] = f2b(v);
            part += v * fvb[c];
        }
        #pragma unroll
        for (int off = 32; off > 0; off >>= 1) part += __shfl_down(part, off, 64);
        if ((tid & 63) == 0) red[tid >> 6] = part;
        __syncthreads();
        if (tid == 0) b2[o] = (red[0] + red[1]) + (red[2] + red[3]) + w1b[o] + w2b[o];
    } else if (bid < 3040) {
        const int t3 = bid - 2880;
        const int s = t3 % NS, b = t3 / NS;
        float* qs  = (float*)smem;
        float* red = qs + 512;
        qs[tid] = query[((size_t)b * NS + s) * NC + tid];
        qs[tid + 256] = query[((size_t)b * NS + s) * NC + tid + 256];
        __syncthreads();
        float a0 = 0.f, a1 = 0.f;
        for (int o = 0; o < NC; ++o) {
            float qv = qs[o];
            a0 += qv * wv_w[(size_t)o * NC + tid];
            a1 += qv * wv_w[(size_t)o * NC + tid + 256];
        }
        qw[((size_t)b * NS + s) * NC + tid] = a0;
        qw[((size_t)b * NS + s) * NC + tid + 256] = a1;
        float pb = qs[tid] * wv_b[tid] + qs[tid + 256] * wv_b[tid + 256];
        #pragma unroll
        for (int off = 32; off > 0; off >>= 1) pb += __shfl_down(pb, off, 64);
        if ((tid & 63) == 0) red[tid >> 6] = pb;
        __syncthreads();
        if (tid == 0) qb[b * NS + s] = (red[0] + red[1]) + (red[2] + red[3]);
    } else {
        const int t4 = bid - 3040;
        const int x = t4 % 48, b = t4 / 48;
        float (*qsh)[NC] = (float(*)[NC])smem;
        for (int idx = tid; idx < NS * NC; idx += 256)
            qsh[idx >> 9][idx & 511] = query[(size_t)b * NS * NC + idx];
        __syncthreads();
        const int row = x * 16 + (tid >> 4);
        const int ct = tid & 15;
        const float* wp = (row < 256) ? &fq[(size_t)row * NC]
                                      : &w1[(size_t)(row - 256) * 1024 + 512];
        float acc[NS] = {};
        #pragma unroll 4
        for (int i = 0; i < 32; ++i) {
            int c = ct + i * 16;
            float w = wp[c];
            #pragma unroll
            for (int s = 0; s < NS; ++s) acc[s] += w * qsh[s][c];
        }
        #pragma unroll
        for (int off = 1; off < 16; off <<= 1)
            #pragma unroll
            for (int s = 0; s < NS; ++s) acc[s] += __shfl_xor(acc[s], off, 64);
        if (ct == 0) {
            #pragma unroll
            for (int s = 0; s < NS; ++s)
                O[((size_t)b * 768 + row) * NS + s] = acc[s];
        }
    }
}

// ---------------------------------------------------------------------------
// mid_all: fold_g (64 blocks) + wcv GEMM (16 blocks), both dep only on prep_all.
// ---------------------------------------------------------------------------
__global__ __launch_bounds__(256)
void mid_all(const float* __restrict__ O, const float* __restrict__ fk,
             const float* __restrict__ fq_b, const float* __restrict__ fk_b,
             float* __restrict__ g, float* __restrict__ h,
             const u16* __restrict__ wc2b, const u16* __restrict__ fvT,
             u16* __restrict__ wcv)
{
    __shared__ __align__(16) char smem[32768];
    const int bid = blockIdx.x;
    const int tid = threadIdx.x;
    if (bid < 64) {
        const int xb = bid & 7, b = bid >> 3;
        float (*fqqsh)[21] = (float(*)[21])smem;                 // 21504 B
        float* fqbsh = (float*)(smem + 21504);                   // 1024 B
        float (*red)[64][7] = (float(*)[64][7])(smem + 22528);   // 5376 B
        for (int idx = tid; idx < 256 * NS; idx += 256) {
            int kc = idx / NS, s = idx - kc * NS;
            fqqsh[kc][s] = O[((size_t)b * 768 + kc) * NS + s];
        }
        fqbsh[tid] = fq_b[tid];
        __syncthreads();
        const int wave = tid >> 6, lane = tid & 63;
        const int c = xb * 64 + lane;
        float acc[21] = {};
        for (int i = 0; i < 64; ++i) {
            int kc = wave * 64 + i;
            float w = fk[(size_t)kc * NC + c];
            #pragma unroll
            for (int s = 0; s < NS; ++s) acc[s] += w * fqqsh[kc][s];
            acc[20] += w * fqbsh[kc];
        }
        #pragma unroll
        for (int r = 0; r < 3; ++r) {
            if (wave > 0) {
                #pragma unroll
                for (int k = 0; k < 7; ++k) red[wave - 1][lane][k] = acc[r * 7 + k];
            }
            __syncthreads();
            if (wave == 0) {
                #pragma unroll
                for (int k = 0; k < 7; ++k)
                    acc[r * 7 + k] += red[0][lane][k] + red[1][lane][k] + red[2][lane][k];
            }
            __syncthreads();
        }
        if (wave == 0) {
            float* gp = &g[((size_t)b * NC + c) * 24];
            #pragma unroll
            for (int s = 0; s < 21; ++s) gp[s] = acc[s] * SCL;
            gp[21] = gp[22] = gp[23] = 0.f;
        }
        if (xb == 0 && tid < 21) {
            float hh = 0.f;
            for (int kc = 0; kc < 256; ++kc)
                hh += fk_b[kc] * (tid < 20 ? fqqsh[kc][tid] : fqbsh[kc]);
            h[b * 24 + tid] = hh * SCL;
        }
    } else {
        const int t = bid - 64;
        const int nBase = (t & 3) * 128;
        const int mBase = (t >> 2) * 128;
        u16* sA = (u16*)smem;
        u16* sB = (u16*)(smem + 16384);
        gemm_body(wc2b + (size_t)mBase * 512, 512, fvT + (size_t)nBase * 512, 512,
                  wcv, 512, 512, 1.f, 0, mBase, nBase, sA, sB);
    }
}

// ---------------------------------------------------------------------------
// scan_vproj: scan_wk (288 blocks) + vproj GEMM (576 blocks), independent.
// ---------------------------------------------------------------------------
__global__ __launch_bounds__(256)
void scan_vproj(const float* __restrict__ key, const float* __restrict__ qw,
                const float* __restrict__ qb, const int* __restrict__ wid,
                const float* __restrict__ g, const float* __restrict__ h,
                float* __restrict__ attnw, u16* __restrict__ attnwT,
                u16* __restrict__ ks,
                const u16* __restrict__ wcv, const u16* __restrict__ keyT,
                u8* __restrict__ vp8)
{
    __shared__ __align__(16) char smem[69632];
    const int bid = blockIdx.x;
    const int tid = threadIdx.x;
    if (bid < 288) {
        const int xb = bid % 36, b = bid / 36;
        float (*qshT)[20] = (float(*)[20])smem;                  // 40960
        u16 (*gshb)[22] = (u16(*)[22])(smem + 40960);            // 22528
        float (*red)[64][7] = (float(*)[64][7])(smem + 63488);   // 5376
        float* msk = (float*)(smem + 68864);
        float* qbs = (float*)(smem + 68944);
        float* hsh = (float*)(smem + 69024);
        const float* qwb = qw + (size_t)b * NS * NC;
        for (int idx = tid; idx < NC * 20; idx += 256) {
            int c = idx / 20, s = idx - c * 20;
            qshT[c][s] = qwb[s * NC + c];
        }
        for (int idx = tid; idx < NC * 21; idx += 256) {
            int c = idx / 21, s = idx - c * 21;
            gshb[c][s] = f2b(g[((size_t)b * NC + c) * 24 + s]);
        }
        if (tid < 20) {
            msk[tid] = (wid[b * NS + tid] != 0) ? 1.f : 0.f;
            qbs[tid] = qb[b * NS + tid];
        }
        if (tid < 21) hsh[tid] = h[b * 24 + tid];
        __syncthreads();
        const int wave = tid >> 6, lane = tid & 63;
        const int n = xb * 64 + lane;
        const int cbase = wave * 128;
        const float* kp = key + (size_t)b * NC * NHW + n;
        float acc[41];
        #pragma unroll
        for (int s = 0; s < 41; ++s)
            acc[s] = (wave == 0) ? (s < 20 ? qbs[s] : hsh[s - 20]) : 0.f;
        #pragma unroll 4
        for (int ci = 0; ci < 128; ++ci) {
            const int c = cbase + ci;
            float kv = kp[(size_t)c * NHW];
            #pragma unroll
            for (int s = 0; s < 20; ++s) acc[s] += qshT[c][s] * kv;
            #pragma unroll
            for (int s = 0; s < 21; ++s) acc[20 + s] += b2f(gshb[c][s]) * kv;
        }
        #pragma unroll
        for (int r = 0; r < 6; ++r) {
            if (wave > 0) {
                #pragma unroll
                for (int k = 0; k < 7; ++k) {
                    int idx = r * 7 + k;
                    if (idx < 41) red[wave - 1][lane][k] = acc[idx];
                }
            }
            __syncthreads();
            if (wave == 0) {
                #pragma unroll
                for (int k = 0; k < 7; ++k) {
                    int idx = r * 7 + k;
                    if (idx < 41)
                        acc[idx] += red[0][lane][k] + red[1][lane][k] + red[2][lane][k];
                }
            }
            __syncthreads();
        }
        if (wave == 0) {
            float mx = acc[0];
            #pragma unroll
            for (int s = 1; s < 20; ++s) mx = fmaxf(mx, acc[s]);
            float msum = 0.f;
            #pragma unroll
            for (int s = 0; s < 20; ++s) {
                acc[s] = __expf(acc[s] - mx) * msk[s];
                msum += acc[s];
            }
            const float rr = 1.f / msum;
            u16 row32[32];
            #pragma unroll
            for (int s = 0; s < 20; ++s) {
                float a = acc[s] * rr;
                attnw[((size_t)b * NS + s) * NHW + n] = a;
                row32[s] = f2b(a);
            }
            row32[20] = 0x3F80;
            #pragma unroll
            for (int s = 21; s < 32; ++s) row32[s] = 0;
            u16* dp = attnwT + ((size_t)b * NHW + n) * 32;
            #pragma unroll
            for (int q = 0; q < 4; ++q)
                *(u16x8*)&dp[q * 8] = *(u16x8*)&row32[q * 8];
            u16 rk[32];
            #pragma unroll
            for (int s = 0; s < 21; ++s) rk[s] = f2b(acc[20 + s]);
            #pragma unroll
            for (int s = 21; s < 32; ++s) rk[s] = 0;
            u16* kp2 = ks + ((size_t)b * NHW + n) * 32;
            #pragma unroll
            for (int q = 0; q < 4; ++q)
                *(u16x8*)&kp2[q * 8] = *(u16x8*)&rk[q * 8];
        }
    } else {
        const int t = bid - 288;
        const int nBase = (t % 18) * 128;
        const int mBase = ((t / 18) & 3) * 128;
        const int bb = t / 72;
        u16* sA = (u16*)smem;
        u16* sB = (u16*)(smem + 16384);
        gemm_body(wcv + (size_t)mBase * 512, 512,
                  keyT + (size_t)bb * NHW * 512 + (size_t)nBase * 512, 512,
                  vp8 + (size_t)bb * NC * NHW, NHW, 512, 1.f, 2,
                  mBase, nBase, sA, sB);
    }
}

extern "C" void kernel_launch(void* const* d_in, const int* in_sizes, int n_in,
                              void* d_out, int out_size, void* d_ws, size_t ws_size,
                              hipStream_t stream)
{
    const float* key   = (const float*)d_in[0];
    const float* query = (const float*)d_in[1];
    const int*   wid   = (const int*)d_in[2];
    const float* wv_w  = (const float*)d_in[3];
    const float* wv_b  = (const float*)d_in[4];
    const float* fk_w  = (const float*)d_in[5];
    const float* fk_b  = (const float*)d_in[6];
    const float* fq_w  = (const float*)d_in[7];
    const float* fq_b  = (const float*)d_in[8];
    const float* fv_w  = (const float*)d_in[9];
    const float* fv_b  = (const float*)d_in[10];
    const float* w1_w  = (const float*)d_in[11];
    const float* w1_b  = (const float*)d_in[12];
    const float* w2_w  = (const float*)d_in[13];
    const float* w2_b  = (const float*)d_in[14];
    float* out = (float*)d_out;

    char* p = (char*)d_ws;
    u16*   keyT   = (u16*)p;   p += (size_t)NB * NHW * NC * 2;    // 18.9 MB
    u8*    E8     = (u8*)p;    p += (size_t)NB * NHW * NHW;       // 42.5 MB
    u8*    vp8    = (u8*)p;    p += (size_t)NB * NC * NHW;        // 9.4 MB
    u16*   fvT    = (u16*)p;   p += (size_t)512 * 512 * 2;
    u16*   wc2b   = (u16*)p;   p += (size_t)512 * 512 * 2;
    u16*   wcv    = (u16*)p;   p += (size_t)512 * 512 * 2;
    u16*   attnwT = (u16*)p;   p += (size_t)NB * NHW * 32 * 2;
    u16*   ksb    = (u16*)p;   p += (size_t)NB * NHW * 32 * 2;
    float* attnw  = (float*)p; p += (size_t)NB * NS * NHW * 4;
    float* qw     = (float*)p; p += (size_t)NB * NS * NC * 4;
    float* qbuf   = (float*)p; p += (size_t)NB * NS * 4;
    float* Ofold  = (float*)p; p += (size_t)NB * 768 * NS * 4;
    float* g      = (float*)p; p += (size_t)NB * NC * 24 * 4;
    float* h      = (float*)p; p += (size_t)NB * 24 * 4;
    float* b2     = (float*)p; p += (size_t)512 * 4;
    float* Dpart  = (float*)p; p += (size_t)NB * 18 * NHW * 4;

    dim3 blk(256);

    // 1. fused prep: keyT + fvT + wc2/b2 + qw/qb + Ofold
    prep_all<<<dim3(3424), blk, 0, stream>>>(
        key, keyT, fv_w, fvT, w1_w, w1_b, w2_w, w2_b, fv_b, wc2b, b2,
        query, wv_w, wv_b, qw, qbuf, fq_w, Ofold);
    // 2. fold_g + wcv GEMM
    mid_all<<<dim3(80), blk, 0, stream>>>(
        Ofold, fk_w, fq_b, fk_b, g, h, wc2b, fvT, wcv);
    // 3. scan_wk + vproj GEMM
    scan_vproj<<<dim3(864), blk, 0, stream>>>(
        key, qw, qbuf, wid, g, h, attnw, attnwT, ksb, wcv, keyT, vp8);
    // 4. E (fp8) + partial row sums
    e_gemm<<<dim3(18, 18, NB), blk, 0, stream>>>(attnwT, ksb, E8, Dpart);
    // 5. PV fp8 BK=128 with low-rank accumulator init
    pv_gemm<<<dim3(576), blk, 0, stream>>>(vp8, E8, Dpart, attnw, Ofold, b2, out);
}

// Round 25
// 198.834 us; speedup vs baseline: 1.3715x; 1.0188x over previous
//
#include <hip/hip_runtime.h>

#define NHW 2304
#define NB  8
#define NS  20
#define NC  512
#define SCL 0.09016844005555897f   // log2(e)/16

typedef unsigned short u16;
typedef unsigned char u8;
typedef short short8 __attribute__((ext_vector_type(8)));
typedef unsigned short u16x8 __attribute__((ext_vector_type(8)));
typedef u8 u8x16 __attribute__((ext_vector_type(16)));
typedef float f32x4 __attribute__((ext_vector_type(4)));

__device__ __forceinline__ float b2f(u16 u) {
    unsigned int v = ((unsigned int)u) << 16;
    return __builtin_bit_cast(float, v);
}
__device__ __forceinline__ u16 f2b(float f) {
    unsigned int u = __builtin_bit_cast(unsigned int, f);
    u += 0x7fffu + ((u >> 16) & 1u);
    return (u16)(u >> 16);
}

// ---- software fp8 e4m3fn fallback ----
__device__ __forceinline__ u8 f2e4_sw(float f) {
    unsigned int u = __builtin_bit_cast(unsigned int, f);
    u8 sign = (u >> 24) & 0x80;
    unsigned int a = u & 0x7FFFFFFFu;
    if (a >= 0x43E00000u) return sign | 0x7E;
    int e = (int)(a >> 23) - 127;
    unsigned int m = (a & 0x7FFFFF) | 0x800000;
    int ne = e + 7;
    if (ne <= 0) {
        int shift = 21 - ne;
        if (shift > 24) return sign;
        unsigned int q = m >> shift;
        unsigned int rem = m & ((1u << shift) - 1);
        unsigned int half = 1u << (shift - 1);
        q += (rem > half) || (rem == half && (q & 1));
        return sign | (u8)q;
    }
    unsigned int q = m >> 20;
    unsigned int rem = m & 0xFFFFFu;
    q += (rem > 0x80000u) || (rem == 0x80000u && (q & 1));
    if (q >= 16) { q >>= 1; ne++; }
    if (ne >= 16 || (ne == 15 && q == 15)) return sign | 0x7E;
    return sign | (u8)((ne << 3) | (q & 7));
}
__device__ __forceinline__ float e42f_sw(u8 v) {
    int e = (v >> 3) & 15;
    int m = v & 7;
    float r;
    if (e == 0) r = (float)m * 0.001953125f;
    else {
        unsigned int bits = ((unsigned int)(e + 120) << 23) | ((unsigned int)m << 20);
        r = __builtin_bit_cast(float, bits);
    }
    return (v & 0x80) ? -r : r;
}

// ---- hardware fp8 conversion (gfx950); hi/sel must be immediates ----
#if defined(__has_builtin)
#if __has_builtin(__builtin_amdgcn_cvt_pk_fp8_f32) && __has_builtin(__builtin_amdgcn_cvt_f32_fp8)
#define HW_FP8 1
#endif
#endif

template<bool HI>
__device__ __forceinline__ unsigned int pk2_fp8(float a, float b, unsigned int old) {
#ifdef HW_FP8
    return (unsigned int)__builtin_amdgcn_cvt_pk_fp8_f32(a, b, (int)old, HI);
#else
    unsigned int lo = (unsigned int)f2e4_sw(a) | ((unsigned int)f2e4_sw(b) << 8);
    return HI ? ((old & 0x0000FFFFu) | (lo << 16)) : ((old & 0xFFFF0000u) | lo);
#endif
}
#ifdef HW_FP8
#define DEC_FP8(w, sel) __builtin_amdgcn_cvt_f32_fp8((int)(w), (sel))
#else
#define DEC_FP8(w, sel) e42f_sw((u8)((w) >> (8 * (sel))))
#endif

__device__ __forceinline__ void load_lds16(const void* g, void* l) {
    __builtin_amdgcn_global_load_lds((const __attribute__((address_space(1))) void*)g,
                                     (__attribute__((address_space(3))) void*)l, 16, 0, 0);
}

// ---------------------------------------------------------------------------
// bf16 NT GEMM body (128x128 tile, BK=64, bank-swizzled LDS), no bias.
// Requires sA/sB each 8192 u16 (16 KB). out_mode: 0 bf16, 2 fp8.
// ---------------------------------------------------------------------------
__device__ __forceinline__ void gemm_body(
    const u16* __restrict__ Ab, int lda, const u16* __restrict__ Bb, int ldb,
    void* __restrict__ Cb, int ldc, int K, float scale, int out_mode,
    int mBase, int nBase, u16* sA, u16* sB)
{
    const int tid = threadIdx.x;
    const int lane = tid & 63;
    const int wave = tid >> 6;
    const int wr = wave >> 1, wc = wave & 1;
    const int srow[4] = { ((wave * 4 + 0) & 7) * 16 + (lane >> 2),
                          ((wave * 4 + 1) & 7) * 16 + (lane >> 2),
                          ((wave * 4 + 2) & 7) * 16 + (lane >> 2),
                          ((wave * 4 + 3) & 7) * 16 + (lane >> 2) };
    const int swzw = ((lane & 3) ^ ((lane >> 3) & 3)) * 8;
    const int rsw  = ((lane >> 4) ^ ((lane >> 1) & 3)) * 8;
    f32x4 acc[4][4] = {};
    for (int k0 = 0; k0 < K; k0 += 64) {
        __syncthreads();
        #pragma unroll
        for (int it = 0; it < 4; ++it) {
            const int chunk = wave * 4 + it;
            const int kofs = (chunk >> 3) * 32 + swzw;
            load_lds16(&Ab[(size_t)srow[it] * lda + k0 + kofs], &sA[chunk * 512 + lane * 8]);
            load_lds16(&Bb[(size_t)srow[it] * ldb + k0 + kofs], &sB[chunk * 512 + lane * 8]);
        }
        __syncthreads();
        #pragma unroll
        for (int kk = 0; kk < 2; ++kk) {
            short8 af[4], bg[4];
            #pragma unroll
            for (int i = 0; i < 4; ++i)
                af[i] = *(const short8*)&sA[kk * 4096 + (wr * 64 + i * 16 + (lane & 15)) * 32 + rsw];
            #pragma unroll
            for (int j = 0; j < 4; ++j)
                bg[j] = *(const short8*)&sB[kk * 4096 + (wc * 64 + j * 16 + (lane & 15)) * 32 + rsw];
            #pragma unroll
            for (int i = 0; i < 4; ++i)
                #pragma unroll
                for (int j = 0; j < 4; ++j)
                    acc[i][j] = __builtin_amdgcn_mfma_f32_16x16x32_bf16(af[i], bg[j], acc[i][j], 0, 0, 0);
        }
    }
    const int r0 = mBase + wr * 64 + (lane >> 4) * 4;
    const int c0 = nBase + wc * 64 + (lane & 15);
    #pragma unroll
    for (int i = 0; i < 4; ++i) {
        #pragma unroll
        for (int r = 0; r < 4; ++r) {
            const int row = r0 + i * 16 + r;
            if (out_mode == 2) {
                float vv[4];
                #pragma unroll
                for (int j = 0; j < 4; ++j) vv[j] = acc[i][j][r] * scale;
                unsigned int w = 0;
                w = pk2_fp8<false>(vv[0], vv[1], w);
                w = pk2_fp8<true>(vv[2], vv[3], w);
                #pragma unroll
                for (int j = 0; j < 4; ++j)
                    ((u8*)Cb)[(size_t)row * ldc + c0 + j * 16] = (u8)(w >> (8 * j));
            } else {
                #pragma unroll
                for (int j = 0; j < 4; ++j)
                    ((u16*)Cb)[(size_t)row * ldc + c0 + j * 16] = f2b(acc[i][j][r] * scale);
            }
        }
    }
}

// ---------------------------------------------------------------------------
// vproj GEMM: vp8 = fp8(wcv @ keyT^T), grid 576 (18 n-tiles x 4 m-tiles x 8 b)
// ---------------------------------------------------------------------------
__global__ __launch_bounds__(256)
void vproj_gemm(const u16* __restrict__ wcv, const u16* __restrict__ keyT,
                u8* __restrict__ vp8)
{
    __shared__ __align__(16) u16 sA[8192];   // 16 KB: 2 panels x [128][32]
    __shared__ __align__(16) u16 sB[8192];
    const int t = blockIdx.x;
    const int nBase = (t % 18) * 128;
    const int mBase = ((t / 18) & 3) * 128;
    const int bb = t / 72;
    gemm_body(wcv + (size_t)mBase * 512, 512,
              keyT + (size_t)bb * NHW * 512 + (size_t)nBase * 512, 512,
              vp8 + (size_t)bb * NC * NHW, NHW, 512, 1.f, 2,
              mBase, nBase, sA, sB);
}

// ---------------------------------------------------------------------------
// E-GEMM: E8[n][m] = fp8(exp2(attnwT[n]·ks[m])); Dpart from ROUNDED values (HW cvt).
// ---------------------------------------------------------------------------
__global__ __launch_bounds__(256)
void e_gemm(const u16* __restrict__ attnwT, const u16* __restrict__ ks,
            u8* __restrict__ E8, float* __restrict__ Dpart)
{
    __shared__ __align__(16) u16 sA[128 * 32];
    __shared__ __align__(16) u16 sB[128 * 32];
    __shared__ __align__(16) u8 Etile[128 * 128];   // 16 KB, swizzled
    __shared__ float Dsh[2][128];
    const int tid = threadIdx.x;
    const int b = blockIdx.z;
    const int mt = blockIdx.x, nt = blockIdx.y;
    const int mBase = mt * 128, nBase = nt * 128;
    const u16* Ab = attnwT + ((size_t)b * NHW + nBase) * 32;
    const u16* Bb = ks     + ((size_t)b * NHW + mBase) * 32;
    const int lane = tid & 63;
    const int wave = tid >> 6;
    const int wr = wave >> 1, wc = wave & 1;
    const int str = tid >> 2;
    const int stk = (tid & 3) * 8;
    load_lds16(&Ab[(size_t)str * 32 + stk],        &sA[tid * 8]);
    load_lds16(&Ab[(size_t)(str + 64) * 32 + stk], &sA[2048 + tid * 8]);
    load_lds16(&Bb[(size_t)str * 32 + stk],        &sB[tid * 8]);
    load_lds16(&Bb[(size_t)(str + 64) * 32 + stk], &sB[2048 + tid * 8]);
    __syncthreads();
    short8 af[4], bg[4];
    #pragma unroll
    for (int i = 0; i < 4; ++i)
        af[i] = *(const short8*)&sA[(wr * 64 + i * 16 + (lane & 15)) * 32 + (lane >> 4) * 8];
    #pragma unroll
    for (int j = 0; j < 4; ++j)
        bg[j] = *(const short8*)&sB[(wc * 64 + j * 16 + (lane & 15)) * 32 + (lane >> 4) * 8];
    f32x4 acc[4][4] = {};
    #pragma unroll
    for (int i = 0; i < 4; ++i)
        #pragma unroll
        for (int j = 0; j < 4; ++j)
            acc[i][j] = __builtin_amdgcn_mfma_f32_16x16x32_bf16(af[i], bg[j], acc[i][j], 0, 0, 0);

    float dpart[16] = {};
    #pragma unroll
    for (int i = 0; i < 4; ++i) {
        #pragma unroll
        for (int r = 0; r < 4; ++r) {
            const int rowloc = wr * 64 + i * 16 + (lane >> 4) * 4 + r;
            unsigned int w = 0;
            w = pk2_fp8<false>(exp2f(acc[i][0][r]), exp2f(acc[i][1][r]), w);
            w = pk2_fp8<true>(exp2f(acc[i][2][r]), exp2f(acc[i][3][r]), w);
            dpart[i * 4 + r] += DEC_FP8(w, 0) + DEC_FP8(w, 1) + DEC_FP8(w, 2) + DEC_FP8(w, 3);
            #pragma unroll
            for (int j = 0; j < 4; ++j) {
                const int colloc = wc * 64 + j * 16 + (lane & 15);
                Etile[rowloc * 128 + (colloc ^ ((rowloc & 7) << 4))] = (u8)(w >> (8 * j));
            }
        }
    }
    #pragma unroll
    for (int mask = 1; mask < 16; mask <<= 1)
        #pragma unroll
        for (int k = 0; k < 16; ++k)
            dpart[k] += __shfl_xor(dpart[k], mask, 64);
    if ((lane & 15) == 0) {
        #pragma unroll
        for (int i = 0; i < 4; ++i)
            #pragma unroll
            for (int r = 0; r < 4; ++r)
                Dsh[wc][wr * 64 + i * 16 + (lane >> 4) * 4 + r] = dpart[i * 4 + r];
    }
    __syncthreads();
    if (tid < 128)
        Dpart[((size_t)(b * 18 + mt)) * NHW + nBase + tid] = Dsh[0][tid] + Dsh[1][tid];
    #pragma unroll
    for (int rep = 0; rep < 4; ++rep) {
        const int row = wave * 32 + rep * 8 + (lane >> 3);
        const int slot = lane & 7;
        u8x16 v = *(const u8x16*)&Etile[row * 128 + ((slot ^ (row & 7)) << 4)];
        *(u8x16*)&E8[((size_t)b * NHW + nBase + row) * NHW + mBase + slot * 16] = v;
    }
}

// ---------------------------------------------------------------------------
// PV GEMM fp8, 128x128 tile, BK=128, chunk-XOR swizzle c^=(row&7).
// ---------------------------------------------------------------------------
__global__ __launch_bounds__(256)
void pv_gemm(const u8* __restrict__ vp8, const u8* __restrict__ E8,
             const float* __restrict__ Dpart, const float* __restrict__ attnw,
             const float* __restrict__ Ofold, const float* __restrict__ b2,
             float* __restrict__ out)
{
    __shared__ __align__(16) u8 sA[16384];
    __shared__ __align__(16) u8 sB[16384];
    __shared__ float DsumSh[128];
    __shared__ float DinvSh[128];
    const int tid = threadIdx.x;
    const int bid = blockIdx.x;
    const int xcd = bid & 7, slot = bid >> 3;
    const int b = xcd;
    const int nt = slot >> 2;
    const int ot = slot & 3;
    const int oBase = ot * 128, nBase = nt * 128;

    const u8* A8 = vp8 + ((size_t)b * NC + oBase) * NHW;
    const u8* B8 = E8  + ((size_t)b * NHW + nBase) * NHW;
    const int lane = tid & 63;
    const int wave = tid >> 6;
    const int wr = wave >> 1, wc = wave & 1;

    int srowS[4], sgofS[4];
    #pragma unroll
    for (int it = 0; it < 4; ++it) {
        const int cd = (wave * 4 + it) * 64 + lane;
        srowS[it] = cd >> 3;
        sgofS[it] = ((cd & 7) ^ ((cd >> 3) & 7)) * 16;
    }
    #define PV_STAGE(k0) { \
        _Pragma("unroll") \
        for (int it = 0; it < 4; ++it) { \
            load_lds16(&A8[(size_t)srowS[it] * NHW + (k0) + sgofS[it]], &sA[((wave * 4 + it) * 64 + lane) * 16]); \
            load_lds16(&B8[(size_t)srowS[it] * NHW + (k0) + sgofS[it]], &sB[((wave * 4 + it) * 64 + lane) * 16]); \
        } }

    u16* sAh = (u16*)sA;
    u16* sBh = (u16*)sB;
    if (tid < 128) {
        float s = 0.f;
        #pragma unroll
        for (int mt = 0; mt < 18; ++mt)
            s += Dpart[((size_t)(b * 18 + mt)) * NHW + nBase + tid];
        DsumSh[tid] = s;
        DinvSh[tid] = 1.f / s;
    }
    for (int idx = tid; idx < 128 * 32; idx += 256) {
        const int o = idx >> 5, s = idx & 31;
        float v = 0.f;
        if (s < 20) v = Ofold[((size_t)b * 768 + 256 + oBase + o) * NS + s];
        else if (s == 20) v = b2[oBase + o];
        sAh[idx] = f2b(v);
    }
    __syncthreads();
    for (int idx = tid; idx < 128 * 32; idx += 256) {
        const int n = idx >> 5, s = idx & 31;
        float v = 0.f;
        if (s <= 20) {
            const float ds = DsumSh[n];
            v = (s < 20) ? attnw[((size_t)b * NS + s) * NHW + nBase + n] * ds : ds;
        }
        sBh[idx] = f2b(v);
    }
    __syncthreads();

    f32x4 acc[4][4];
    {
        const f32x4 zero = {0.f, 0.f, 0.f, 0.f};
        short8 qf[4], afr[4];
        #pragma unroll
        for (int i = 0; i < 4; ++i)
            qf[i] = *(const short8*)&sAh[(wr * 64 + i * 16 + (lane & 15)) * 32 + (lane >> 4) * 8];
        #pragma unroll
        for (int j = 0; j < 4; ++j)
            afr[j] = *(const short8*)&sBh[(wc * 64 + j * 16 + (lane & 15)) * 32 + (lane >> 4) * 8];
        #pragma unroll
        for (int i = 0; i < 4; ++i)
            #pragma unroll
            for (int j = 0; j < 4; ++j)
                acc[i][j] = __builtin_amdgcn_mfma_f32_16x16x32_bf16(qf[i], afr[j], zero, 0, 0, 0);
    }

    const int krow_a = wr * 64 + (lane & 15);
    const int krow_b = wc * 64 + (lane & 15);
    const int khalf = ((lane >> 4) & 1) * 8;
    const int kc2   = (lane >> 5);

    for (int k0 = 0; k0 < NHW; k0 += 128) {
        __syncthreads();
        PV_STAGE(k0);
        __syncthreads();
        #pragma unroll
        for (int kk = 0; kk < 4; ++kk) {
            long af[4], bg[4];
            #pragma unroll
            for (int i = 0; i < 4; ++i) {
                const int row = krow_a + i * 16;
                const int c = (kk * 2 + kc2) ^ (row & 7);
                af[i] = *(const long*)&sA[row * 128 + c * 16 + khalf];
            }
            #pragma unroll
            for (int j = 0; j < 4; ++j) {
                const int row = krow_b + j * 16;
                const int c = (kk * 2 + kc2) ^ (row & 7);
                bg[j] = *(const long*)&sB[row * 128 + c * 16 + khalf];
            }
            #pragma unroll
            for (int i = 0; i < 4; ++i)
                #pragma unroll
                for (int j = 0; j < 4; ++j)
                    acc[i][j] = __builtin_amdgcn_mfma_f32_16x16x32_fp8_fp8(af[i], bg[j], acc[i][j], 0, 0, 0);
        }
    }
    #pragma unroll
    for (int i = 0; i < 4; ++i) {
        #pragma unroll
        for (int r = 0; r < 4; ++r) {
            const int rowloc = wr * 64 + i * 16 + (lane >> 4) * 4 + r;
            #pragma unroll
            for (int j = 0; j < 4; ++j) {
                const int colloc = wc * 64 + j * 16 + (lane & 15);
                out[((size_t)b * NC + oBase + rowloc) * NHW + nBase + colloc] =
                    acc[i][j][r] * DinvSh[colloc];
            }
        }
    }
    #undef PV_STAGE
}

// ---------------------------------------------------------------------------
// prep_all: fused independent prep work, branch on blockIdx range.
// ---------------------------------------------------------------------------
__global__ __launch_bounds__(256)
void prep_all(const float* __restrict__ key, u16* __restrict__ keyT,
              const float* __restrict__ fv_w, u16* __restrict__ fvT,
              const float* __restrict__ w1, const float* __restrict__ w1b,
              const float* __restrict__ w2, const float* __restrict__ w2b,
              const float* __restrict__ fvb, u16* __restrict__ wc2b,
              float* __restrict__ b2,
              const float* __restrict__ query, const float* __restrict__ wv_w,
              const float* __restrict__ wv_b, float* __restrict__ qw,
              float* __restrict__ qb,
              const float* __restrict__ fq, float* __restrict__ O)
{
    __shared__ __align__(16) char smem[44032];
    const int bid = blockIdx.x;
    const int tid = threadIdx.x;

    if (bid < 2368) {
        const float* src; u16* dst; int R, Cc, cBase, rBase, b;
        if (bid < 2304) {
            src = key; dst = keyT; R = NC; Cc = NHW;
            cBase = (bid % 36) * 64; rBase = ((bid / 36) % 8) * 64; b = bid / 288;
        } else {
            const int t2 = bid - 2304;
            src = fv_w; dst = fvT; R = 512; Cc = 512;
            cBase = (t2 % 8) * 64; rBase = (t2 / 8) * 64; b = 0;
        }
        u16 (*t)[72] = (u16(*)[72])smem;
        const float* sb = src + ((size_t)b * R + rBase) * Cc + cBase;
        const int ln = tid & 63;
        const int lr = tid >> 6;
        #pragma unroll
        for (int rr = 0; rr < 16; ++rr) {
            int r = lr + rr * 4;
            t[r][ln] = f2b(sb[(size_t)r * Cc + ln]);
        }
        __syncthreads();
        u16* ob = dst + ((size_t)b * Cc + cBase) * R + rBase;
        #pragma unroll
        for (int rep = 0; rep < 2; ++rep) {
            int slot = rep * 256 + tid;
            int cc = slot >> 3;
            int r8 = (slot & 7) * 8;
            u16x8 v;
            #pragma unroll
            for (int e = 0; e < 8; ++e) v[e] = t[r8 + e][cc];
            *(u16x8*)&ob[(size_t)cc * R + r8] = v;
        }
    } else if (bid < 2880) {
        const int o = bid - 2368;
        float* red = (float*)smem;
        float part = 0.f;
        for (int c = tid; c < 512; c += 256) {
            float v = w1[(size_t)o * 1024 + c] + w2[(size_t)o * 512 + c];
            wc2b[(size_t)o * 512 + c] = f2b(v);
            part += v * fvb[c];
        }
        #pragma unroll
        for (int off = 32; off > 0; off >>= 1) part += __shfl_down(part, off, 64);
        if ((tid & 63) == 0) red[tid >> 6] = part;
        __syncthreads();
        if (tid == 0) b2[o] = (red[0] + red[1]) + (red[2] + red[3]) + w1b[o] + w2b[o];
    } else if (bid < 3040) {
        const int t3 = bid - 2880;
        const int s = t3 % NS, b = t3 / NS;
        float* qs  = (float*)smem;
        float* red = qs + 512;
        qs[tid] = query[((size_t)b * NS + s) * NC + tid];
        qs[tid + 256] = query[((size_t)b * NS + s) * NC + tid + 256];
        __syncthreads();
        float a0 = 0.f, a1 = 0.f;
        for (int o = 0; o < NC; ++o) {
            float qv = qs[o];
            a0 += qv * wv_w[(size_t)o * NC + tid];
            a1 += qv * wv_w[(size_t)o * NC + tid + 256];
        }
        qw[((size_t)b * NS + s) * NC + tid] = a0;
        qw[((size_t)b * NS + s) * NC + tid + 256] = a1;
        float pb = qs[tid] * wv_b[tid] + qs[tid + 256] * wv_b[tid + 256];
        #pragma unroll
        for (int off = 32; off > 0; off >>= 1) pb += __shfl_down(pb, off, 64);
        if ((tid & 63) == 0) red[tid >> 6] = pb;
        __syncthreads();
        if (tid == 0) qb[b * NS + s] = (red[0] + red[1]) + (red[2] + red[3]);
    } else {
        const int t4 = bid - 3040;
        const int x = t4 % 48, b = t4 / 48;
        float (*qsh)[NC] = (float(*)[NC])smem;
        for (int idx = tid; idx < NS * NC; idx += 256)
            qsh[idx >> 9][idx & 511] = query[(size_t)b * NS * NC + idx];
        __syncthreads();
        const int row = x * 16 + (tid >> 4);
        const int ct = tid & 15;
        const float* wp = (row < 256) ? &fq[(size_t)row * NC]
                                      : &w1[(size_t)(row - 256) * 1024 + 512];
        float acc[NS] = {};
        #pragma unroll 4
        for (int i = 0; i < 32; ++i) {
            int c = ct + i * 16;
            float w = wp[c];
            #pragma unroll
            for (int s = 0; s < NS; ++s) acc[s] += w * qsh[s][c];
        }
        #pragma unroll
        for (int off = 1; off < 16; off <<= 1)
            #pragma unroll
            for (int s = 0; s < NS; ++s) acc[s] += __shfl_xor(acc[s], off, 64);
        if (ct == 0) {
            #pragma unroll
            for (int s = 0; s < NS; ++s)
                O[((size_t)b * 768 + row) * NS + s] = acc[s];
        }
    }
}

// ---------------------------------------------------------------------------
// mid_all: fold_g (64 blocks) + wcv GEMM (16 blocks), both dep only on prep_all.
// ---------------------------------------------------------------------------
__global__ __launch_bounds__(256)
void mid_all(const float* __restrict__ O, const float* __restrict__ fk,
             const float* __restrict__ fq_b, const float* __restrict__ fk_b,
             float* __restrict__ g, float* __restrict__ h,
             const u16* __restrict__ wc2b, const u16* __restrict__ fvT,
             u16* __restrict__ wcv)
{
    __shared__ __align__(16) char smem[32768];
    const int bid = blockIdx.x;
    const int tid = threadIdx.x;
    if (bid < 64) {
        const int xb = bid & 7, b = bid >> 3;
        float (*fqqsh)[21] = (float(*)[21])smem;
        float* fqbsh = (float*)(smem + 21504);
        float (*red)[64][7] = (float(*)[64][7])(smem + 22528);
        for (int idx = tid; idx < 256 * NS; idx += 256) {
            int kc = idx / NS, s = idx - kc * NS;
            fqqsh[kc][s] = O[((size_t)b * 768 + kc) * NS + s];
        }
        fqbsh[tid] = fq_b[tid];
        __syncthreads();
        const int wave = tid >> 6, lane = tid & 63;
        const int c = xb * 64 + lane;
        float acc[21] = {};
        for (int i = 0; i < 64; ++i) {
            int kc = wave * 64 + i;
            float w = fk[(size_t)kc * NC + c];
            #pragma unroll
            for (int s = 0; s < NS; ++s) acc[s] += w * fqqsh[kc][s];
            acc[20] += w * fqbsh[kc];
        }
        #pragma unroll
        for (int r = 0; r < 3; ++r) {
            if (wave > 0) {
                #pragma unroll
                for (int k = 0; k < 7; ++k) red[wave - 1][lane][k] = acc[r * 7 + k];
            }
            __syncthreads();
            if (wave == 0) {
                #pragma unroll
                for (int k = 0; k < 7; ++k)
                    acc[r * 7 + k] += red[0][lane][k] + red[1][lane][k] + red[2][lane][k];
            }
            __syncthreads();
        }
        if (wave == 0) {
            float* gp = &g[((size_t)b * NC + c) * 24];
            #pragma unroll
            for (int s = 0; s < 21; ++s) gp[s] = acc[s] * SCL;
            gp[21] = gp[22] = gp[23] = 0.f;
        }
        if (xb == 0 && tid < 21) {
            float hh = 0.f;
            for (int kc = 0; kc < 256; ++kc)
                hh += fk_b[kc] * (tid < 20 ? fqqsh[kc][tid] : fqbsh[kc]);
            h[b * 24 + tid] = hh * SCL;
        }
    } else {
        const int t = bid - 64;
        const int nBase = (t & 3) * 128;
        const int mBase = (t >> 2) * 128;
        u16* sA = (u16*)smem;
        u16* sB = (u16*)(smem + 16384);
        gemm_body(wc2b + (size_t)mBase * 512, 512, fvT + (size_t)nBase * 512, 512,
                  wcv, 512, 512, 1.f, 0, mBase, nBase, sA, sB);
    }
}

// ---------------------------------------------------------------------------
// Fused key scan: word-attn logits (fp32) AND ks logits in one pass over key.
// ---------------------------------------------------------------------------
__global__ __launch_bounds__(256)
void scan_wk(const float* __restrict__ key, const float* __restrict__ qw,
             const float* __restrict__ qb, const int* __restrict__ wid,
             const float* __restrict__ g, const float* __restrict__ h,
             float* __restrict__ attnw, u16* __restrict__ attnwT,
             u16* __restrict__ ks)
{
    __shared__ float qshT[NC][20];
    __shared__ u16 gshb[NC][22];
    __shared__ float red[3][64][7];
    __shared__ float msk[20], qbs[20], hsh[21];
    const int b = blockIdx.y;
    const int tid = threadIdx.x;
    const float* qwb = qw + (size_t)b * NS * NC;
    for (int idx = tid; idx < NC * 20; idx += 256) {
        int c = idx / 20, s = idx - c * 20;
        qshT[c][s] = qwb[s * NC + c];
    }
    for (int idx = tid; idx < NC * 21; idx += 256) {
        int c = idx / 21, s = idx - c * 21;
        gshb[c][s] = f2b(g[((size_t)b * NC + c) * 24 + s]);
    }
    if (tid < 20) {
        msk[tid] = (wid[b * NS + tid] != 0) ? 1.f : 0.f;
        qbs[tid] = qb[b * NS + tid];
    }
    if (tid < 21) hsh[tid] = h[b * 24 + tid];
    __syncthreads();
    const int wave = tid >> 6, lane = tid & 63;
    const int n = blockIdx.x * 64 + lane;
    const int cbase = wave * 128;
    const float* kp = key + (size_t)b * NC * NHW + n;
    float acc[41];
    #pragma unroll
    for (int s = 0; s < 41; ++s)
        acc[s] = (wave == 0) ? (s < 20 ? qbs[s] : hsh[s - 20]) : 0.f;
    #pragma unroll 4
    for (int ci = 0; ci < 128; ++ci) {
        const int c = cbase + ci;
        float kv = kp[(size_t)c * NHW];
        #pragma unroll
        for (int s = 0; s < 20; ++s) acc[s] += qshT[c][s] * kv;
        #pragma unroll
        for (int s = 0; s < 21; ++s) acc[20 + s] += b2f(gshb[c][s]) * kv;
    }
    #pragma unroll
    for (int r = 0; r < 6; ++r) {
        if (wave > 0) {
            #pragma unroll
            for (int k = 0; k < 7; ++k) {
                int idx = r * 7 + k;
                if (idx < 41) red[wave - 1][lane][k] = acc[idx];
            }
        }
        __syncthreads();
        if (wave == 0) {
            #pragma unroll
            for (int k = 0; k < 7; ++k) {
                int idx = r * 7 + k;
                if (idx < 41)
                    acc[idx] += red[0][lane][k] + red[1][lane][k] + red[2][lane][k];
            }
        }
        __syncthreads();
    }
    if (wave == 0) {
        float mx = acc[0];
        #pragma unroll
        for (int s = 1; s < 20; ++s) mx = fmaxf(mx, acc[s]);
        float msum = 0.f;
        #pragma unroll
        for (int s = 0; s < 20; ++s) {
            acc[s] = __expf(acc[s] - mx) * msk[s];
            msum += acc[s];
        }
        const float rr = 1.f / msum;
        u16 row32[32];
        #pragma unroll
        for (int s = 0; s < 20; ++s) {
            float a = acc[s] * rr;
            attnw[((size_t)b * NS + s) * NHW + n] = a;
            row32[s] = f2b(a);
        }
        row32[20] = 0x3F80;
        #pragma unroll
        for (int s = 21; s < 32; ++s) row32[s] = 0;
        u16* dp = attnwT + ((size_t)b * NHW + n) * 32;
        #pragma unroll
        for (int q = 0; q < 4; ++q)
            *(u16x8*)&dp[q * 8] = *(u16x8*)&row32[q * 8];
        u16 rk[32];
        #pragma unroll
        for (int s = 0; s < 21; ++s) rk[s] = f2b(acc[20 + s]);
        #pragma unroll
        for (int s = 21; s < 32; ++s) rk[s] = 0;
        u16* kp2 = ks + ((size_t)b * NHW + n) * 32;
        #pragma unroll
        for (int q = 0; q < 4; ++q)
            *(u16x8*)&kp2[q * 8] = *(u16x8*)&rk[q * 8];
    }
}

extern "C" void kernel_launch(void* const* d_in, const int* in_sizes, int n_in,
                              void* d_out, int out_size, void* d_ws, size_t ws_size,
                              hipStream_t stream)
{
    const float* key   = (const float*)d_in[0];
    const float* query = (const float*)d_in[1];
    const int*   wid   = (const int*)d_in[2];
    const float* wv_w  = (const float*)d_in[3];
    const float* wv_b  = (const float*)d_in[4];
    const float* fk_w  = (const float*)d_in[5];
    const float* fk_b  = (const float*)d_in[6];
    const float* fq_w  = (const float*)d_in[7];
    const float* fq_b  = (const float*)d_in[8];
    const float* fv_w  = (const float*)d_in[9];
    const float* fv_b  = (const float*)d_in[10];
    const float* w1_w  = (const float*)d_in[11];
    const float* w1_b  = (const float*)d_in[12];
    const float* w2_w  = (const float*)d_in[13];
    const float* w2_b  = (const float*)d_in[14];
    float* out = (float*)d_out;

    char* p = (char*)d_ws;
    u16*   keyT   = (u16*)p;   p += (size_t)NB * NHW * NC * 2;    // 18.9 MB
    u8*    E8     = (u8*)p;    p += (size_t)NB * NHW * NHW;       // 42.5 MB
    u8*    vp8    = (u8*)p;    p += (size_t)NB * NC * NHW;        // 9.4 MB
    u16*   fvT    = (u16*)p;   p += (size_t)512 * 512 * 2;
    u16*   wc2b   = (u16*)p;   p += (size_t)512 * 512 * 2;
    u16*   wcv    = (u16*)p;   p += (size_t)512 * 512 * 2;
    u16*   attnwT = (u16*)p;   p += (size_t)NB * NHW * 32 * 2;
    u16*   ksb    = (u16*)p;   p += (size_t)NB * NHW * 32 * 2;
    float* attnw  = (float*)p; p += (size_t)NB * NS * NHW * 4;
    float* qw     = (float*)p; p += (size_t)NB * NS * NC * 4;
    float* qbuf   = (float*)p; p += (size_t)NB * NS * 4;
    float* Ofold  = (float*)p; p += (size_t)NB * 768 * NS * 4;
    float* g      = (float*)p; p += (size_t)NB * NC * 24 * 4;
    float* h      = (float*)p; p += (size_t)NB * 24 * 4;
    float* b2     = (float*)p; p += (size_t)512 * 4;
    float* Dpart  = (float*)p; p += (size_t)NB * 18 * NHW * 4;

    dim3 blk(256);

    // 1. fused prep: keyT + fvT + wc2/b2 + qw/qb + Ofold
    prep_all<<<dim3(3424), blk, 0, stream>>>(
        key, keyT, fv_w, fvT, w1_w, w1_b, w2_w, w2_b, fv_b, wc2b, b2,
        query, wv_w, wv_b, qw, qbuf, fq_w, Ofold);
    // 2. fold_g + wcv GEMM
    mid_all<<<dim3(80), blk, 0, stream>>>(
        Ofold, fk_w, fq_b, fk_b, g, h, wc2b, fvT, wcv);
    // 3a. scan_wk (own resources: 69 KB LDS)
    scan_wk<<<dim3(36, NB), blk, 0, stream>>>(key, qw, qbuf, wid, g, h,
                                              attnw, attnwT, ksb);
    // 3b. vproj GEMM (own resources: 32 KB LDS, 76 VGPR)
    vproj_gemm<<<dim3(576), blk, 0, stream>>>(wcv, keyT, vp8);
    // 4. E (fp8) + partial row sums
    e_gemm<<<dim3(18, 18, NB), blk, 0, stream>>>(attnwT, ksb, E8, Dpart);
    // 5. PV fp8 BK=128 with low-rank accumulator init
    pv_gemm<<<dim3(576), blk, 0, stream>>>(vp8, E8, Dpart, attnw, Ofold, b2, out);
}

// Round 26
// 194.300 us; speedup vs baseline: 1.4035x; 1.0233x over previous
//
#include <hip/hip_runtime.h>

#define NHW 2304
#define NB  8
#define NS  20
#define NC  512
#define SCL 0.09016844005555897f   // log2(e)/16

typedef unsigned short u16;
typedef unsigned char u8;
typedef short short8 __attribute__((ext_vector_type(8)));
typedef unsigned short u16x8 __attribute__((ext_vector_type(8)));
typedef u8 u8x16 __attribute__((ext_vector_type(16)));
typedef float f32x4 __attribute__((ext_vector_type(4)));

__device__ __forceinline__ float b2f(u16 u) {
    unsigned int v = ((unsigned int)u) << 16;
    return __builtin_bit_cast(float, v);
}
__device__ __forceinline__ u16 f2b(float f) {
    unsigned int u = __builtin_bit_cast(unsigned int, f);
    u += 0x7fffu + ((u >> 16) & 1u);
    return (u16)(u >> 16);
}

// ---- software fp8 e4m3fn fallback ----
__device__ __forceinline__ u8 f2e4_sw(float f) {
    unsigned int u = __builtin_bit_cast(unsigned int, f);
    u8 sign = (u >> 24) & 0x80;
    unsigned int a = u & 0x7FFFFFFFu;
    if (a >= 0x43E00000u) return sign | 0x7E;
    int e = (int)(a >> 23) - 127;
    unsigned int m = (a & 0x7FFFFF) | 0x800000;
    int ne = e + 7;
    if (ne <= 0) {
        int shift = 21 - ne;
        if (shift > 24) return sign;
        unsigned int q = m >> shift;
        unsigned int rem = m & ((1u << shift) - 1);
        unsigned int half = 1u << (shift - 1);
        q += (rem > half) || (rem == half && (q & 1));
        return sign | (u8)q;
    }
    unsigned int q = m >> 20;
    unsigned int rem = m & 0xFFFFFu;
    q += (rem > 0x80000u) || (rem == 0x80000u && (q & 1));
    if (q >= 16) { q >>= 1; ne++; }
    if (ne >= 16 || (ne == 15 && q == 15)) return sign | 0x7E;
    return sign | (u8)((ne << 3) | (q & 7));
}
__device__ __forceinline__ float e42f_sw(u8 v) {
    int e = (v >> 3) & 15;
    int m = v & 7;
    float r;
    if (e == 0) r = (float)m * 0.001953125f;
    else {
        unsigned int bits = ((unsigned int)(e + 120) << 23) | ((unsigned int)m << 20);
        r = __builtin_bit_cast(float, bits);
    }
    return (v & 0x80) ? -r : r;
}

// ---- hardware fp8 conversion (gfx950); hi/sel must be immediates ----
#if defined(__has_builtin)
#if __has_builtin(__builtin_amdgcn_cvt_pk_fp8_f32) && __has_builtin(__builtin_amdgcn_cvt_f32_fp8)
#define HW_FP8 1
#endif
#endif

template<bool HI>
__device__ __forceinline__ unsigned int pk2_fp8(float a, float b, unsigned int old) {
#ifdef HW_FP8
    return (unsigned int)__builtin_amdgcn_cvt_pk_fp8_f32(a, b, (int)old, HI);
#else
    unsigned int lo = (unsigned int)f2e4_sw(a) | ((unsigned int)f2e4_sw(b) << 8);
    return HI ? ((old & 0x0000FFFFu) | (lo << 16)) : ((old & 0xFFFF0000u) | lo);
#endif
}
#ifdef HW_FP8
#define DEC_FP8(w, sel) __builtin_amdgcn_cvt_f32_fp8((int)(w), (sel))
#else
#define DEC_FP8(w, sel) e42f_sw((u8)((w) >> (8 * (sel))))
#endif

__device__ __forceinline__ void load_lds16(const void* g, void* l) {
    __builtin_amdgcn_global_load_lds((const __attribute__((address_space(1))) void*)g,
                                     (__attribute__((address_space(3))) void*)l, 16, 0, 0);
}

// ---------------------------------------------------------------------------
// bf16 NT GEMM body (128x128 tile, BK=64, bank-swizzled LDS), no bias.
// Requires sA/sB each 8192 u16 (16 KB). out_mode: 0 bf16, 2 fp8.
// ---------------------------------------------------------------------------
__device__ __forceinline__ void gemm_body(
    const u16* __restrict__ Ab, int lda, const u16* __restrict__ Bb, int ldb,
    void* __restrict__ Cb, int ldc, int K, float scale, int out_mode,
    int mBase, int nBase, u16* sA, u16* sB)
{
    const int tid = threadIdx.x;
    const int lane = tid & 63;
    const int wave = tid >> 6;
    const int wr = wave >> 1, wc = wave & 1;
    const int srow[4] = { ((wave * 4 + 0) & 7) * 16 + (lane >> 2),
                          ((wave * 4 + 1) & 7) * 16 + (lane >> 2),
                          ((wave * 4 + 2) & 7) * 16 + (lane >> 2),
                          ((wave * 4 + 3) & 7) * 16 + (lane >> 2) };
    const int swzw = ((lane & 3) ^ ((lane >> 3) & 3)) * 8;
    const int rsw  = ((lane >> 4) ^ ((lane >> 1) & 3)) * 8;
    f32x4 acc[4][4] = {};
    for (int k0 = 0; k0 < K; k0 += 64) {
        __syncthreads();
        #pragma unroll
        for (int it = 0; it < 4; ++it) {
            const int chunk = wave * 4 + it;
            const int kofs = (chunk >> 3) * 32 + swzw;
            load_lds16(&Ab[(size_t)srow[it] * lda + k0 + kofs], &sA[chunk * 512 + lane * 8]);
            load_lds16(&Bb[(size_t)srow[it] * ldb + k0 + kofs], &sB[chunk * 512 + lane * 8]);
        }
        __syncthreads();
        #pragma unroll
        for (int kk = 0; kk < 2; ++kk) {
            short8 af[4], bg[4];
            #pragma unroll
            for (int i = 0; i < 4; ++i)
                af[i] = *(const short8*)&sA[kk * 4096 + (wr * 64 + i * 16 + (lane & 15)) * 32 + rsw];
            #pragma unroll
            for (int j = 0; j < 4; ++j)
                bg[j] = *(const short8*)&sB[kk * 4096 + (wc * 64 + j * 16 + (lane & 15)) * 32 + rsw];
            #pragma unroll
            for (int i = 0; i < 4; ++i)
                #pragma unroll
                for (int j = 0; j < 4; ++j)
                    acc[i][j] = __builtin_amdgcn_mfma_f32_16x16x32_bf16(af[i], bg[j], acc[i][j], 0, 0, 0);
        }
    }
    const int r0 = mBase + wr * 64 + (lane >> 4) * 4;
    const int c0 = nBase + wc * 64 + (lane & 15);
    #pragma unroll
    for (int i = 0; i < 4; ++i) {
        #pragma unroll
        for (int r = 0; r < 4; ++r) {
            const int row = r0 + i * 16 + r;
            if (out_mode == 2) {
                float vv[4];
                #pragma unroll
                for (int j = 0; j < 4; ++j) vv[j] = acc[i][j][r] * scale;
                unsigned int w = 0;
                w = pk2_fp8<false>(vv[0], vv[1], w);
                w = pk2_fp8<true>(vv[2], vv[3], w);
                #pragma unroll
                for (int j = 0; j < 4; ++j)
                    ((u8*)Cb)[(size_t)row * ldc + c0 + j * 16] = (u8)(w >> (8 * j));
            } else {
                #pragma unroll
                for (int j = 0; j < 4; ++j)
                    ((u16*)Cb)[(size_t)row * ldc + c0 + j * 16] = f2b(acc[i][j][r] * scale);
            }
        }
    }
}

// ---------------------------------------------------------------------------
// tail_a: vproj GEMM (576 blocks) + E-GEMM (2592 blocks), independent,
// resource-compatible (32 KB vs 33.8 KB LDS, similar VGPR).
// ---------------------------------------------------------------------------
__global__ __launch_bounds__(256)
void tail_a(const u16* __restrict__ wcv, const u16* __restrict__ keyT,
            u8* __restrict__ vp8,
            const u16* __restrict__ attnwT, const u16* __restrict__ ks,
            u8* __restrict__ E8, float* __restrict__ Dpart)
{
    __shared__ __align__(16) char smem[33792];
    const int bid = blockIdx.x;
    const int tid = threadIdx.x;
    if (bid < 576) {
        // ---- vproj branch: sA/sB each 16 KB ----
        u16* sA = (u16*)smem;
        u16* sB = (u16*)(smem + 16384);
        const int t = bid;
        const int nBase = (t % 18) * 128;
        const int mBase = ((t / 18) & 3) * 128;
        const int bb = t / 72;
        gemm_body(wcv + (size_t)mBase * 512, 512,
                  keyT + (size_t)bb * NHW * 512 + (size_t)nBase * 512, 512,
                  vp8 + (size_t)bb * NC * NHW, NHW, 512, 1.f, 2,
                  mBase, nBase, sA, sB);
    } else {
        // ---- e_gemm branch: sA 8K | sB 8K | Etile 16K | Dsh 1K ----
        u16* sA = (u16*)smem;                       // [128*32] u16
        u16* sB = (u16*)(smem + 8192);              // [128*32] u16
        u8*  Etile = (u8*)(smem + 16384);           // [128*128]
        float (*Dsh)[128] = (float(*)[128])(smem + 32768);
        const int t = bid - 576;
        const int mt = t % 18;
        const int nt = (t / 18) % 18;
        const int b  = t / 324;
        const int mBase = mt * 128, nBase = nt * 128;
        const u16* Ab = attnwT + ((size_t)b * NHW + nBase) * 32;
        const u16* Bb = ks     + ((size_t)b * NHW + mBase) * 32;
        const int lane = tid & 63;
        const int wave = tid >> 6;
        const int wr = wave >> 1, wc = wave & 1;
        const int str = tid >> 2;
        const int stk = (tid & 3) * 8;
        load_lds16(&Ab[(size_t)str * 32 + stk],        &sA[tid * 8]);
        load_lds16(&Ab[(size_t)(str + 64) * 32 + stk], &sA[2048 + tid * 8]);
        load_lds16(&Bb[(size_t)str * 32 + stk],        &sB[tid * 8]);
        load_lds16(&Bb[(size_t)(str + 64) * 32 + stk], &sB[2048 + tid * 8]);
        __syncthreads();
        short8 af[4], bg[4];
        #pragma unroll
        for (int i = 0; i < 4; ++i)
            af[i] = *(const short8*)&sA[(wr * 64 + i * 16 + (lane & 15)) * 32 + (lane >> 4) * 8];
        #pragma unroll
        for (int j = 0; j < 4; ++j)
            bg[j] = *(const short8*)&sB[(wc * 64 + j * 16 + (lane & 15)) * 32 + (lane >> 4) * 8];
        f32x4 acc[4][4] = {};
        #pragma unroll
        for (int i = 0; i < 4; ++i)
            #pragma unroll
            for (int j = 0; j < 4; ++j)
                acc[i][j] = __builtin_amdgcn_mfma_f32_16x16x32_bf16(af[i], bg[j], acc[i][j], 0, 0, 0);

        float dpart[16] = {};
        #pragma unroll
        for (int i = 0; i < 4; ++i) {
            #pragma unroll
            for (int r = 0; r < 4; ++r) {
                const int rowloc = wr * 64 + i * 16 + (lane >> 4) * 4 + r;
                unsigned int w = 0;
                w = pk2_fp8<false>(exp2f(acc[i][0][r]), exp2f(acc[i][1][r]), w);
                w = pk2_fp8<true>(exp2f(acc[i][2][r]), exp2f(acc[i][3][r]), w);
                dpart[i * 4 + r] += DEC_FP8(w, 0) + DEC_FP8(w, 1) + DEC_FP8(w, 2) + DEC_FP8(w, 3);
                #pragma unroll
                for (int j = 0; j < 4; ++j) {
                    const int colloc = wc * 64 + j * 16 + (lane & 15);
                    Etile[rowloc * 128 + (colloc ^ ((rowloc & 7) << 4))] = (u8)(w >> (8 * j));
                }
            }
        }
        #pragma unroll
        for (int mask = 1; mask < 16; mask <<= 1)
            #pragma unroll
            for (int k = 0; k < 16; ++k)
                dpart[k] += __shfl_xor(dpart[k], mask, 64);
        if ((lane & 15) == 0) {
            #pragma unroll
            for (int i = 0; i < 4; ++i)
                #pragma unroll
                for (int r = 0; r < 4; ++r)
                    Dsh[wc][wr * 64 + i * 16 + (lane >> 4) * 4 + r] = dpart[i * 4 + r];
        }
        __syncthreads();
        if (tid < 128)
            Dpart[((size_t)(b * 18 + mt)) * NHW + nBase + tid] = Dsh[0][tid] + Dsh[1][tid];
        #pragma unroll
        for (int rep = 0; rep < 4; ++rep) {
            const int row = wave * 32 + rep * 8 + (lane >> 3);
            const int slot = lane & 7;
            u8x16 v = *(const u8x16*)&Etile[row * 128 + ((slot ^ (row & 7)) << 4)];
            *(u8x16*)&E8[((size_t)b * NHW + nBase + row) * NHW + mBase + slot * 16] = v;
        }
    }
}

// ---------------------------------------------------------------------------
// PV GEMM fp8, 128x128 tile, BK=128, chunk-XOR swizzle c^=(row&7).
// ---------------------------------------------------------------------------
__global__ __launch_bounds__(256)
void pv_gemm(const u8* __restrict__ vp8, const u8* __restrict__ E8,
             const float* __restrict__ Dpart, const float* __restrict__ attnw,
             const float* __restrict__ Ofold, const float* __restrict__ b2,
             float* __restrict__ out)
{
    __shared__ __align__(16) u8 sA[16384];
    __shared__ __align__(16) u8 sB[16384];
    __shared__ float DsumSh[128];
    __shared__ float DinvSh[128];
    const int tid = threadIdx.x;
    const int bid = blockIdx.x;
    const int xcd = bid & 7, slot = bid >> 3;
    const int b = xcd;
    const int nt = slot >> 2;
    const int ot = slot & 3;
    const int oBase = ot * 128, nBase = nt * 128;

    const u8* A8 = vp8 + ((size_t)b * NC + oBase) * NHW;
    const u8* B8 = E8  + ((size_t)b * NHW + nBase) * NHW;
    const int lane = tid & 63;
    const int wave = tid >> 6;
    const int wr = wave >> 1, wc = wave & 1;

    int srowS[4], sgofS[4];
    #pragma unroll
    for (int it = 0; it < 4; ++it) {
        const int cd = (wave * 4 + it) * 64 + lane;
        srowS[it] = cd >> 3;
        sgofS[it] = ((cd & 7) ^ ((cd >> 3) & 7)) * 16;
    }
    #define PV_STAGE(k0) { \
        _Pragma("unroll") \
        for (int it = 0; it < 4; ++it) { \
            load_lds16(&A8[(size_t)srowS[it] * NHW + (k0) + sgofS[it]], &sA[((wave * 4 + it) * 64 + lane) * 16]); \
            load_lds16(&B8[(size_t)srowS[it] * NHW + (k0) + sgofS[it]], &sB[((wave * 4 + it) * 64 + lane) * 16]); \
        } }

    u16* sAh = (u16*)sA;
    u16* sBh = (u16*)sB;
    if (tid < 128) {
        float s = 0.f;
        #pragma unroll
        for (int mt = 0; mt < 18; ++mt)
            s += Dpart[((size_t)(b * 18 + mt)) * NHW + nBase + tid];
        DsumSh[tid] = s;
        DinvSh[tid] = 1.f / s;
    }
    for (int idx = tid; idx < 128 * 32; idx += 256) {
        const int o = idx >> 5, s = idx & 31;
        float v = 0.f;
        if (s < 20) v = Ofold[((size_t)b * 768 + 256 + oBase + o) * NS + s];
        else if (s == 20) v = b2[oBase + o];
        sAh[idx] = f2b(v);
    }
    __syncthreads();
    for (int idx = tid; idx < 128 * 32; idx += 256) {
        const int n = idx >> 5, s = idx & 31;
        float v = 0.f;
        if (s <= 20) {
            const float ds = DsumSh[n];
            v = (s < 20) ? attnw[((size_t)b * NS + s) * NHW + nBase + n] * ds : ds;
        }
        sBh[idx] = f2b(v);
    }
    __syncthreads();

    f32x4 acc[4][4];
    {
        const f32x4 zero = {0.f, 0.f, 0.f, 0.f};
        short8 qf[4], afr[4];
        #pragma unroll
        for (int i = 0; i < 4; ++i)
            qf[i] = *(const short8*)&sAh[(wr * 64 + i * 16 + (lane & 15)) * 32 + (lane >> 4) * 8];
        #pragma unroll
        for (int j = 0; j < 4; ++j)
            afr[j] = *(const short8*)&sBh[(wc * 64 + j * 16 + (lane & 15)) * 32 + (lane >> 4) * 8];
        #pragma unroll
        for (int i = 0; i < 4; ++i)
            #pragma unroll
            for (int j = 0; j < 4; ++j)
                acc[i][j] = __builtin_amdgcn_mfma_f32_16x16x32_bf16(qf[i], afr[j], zero, 0, 0, 0);
    }

    const int krow_a = wr * 64 + (lane & 15);
    const int krow_b = wc * 64 + (lane & 15);
    const int khalf = ((lane >> 4) & 1) * 8;
    const int kc2   = (lane >> 5);

    for (int k0 = 0; k0 < NHW; k0 += 128) {
        __syncthreads();
        PV_STAGE(k0);
        __syncthreads();
        #pragma unroll
        for (int kk = 0; kk < 4; ++kk) {
            long af[4], bg[4];
            #pragma unroll
            for (int i = 0; i < 4; ++i) {
                const int row = krow_a + i * 16;
                const int c = (kk * 2 + kc2) ^ (row & 7);
                af[i] = *(const long*)&sA[row * 128 + c * 16 + khalf];
            }
            #pragma unroll
            for (int j = 0; j < 4; ++j) {
                const int row = krow_b + j * 16;
                const int c = (kk * 2 + kc2) ^ (row & 7);
                bg[j] = *(const long*)&sB[row * 128 + c * 16 + khalf];
            }
            #pragma unroll
            for (int i = 0; i < 4; ++i)
                #pragma unroll
                for (int j = 0; j < 4; ++j)
                    acc[i][j] = __builtin_amdgcn_mfma_f32_16x16x32_fp8_fp8(af[i], bg[j], acc[i][j], 0, 0, 0);
        }
    }
    #pragma unroll
    for (int i = 0; i < 4; ++i) {
        #pragma unroll
        for (int r = 0; r < 4; ++r) {
            const int rowloc = wr * 64 + i * 16 + (lane >> 4) * 4 + r;
            #pragma unroll
            for (int j = 0; j < 4; ++j) {
                const int colloc = wc * 64 + j * 16 + (lane & 15);
                out[((size_t)b * NC + oBase + rowloc) * NHW + nBase + colloc] =
                    acc[i][j][r] * DinvSh[colloc];
            }
        }
    }
    #undef PV_STAGE
}

// ---------------------------------------------------------------------------
// prep_all: fused independent prep work, branch on blockIdx range.
// ---------------------------------------------------------------------------
__global__ __launch_bounds__(256)
void prep_all(const float* __restrict__ key, u16* __restrict__ keyT,
              const float* __restrict__ fv_w, u16* __restrict__ fvT,
              const float* __restrict__ w1, const float* __restrict__ w1b,
              const float* __restrict__ w2, const float* __restrict__ w2b,
              const float* __restrict__ fvb, u16* __restrict__ wc2b,
              float* __restrict__ b2,
              const float* __restrict__ query, const float* __restrict__ wv_w,
              const float* __restrict__ wv_b, float* __restrict__ qw,
              float* __restrict__ qb,
              const float* __restrict__ fq, float* __restrict__ O)
{
    __shared__ __align__(16) char smem[44032];
    const int bid = blockIdx.x;
    const int tid = threadIdx.x;

    if (bid < 2368) {
        const float* src; u16* dst; int R, Cc, cBase, rBase, b;
        if (bid < 2304) {
            src = key; dst = keyT; R = NC; Cc = NHW;
            cBase = (bid % 36) * 64; rBase = ((bid / 36) % 8) * 64; b = bid / 288;
        } else {
            const int t2 = bid - 2304;
            src = fv_w; dst = fvT; R = 512; Cc = 512;
            cBase = (t2 % 8) * 64; rBase = (t2 / 8) * 64; b = 0;
        }
        u16 (*t)[72] = (u16(*)[72])smem;
        const float* sb = src + ((size_t)b * R + rBase) * Cc + cBase;
        const int ln = tid & 63;
        const int lr = tid >> 6;
        #pragma unroll
        for (int rr = 0; rr < 16; ++rr) {
            int r = lr + rr * 4;
            t[r][ln] = f2b(sb[(size_t)r * Cc + ln]);
        }
        __syncthreads();
        u16* ob = dst + ((size_t)b * Cc + cBase) * R + rBase;
        #pragma unroll
        for (int rep = 0; rep < 2; ++rep) {
            int slot = rep * 256 + tid;
            int cc = slot >> 3;
            int r8 = (slot & 7) * 8;
            u16x8 v;
            #pragma unroll
            for (int e = 0; e < 8; ++e) v[e] = t[r8 + e][cc];
            *(u16x8*)&ob[(size_t)cc * R + r8] = v;
        }
    } else if (bid < 2880) {
        const int o = bid - 2368;
        float* red = (float*)smem;
        float part = 0.f;
        for (int c = tid; c < 512; c += 256) {
            float v = w1[(size_t)o * 1024 + c] + w2[(size_t)o * 512 + c];
            wc2b[(size_t)o * 512 + c] = f2b(v);
            part += v * fvb[c];
        }
        #pragma unroll
        for (int off = 32; off > 0; off >>= 1) part += __shfl_down(part, off, 64);
        if ((tid & 63) == 0) red[tid >> 6] = part;
        __syncthreads();
        if (tid == 0) b2[o] = (red[0] + red[1]) + (red[2] + red[3]) + w1b[o] + w2b[o];
    } else if (bid < 3040) {
        const int t3 = bid - 2880;
        const int s = t3 % NS, b = t3 / NS;
        float* qs  = (float*)smem;
        float* red = qs + 512;
        qs[tid] = query[((size_t)b * NS + s) * NC + tid];
        qs[tid + 256] = query[((size_t)b * NS + s) * NC + tid + 256];
        __syncthreads();
        float a0 = 0.f, a1 = 0.f;
        for (int o = 0; o < NC; ++o) {
            float qv = qs[o];
            a0 += qv * wv_w[(size_t)o * NC + tid];
            a1 += qv * wv_w[(size_t)o * NC + tid + 256];
        }
        qw[((size_t)b * NS + s) * NC + tid] = a0;
        qw[((size_t)b * NS + s) * NC + tid + 256] = a1;
        float pb = qs[tid] * wv_b[tid] + qs[tid + 256] * wv_b[tid + 256];
        #pragma unroll
        for (int off = 32; off > 0; off >>= 1) pb += __shfl_down(pb, off, 64);
        if ((tid & 63) == 0) red[tid >> 6] = pb;
        __syncthreads();
        if (tid == 0) qb[b * NS + s] = (red[0] + red[1]) + (red[2] + red[3]);
    } else {
        const int t4 = bid - 3040;
        const int x = t4 % 48, b = t4 / 48;
        float (*qsh)[NC] = (float(*)[NC])smem;
        for (int idx = tid; idx < NS * NC; idx += 256)
            qsh[idx >> 9][idx & 511] = query[(size_t)b * NS * NC + idx];
        __syncthreads();
        const int row = x * 16 + (tid >> 4);
        const int ct = tid & 15;
        const float* wp = (row < 256) ? &fq[(size_t)row * NC]
                                      : &w1[(size_t)(row - 256) * 1024 + 512];
        float acc[NS] = {};
        #pragma unroll 4
        for (int i = 0; i < 32; ++i) {
            int c = ct + i * 16;
            float w = wp[c];
            #pragma unroll
            for (int s = 0; s < NS; ++s) acc[s] += w * qsh[s][c];
        }
        #pragma unroll
        for (int off = 1; off < 16; off <<= 1)
            #pragma unroll
            for (int s = 0; s < NS; ++s) acc[s] += __shfl_xor(acc[s], off, 64);
        if (ct == 0) {
            #pragma unroll
            for (int s = 0; s < NS; ++s)
                O[((size_t)b * 768 + row) * NS + s] = acc[s];
        }
    }
}

// ---------------------------------------------------------------------------
// mid_all: fold_g (64 blocks) + wcv GEMM (16 blocks), both dep only on prep_all.
// ---------------------------------------------------------------------------
__global__ __launch_bounds__(256)
void mid_all(const float* __restrict__ O, const float* __restrict__ fk,
             const float* __restrict__ fq_b, const float* __restrict__ fk_b,
             float* __restrict__ g, float* __restrict__ h,
             const u16* __restrict__ wc2b, const u16* __restrict__ fvT,
             u16* __restrict__ wcv)
{
    __shared__ __align__(16) char smem[32768];
    const int bid = blockIdx.x;
    const int tid = threadIdx.x;
    if (bid < 64) {
        const int xb = bid & 7, b = bid >> 3;
        float (*fqqsh)[21] = (float(*)[21])smem;
        float* fqbsh = (float*)(smem + 21504);
        float (*red)[64][7] = (float(*)[64][7])(smem + 22528);
        for (int idx = tid; idx < 256 * NS; idx += 256) {
            int kc = idx / NS, s = idx - kc * NS;
            fqqsh[kc][s] = O[((size_t)b * 768 + kc) * NS + s];
        }
        fqbsh[tid] = fq_b[tid];
        __syncthreads();
        const int wave = tid >> 6, lane = tid & 63;
        const int c = xb * 64 + lane;
        float acc[21] = {};
        for (int i = 0; i < 64; ++i) {
            int kc = wave * 64 + i;
            float w = fk[(size_t)kc * NC + c];
            #pragma unroll
            for (int s = 0; s < NS; ++s) acc[s] += w * fqqsh[kc][s];
            acc[20] += w * fqbsh[kc];
        }
        #pragma unroll
        for (int r = 0; r < 3; ++r) {
            if (wave > 0) {
                #pragma unroll
                for (int k = 0; k < 7; ++k) red[wave - 1][lane][k] = acc[r * 7 + k];
            }
            __syncthreads();
            if (wave == 0) {
                #pragma unroll
                for (int k = 0; k < 7; ++k)
                    acc[r * 7 + k] += red[0][lane][k] + red[1][lane][k] + red[2][lane][k];
            }
            __syncthreads();
        }
        if (wave == 0) {
            float* gp = &g[((size_t)b * NC + c) * 24];
            #pragma unroll
            for (int s = 0; s < 21; ++s) gp[s] = acc[s] * SCL;
            gp[21] = gp[22] = gp[23] = 0.f;
        }
        if (xb == 0 && tid < 21) {
            float hh = 0.f;
            for (int kc = 0; kc < 256; ++kc)
                hh += fk_b[kc] * (tid < 20 ? fqqsh[kc][tid] : fqbsh[kc]);
            h[b * 24 + tid] = hh * SCL;
        }
    } else {
        const int t = bid - 64;
        const int nBase = (t & 3) * 128;
        const int mBase = (t >> 2) * 128;
        u16* sA = (u16*)smem;
        u16* sB = (u16*)(smem + 16384);
        gemm_body(wc2b + (size_t)mBase * 512, 512, fvT + (size_t)nBase * 512, 512,
                  wcv, 512, 512, 1.f, 0, mBase, nBase, sA, sB);
    }
}

// ---------------------------------------------------------------------------
// Fused key scan: word-attn logits (fp32) AND ks logits in one pass over key.
// ---------------------------------------------------------------------------
__global__ __launch_bounds__(256)
void scan_wk(const float* __restrict__ key, const float* __restrict__ qw,
             const float* __restrict__ qb, const int* __restrict__ wid,
             const float* __restrict__ g, const float* __restrict__ h,
             float* __restrict__ attnw, u16* __restrict__ attnwT,
             u16* __restrict__ ks)
{
    __shared__ float qshT[NC][20];
    __shared__ u16 gshb[NC][22];
    __shared__ float red[3][64][7];
    __shared__ float msk[20], qbs[20], hsh[21];
    const int b = blockIdx.y;
    const int tid = threadIdx.x;
    const float* qwb = qw + (size_t)b * NS * NC;
    for (int idx = tid; idx < NC * 20; idx += 256) {
        int c = idx / 20, s = idx - c * 20;
        qshT[c][s] = qwb[s * NC + c];
    }
    for (int idx = tid; idx < NC * 21; idx += 256) {
        int c = idx / 21, s = idx - c * 21;
        gshb[c][s] = f2b(g[((size_t)b * NC + c) * 24 + s]);
    }
    if (tid < 20) {
        msk[tid] = (wid[b * NS + tid] != 0) ? 1.f : 0.f;
        qbs[tid] = qb[b * NS + tid];
    }
    if (tid < 21) hsh[tid] = h[b * 24 + tid];
    __syncthreads();
    const int wave = tid >> 6, lane = tid & 63;
    const int n = blockIdx.x * 64 + lane;
    const int cbase = wave * 128;
    const float* kp = key + (size_t)b * NC * NHW + n;
    float acc[41];
    #pragma unroll
    for (int s = 0; s < 41; ++s)
        acc[s] = (wave == 0) ? (s < 20 ? qbs[s] : hsh[s - 20]) : 0.f;
    #pragma unroll 4
    for (int ci = 0; ci < 128; ++ci) {
        const int c = cbase + ci;
        float kv = kp[(size_t)c * NHW];
        #pragma unroll
        for (int s = 0; s < 20; ++s) acc[s] += qshT[c][s] * kv;
        #pragma unroll
        for (int s = 0; s < 21; ++s) acc[20 + s] += b2f(gshb[c][s]) * kv;
    }
    #pragma unroll
    for (int r = 0; r < 6; ++r) {
        if (wave > 0) {
            #pragma unroll
            for (int k = 0; k < 7; ++k) {
                int idx = r * 7 + k;
                if (idx < 41) red[wave - 1][lane][k] = acc[idx];
            }
        }
        __syncthreads();
        if (wave == 0) {
            #pragma unroll
            for (int k = 0; k < 7; ++k) {
                int idx = r * 7 + k;
                if (idx < 41)
                    acc[idx] += red[0][lane][k] + red[1][lane][k] + red[2][lane][k];
            }
        }
        __syncthreads();
    }
    if (wave == 0) {
        float mx = acc[0];
        #pragma unroll
        for (int s = 1; s < 20; ++s) mx = fmaxf(mx, acc[s]);
        float msum = 0.f;
        #pragma unroll
        for (int s = 0; s < 20; ++s) {
            acc[s] = __expf(acc[s] - mx) * msk[s];
            msum += acc[s];
        }
        const float rr = 1.f / msum;
        u16 row32[32];
        #pragma unroll
        for (int s = 0; s < 20; ++s) {
            float a = acc[s] * rr;
            attnw[((size_t)b * NS + s) * NHW + n] = a;
            row32[s] = f2b(a);
        }
        row32[20] = 0x3F80;
        #pragma unroll
        for (int s = 21; s < 32; ++s) row32[s] = 0;
        u16* dp = attnwT + ((size_t)b * NHW + n) * 32;
        #pragma unroll
        for (int q = 0; q < 4; ++q)
            *(u16x8*)&dp[q * 8] = *(u16x8*)&row32[q * 8];
        u16 rk[32];
        #pragma unroll
        for (int s = 0; s < 21; ++s) rk[s] = f2b(acc[20 + s]);
        #pragma unroll
        for (int s = 21; s < 32; ++s) rk[s] = 0;
        u16* kp2 = ks + ((size_t)b * NHW + n) * 32;
        #pragma unroll
        for (int q = 0; q < 4; ++q)
            *(u16x8*)&kp2[q * 8] = *(u16x8*)&rk[q * 8];
    }
}

extern "C" void kernel_launch(void* const* d_in, const int* in_sizes, int n_in,
                              void* d_out, int out_size, void* d_ws, size_t ws_size,
                              hipStream_t stream)
{
    const float* key   = (const float*)d_in[0];
    const float* query = (const float*)d_in[1];
    const int*   wid   = (const int*)d_in[2];
    const float* wv_w  = (const float*)d_in[3];
    const float* wv_b  = (const float*)d_in[4];
    const float* fk_w  = (const float*)d_in[5];
    const float* fk_b  = (const float*)d_in[6];
    const float* fq_w  = (const float*)d_in[7];
    const float* fq_b  = (const float*)d_in[8];
    const float* fv_w  = (const float*)d_in[9];
    const float* fv_b  = (const float*)d_in[10];
    const float* w1_w  = (const float*)d_in[11];
    const float* w1_b  = (const float*)d_in[12];
    const float* w2_w  = (const float*)d_in[13];
    const float* w2_b  = (const float*)d_in[14];
    float* out = (float*)d_out;

    char* p = (char*)d_ws;
    u16*   keyT   = (u16*)p;   p += (size_t)NB * NHW * NC * 2;    // 18.9 MB
    u8*    E8     = (u8*)p;    p += (size_t)NB * NHW * NHW;       // 42.5 MB
    u8*    vp8    = (u8*)p;    p += (size_t)NB * NC * NHW;        // 9.4 MB
    u16*   fvT    = (u16*)p;   p += (size_t)512 * 512 * 2;
    u16*   wc2b   = (u16*)p;   p += (size_t)512 * 512 * 2;
    u16*   wcv    = (u16*)p;   p += (size_t)512 * 512 * 2;
    u16*   attnwT = (u16*)p;   p += (size_t)NB * NHW * 32 * 2;
    u16*   ksb    = (u16*)p;   p += (size_t)NB * NHW * 32 * 2;
    float* attnw  = (float*)p; p += (size_t)NB * NS * NHW * 4;
    float* qw     = (float*)p; p += (size_t)NB * NS * NC * 4;
    float* qbuf   = (float*)p; p += (size_t)NB * NS * 4;
    float* Ofold  = (float*)p; p += (size_t)NB * 768 * NS * 4;
    float* g      = (float*)p; p += (size_t)NB * NC * 24 * 4;
    float* h      = (float*)p; p += (size_t)NB * 24 * 4;
    float* b2     = (float*)p; p += (size_t)512 * 4;
    float* Dpart  = (float*)p; p += (size_t)NB * 18 * NHW * 4;

    dim3 blk(256);

    // 1. fused prep: keyT + fvT + wc2/b2 + qw/qb + Ofold
    prep_all<<<dim3(3424), blk, 0, stream>>>(
        key, keyT, fv_w, fvT, w1_w, w1_b, w2_w, w2_b, fv_b, wc2b, b2,
        query, wv_w, wv_b, qw, qbuf, fq_w, Ofold);
    // 2. fold_g + wcv GEMM
    mid_all<<<dim3(80), blk, 0, stream>>>(
        Ofold, fk_w, fq_b, fk_b, g, h, wc2b, fvT, wcv);
    // 3. scan_wk
    scan_wk<<<dim3(36, NB), blk, 0, stream>>>(key, qw, qbuf, wid, g, h,
                                              attnw, attnwT, ksb);
    // 4. vproj GEMM + E-GEMM (independent, resource-compatible)
    tail_a<<<dim3(3168), blk, 0, stream>>>(wcv, keyT, vp8, attnwT, ksb, E8, Dpart);
    // 5. PV fp8 BK=128 with low-rank accumulator init
    pv_gemm<<<dim3(576), blk, 0, stream>>>(vp8, E8, Dpart, attnw, Ofold, b2, out);
}